// Round 9
// baseline (1337.608 us; speedup 1.0000x reference)
//
#include <hip/hip_runtime.h>

#define NN 20000
#define NE 640000
#define CC 128
#define HH 8
#define GG 50
#define FF 128
#define LL 3
#define TE2 64   // edges per tile in k_edge

typedef unsigned short u16;
typedef __attribute__((ext_vector_type(8))) short bf16x8;   // 8 bf16 = 4 VGPRs
typedef __attribute__((ext_vector_type(4))) float f32x4;

__device__ __forceinline__ u16 f2bf(float f) {
    union { float f; unsigned int i; } x; x.f = f;
    unsigned int r = x.i + 0x7fffu + ((x.i >> 16) & 1u);
    return (u16)(r >> 16);
}
// ShiftedSoftplus: softplus(x)-log2 via HW exp/log; |err| ~1e-7, far below bf16 noise
__device__ __forceinline__ float sspf(float x) {
    return fmaxf(x, 0.0f) + __logf(1.0f + __expf(-fabsf(x))) - 0.69314718055994531f;
}

// ---------------- CSR build (sort edges by dst) ----------------
__global__ void k_zero(int* __restrict__ c, int n) {
    int i = blockIdx.x * 256 + threadIdx.x;
    if (i < n) c[i] = 0;
}

__global__ void k_hist(const int* __restrict__ ei, int* __restrict__ c) {
    int e = blockIdx.x * 256 + threadIdx.x;
    if (e < NE) atomicAdd(&c[ei[NE + e]], 1);
}

__global__ __launch_bounds__(1024) void k_scan(const int* __restrict__ cnt,
                                               int* __restrict__ rowptr,
                                               int* __restrict__ cursor) {
    __shared__ int sums[1024];
    const int t = threadIdx.x;
    int local[20];
    int base = t * 20;
    int s = 0;
    #pragma unroll
    for (int i = 0; i < 20; ++i) {
        int idx = base + i;
        int v = (idx < NN) ? cnt[idx] : 0;
        local[i] = s; s += v;
    }
    sums[t] = s;
    __syncthreads();
    for (int off = 1; off < 1024; off <<= 1) {
        int v = (t >= off) ? sums[t - off] : 0;
        __syncthreads();
        sums[t] += v;
        __syncthreads();
    }
    int excl = (t == 0) ? 0 : sums[t - 1];
    #pragma unroll
    for (int i = 0; i < 20; ++i) {
        int idx = base + i;
        if (idx < NN) { int r = excl + local[i]; rowptr[idx] = r; cursor[idx] = r; }
    }
    if (t == 1023) rowptr[NN] = sums[1023];
}

__global__ void k_scatter(const int* __restrict__ ei, int* __restrict__ cursor,
                          int* __restrict__ srcp, int* __restrict__ dstp) {
    int e = blockIdx.x * 256 + threadIdx.x;
    if (e >= NE) return;
    int s = ei[e], d = ei[NE + e];
    int pp = atomicAdd(&cursor[d], 1);
    srcp[pp] = s; dstp[pp] = d;
}

__global__ void k_hinit(const int* __restrict__ z, const float* __restrict__ emb,
                        float* __restrict__ h) {
    int i = blockIdx.x * 256 + threadIdx.x;
    if (i < NN * CC) h[i] = emb[z[i >> 7] * CC + (i & 127)];
}

// ---------------- weight prep (once per call) ----------------
__global__ void k_prep1(const float* __restrict__ w1, u16* __restrict__ w1tg) {
    int i = blockIdx.x * 256 + threadIdx.x;
    if (i < LL * 128 * 64) {
        int l = i / (128 * 64); int r = i % (128 * 64); int c = r >> 6, k = r & 63;
        float v = (k < GG) ? w1[(l * GG + k) * FF + c] : 0.0f;
        w1tg[i] = f2bf(v);
    }
}

// W23[l][k][cp] = sum_c w2[l][k][c] * we[l][c][cp]; stored transposed bf16 [l][cp][k]
__global__ __launch_bounds__(128) void k_prep23(const float* __restrict__ w2,
                                                const float* __restrict__ we,
                                                u16* __restrict__ w23tg) {
    int l = blockIdx.x >> 7, k = blockIdx.x & 127;
    int cp = threadIdx.x;
    float s = 0.0f;
    for (int c = 0; c < FF; ++c)
        s = fmaf(w2[((size_t)l * FF + k) * FF + c], we[((size_t)l * FF + c) * CC + cp], s);
    w23tg[((size_t)l * CC + cp) * FF + k] = f2bf(s);
}

// b23[l][cp] = be[l][cp] + sum_k b2[l][k] * we[l][k][cp]
__global__ __launch_bounds__(128) void k_prepb(const float* __restrict__ b2,
                                               const float* __restrict__ we,
                                               const float* __restrict__ be,
                                               float* __restrict__ b23g) {
    int l = blockIdx.x;
    int cp = threadIdx.x;
    float s = be[l * CC + cp];
    for (int k = 0; k < FF; ++k)
        s = fmaf(b2[l * FF + k], we[((size_t)l * FF + k) * CC + cp], s);
    b23g[l * CC + cp] = s;
}

// node weights: wn[((l*5+m)*128 + c)*128 + k] = bf16(W_m[l][k][c]); m: q,k,v,skip,l
__global__ void k_prepn(const float* __restrict__ wq, const float* __restrict__ wk,
                        const float* __restrict__ wv, const float* __restrict__ wsk,
                        const float* __restrict__ wl, u16* __restrict__ wn) {
    int i = blockIdx.x * 256 + threadIdx.x;
    if (i >= LL * 5 * 128 * 128) return;
    int k = i & 127, c = (i >> 7) & 127;
    int lm = i >> 14; int m = lm % 5, l = lm / 5;
    const float* W = (m == 0) ? wq : (m == 1) ? wk : (m == 2) ? wv : (m == 3) ? wsk : wl;
    wn[i] = f2bf(W[((size_t)l * 128 + k) * 128 + c]);
}

// ---------------- MFMA node GEMM: q/k/v/skip (grid = tiles*4, one matrix each) --
// m==0 blocks additionally zero num/den for their row range.
__global__ __launch_bounds__(256) void k_qkvs_mfma(
    const float* __restrict__ A, const u16* __restrict__ wnl,
    const float* __restrict__ b0, const float* __restrict__ b1p,
    const float* __restrict__ b2p, const float* __restrict__ b3p,
    float* __restrict__ o0, float* __restrict__ o1,
    float* __restrict__ o2, float* __restrict__ o3,
    float* __restrict__ num, float* __restrict__ den, int nrows)
{
    __shared__ __align__(16) short hb[128 * 136];
    __shared__ __align__(16) short wT[128 * 136];
    const int t = threadIdx.x, lane = t & 63, w = t >> 6;
    const int tx = lane & 15, tg = lane >> 4;
    const int m = blockIdx.x & 3, tile = blockIdx.x >> 2;
    const int n0 = tile * 128;
    for (int idx = t; idx < 128 * 32; idx += 256) {
        int r = idx >> 5, kq = idx & 31;
        int n = n0 + r;
        float4 hv;
        if (n < nrows) hv = *(const float4*)&A[(size_t)n * 128 + kq * 4];
        else { hv.x = hv.y = hv.z = hv.w = 0.0f; }
        uint2 pk = make_uint2((unsigned)f2bf(hv.x) | ((unsigned)f2bf(hv.y) << 16),
                              (unsigned)f2bf(hv.z) | ((unsigned)f2bf(hv.w) << 16));
        *(uint2*)&hb[r * 136 + kq * 4] = pk;
    }
    const u16* Wm = wnl + (size_t)m * 16384;
    for (int idx = t; idx < 128 * 16; idx += 256) {
        int c = idx >> 4, oc = idx & 15;
        *(float4*)&wT[c * 136 + oc * 8] = *(const float4*)&Wm[c * 128 + oc * 8];
    }
    if (m == 0) {
        const float4 z4 = { 0.0f, 0.0f, 0.0f, 0.0f };
        for (int idx = t; idx < 128 * 32; idx += 256) {
            int r = idx >> 5, cq = idx & 31;
            int n = n0 + r;
            if (n < nrows) *(float4*)&num[(size_t)n * 128 + cq * 4] = z4;
        }
        if (t < 256) {
            int r = t >> 1, half = t & 1;
            int n = n0 + r;
            if (n < nrows) *(float4*)&den[(size_t)n * HH + half * 4] = z4;
        }
    }
    __syncthreads();
    const f32x4 zf4 = { 0.0f, 0.0f, 0.0f, 0.0f };
    f32x4 acc[2][8];
    #pragma unroll
    for (int mt = 0; mt < 2; ++mt)
        #pragma unroll
        for (int nt = 0; nt < 8; ++nt) acc[mt][nt] = zf4;
    #pragma unroll
    for (int s = 0; s < 4; ++s) {
        bf16x8 af[2], bfr[8];
        #pragma unroll
        for (int mt = 0; mt < 2; ++mt)
            af[mt] = *(const bf16x8*)&wT[(w * 32 + mt * 16 + tx) * 136 + s * 32 + tg * 8];
        #pragma unroll
        for (int nt = 0; nt < 8; ++nt)
            bfr[nt] = *(const bf16x8*)&hb[(nt * 16 + tx) * 136 + s * 32 + tg * 8];
        #pragma unroll
        for (int mt = 0; mt < 2; ++mt)
            #pragma unroll
            for (int nt = 0; nt < 8; ++nt)
                acc[mt][nt] = __builtin_amdgcn_mfma_f32_16x16x32_bf16(af[mt], bfr[nt], acc[mt][nt], 0, 0, 0);
    }
    const float* Bm = (m == 0) ? b0 : (m == 1) ? b1p : (m == 2) ? b2p : b3p;
    float* Om = (m == 0) ? o0 : (m == 1) ? o1 : (m == 2) ? o2 : o3;
    #pragma unroll
    for (int mt = 0; mt < 2; ++mt) {
        int c0 = w * 32 + mt * 16 + tg * 4;
        float4 bb = *(const float4*)&Bm[c0];
        #pragma unroll
        for (int nt = 0; nt < 8; ++nt) {
            int n = n0 + nt * 16 + tx;
            if (n < nrows) {
                float4 ov;
                ov.x = acc[mt][nt][0] + bb.x; ov.y = acc[mt][nt][1] + bb.y;
                ov.z = acc[mt][nt][2] + bb.z; ov.w = acc[mt][nt][3] + bb.w;
                *(float4*)&Om[(size_t)n * 128 + c0] = ov;
            }
        }
    }
}

// ---------------- MFMA update: t=ssp(num/den+skip) -> GEMM(wl) -> h += ----------
__global__ __launch_bounds__(256) void k_upd_mfma(
    const float* __restrict__ num, const float* __restrict__ den,
    const float* __restrict__ skip, const u16* __restrict__ wlT,
    const float* __restrict__ Bias, float* __restrict__ h, int nrows)
{
    __shared__ __align__(16) short tb[128 * 136];
    __shared__ __align__(16) short wT[128 * 136];
    const int t = threadIdx.x, lane = t & 63, w = t >> 6;
    const int tx = lane & 15, tg = lane >> 4;
    const int n0 = blockIdx.x * 128;
    for (int idx = t; idx < 128 * 32; idx += 256) {
        int r = idx >> 5, kq = idx & 31;
        int n = n0 + r;
        float v0 = 0, v1 = 0, v2 = 0, v3 = 0;
        if (n < nrows) {
            float4 nv = *(const float4*)&num[(size_t)n * 128 + kq * 4];
            float4 sv = *(const float4*)&skip[(size_t)n * 128 + kq * 4];
            float dd = den[n * HH + (kq >> 2)] + 1e-16f;
            v0 = sspf(nv.x / dd + sv.x); v1 = sspf(nv.y / dd + sv.y);
            v2 = sspf(nv.z / dd + sv.z); v3 = sspf(nv.w / dd + sv.w);
        }
        uint2 pk = make_uint2((unsigned)f2bf(v0) | ((unsigned)f2bf(v1) << 16),
                              (unsigned)f2bf(v2) | ((unsigned)f2bf(v3) << 16));
        *(uint2*)&tb[r * 136 + kq * 4] = pk;
    }
    for (int idx = t; idx < 128 * 16; idx += 256) {
        int c = idx >> 4, oc = idx & 15;
        *(float4*)&wT[c * 136 + oc * 8] = *(const float4*)&wlT[c * 128 + oc * 8];
    }
    __syncthreads();
    const f32x4 zf4 = { 0.0f, 0.0f, 0.0f, 0.0f };
    f32x4 acc[2][8];
    #pragma unroll
    for (int mt = 0; mt < 2; ++mt)
        #pragma unroll
        for (int nt = 0; nt < 8; ++nt) acc[mt][nt] = zf4;
    #pragma unroll
    for (int s = 0; s < 4; ++s) {
        bf16x8 af[2], bfr[8];
        #pragma unroll
        for (int mt = 0; mt < 2; ++mt)
            af[mt] = *(const bf16x8*)&wT[(w * 32 + mt * 16 + tx) * 136 + s * 32 + tg * 8];
        #pragma unroll
        for (int nt = 0; nt < 8; ++nt)
            bfr[nt] = *(const bf16x8*)&tb[(nt * 16 + tx) * 136 + s * 32 + tg * 8];
        #pragma unroll
        for (int mt = 0; mt < 2; ++mt)
            #pragma unroll
            for (int nt = 0; nt < 8; ++nt)
                acc[mt][nt] = __builtin_amdgcn_mfma_f32_16x16x32_bf16(af[mt], bfr[nt], acc[mt][nt], 0, 0, 0);
    }
    #pragma unroll
    for (int mt = 0; mt < 2; ++mt) {
        int c0 = w * 32 + mt * 16 + tg * 4;
        float4 bb = *(const float4*)&Bias[c0];
        #pragma unroll
        for (int nt = 0; nt < 8; ++nt) {
            int n = n0 + nt * 16 + tx;
            if (n < nrows) {
                float4 hv = *(const float4*)&h[(size_t)n * 128 + c0];
                hv.x += acc[mt][nt][0] + bb.x; hv.y += acc[mt][nt][1] + bb.y;
                hv.z += acc[mt][nt][2] + bb.z; hv.w += acc[mt][nt][3] + bb.w;
                *(float4*)&h[(size_t)n * 128 + c0] = hv;
            }
        }
    }
}

// ---------------- persistent MFMA edge pipeline: 8 waves, 64-edge tiles, -------
// weights in REGISTERS (48 VGPR), LDS ~46 KB -> 2 blocks/CU for inter-block
// latency hiding. Wave w: wr=w>>1 owns c-rows [wr*32,+32), wc=w&1 owns
// edge-cols [wc*32,+32). q/k/v gathers at use-site (prefetch spills: r5/r7).
__global__ __launch_bounds__(512, 4) void k_edge(
    const int* __restrict__ srcp, const int* __restrict__ dstp,
    const float* __restrict__ pos,
    const u16* __restrict__ w1tg, const u16* __restrict__ w23tg,
    const float* __restrict__ b1, const float* __restrict__ b23,
    const float* __restrict__ qn, const float* __restrict__ kn, const float* __restrict__ vn,
    float* __restrict__ num, float* __restrict__ den, int ntiles)
{
    __shared__ __align__(16) short attrB[TE2 * 72];  // attr [r][k64] staged ahead
    __shared__ __align__(16) short a2[TE2 * 136];    // act1 bf16 / walk-lo f32 [r][68]
    __shared__ __align__(16) short wkB[TE2 * 136];   // walk-hi f32 [r][68]
    __shared__ int sls2[2][TE2], dls2[2][TE2];

    const int t = threadIdx.x;
    const int lane = t & 63;
    const int w = t >> 6;
    const int wr = w >> 1, wc = w & 1;
    const int tx = lane & 15, tg = lane >> 4;

    // ---- tile-invariant weights -> registers (A-fragments of this wave) ----
    bf16x8 af1[4];   // GEMM1: [mt*2+s], rows wr*32+mt*16+tx, k s*32+tg*8 (K=64)
    #pragma unroll
    for (int mt = 0; mt < 2; ++mt)
        #pragma unroll
        for (int s = 0; s < 2; ++s)
            af1[mt * 2 + s] = *(const bf16x8*)&w1tg[(wr * 32 + mt * 16 + tx) * 64 + s * 32 + tg * 8];
    bf16x8 af2[8];   // GEMM23: [mt*4+s], K=128
    #pragma unroll
    for (int mt = 0; mt < 2; ++mt)
        #pragma unroll
        for (int s = 0; s < 4; ++s)
            af2[mt * 4 + s] = *(const bf16x8*)&w23tg[(wr * 32 + mt * 16 + tx) * 128 + s * 32 + tg * 8];

    float b1v[8], bcv[8];
    #pragma unroll
    for (int mt = 0; mt < 2; ++mt)
        #pragma unroll
        for (int q = 0; q < 4; ++q) {
            int c = wr * 32 + mt * 16 + tg * 4 + q;
            b1v[mt * 4 + q] = b1[c]; bcv[mt * 4 + q] = b23[c];
        }

    float* a2f = (float*)a2;
    float* wkf = (float*)wkB;

    const float STEP = 10.0f / 49.0f;
    const float COEF = -0.5f / (STEP * STEP);
    const f32x4 zf4 = { 0.0f, 0.0f, 0.0f, 0.0f };

    // stage tile (idx + gaussian attr) -- 128 threads, ts in [0,128)
    auto stage = [&](int tile, int nx, int ts) {
        int r = ts >> 1, half = ts & 1;
        int e = tile * TE2 + r;
        int sn = srcp[e], dn = dstp[e];
        if (half == 0) { sls2[nx][r] = sn; dls2[nx][r] = dn; }
        float dx = pos[dn * 3 + 0] - pos[sn * 3 + 0];
        float dy = pos[dn * 3 + 1] - pos[sn * 3 + 1];
        float dz = pos[dn * 3 + 2] - pos[sn * 3 + 2];
        float dd = sqrtf(dx * dx + dy * dy + dz * dz + 1e-12f);
        #pragma unroll
        for (int oct = 0; oct < 4; ++oct) {
            int k0 = half * 32 + oct * 8;
            __align__(16) u16 tmp[8];
            #pragma unroll
            for (int j = 0; j < 8; ++j) {
                int k = k0 + j;
                float v = 0.0f;
                if (k < GG) { float df = dd - STEP * (float)k; v = __expf(COEF * df * df); }
                tmp[j] = f2bf(v);
            }
            *(float4*)&attrB[r * 72 + k0] = *(float4*)&tmp[0];
        }
    };

    if (blockIdx.x < (unsigned)ntiles && t >= 384) stage(blockIdx.x, 0, t - 384);
    __syncthreads();

    int it = 0;
    for (int tile = blockIdx.x; tile < ntiles; tile += gridDim.x, ++it) {
        const int cur = it & 1, nx = cur ^ 1;

        // ---- GEMM1^T (weights in regs) ----
        f32x4 acc[2][2];
        #pragma unroll
        for (int mt = 0; mt < 2; ++mt)
            #pragma unroll
            for (int nt = 0; nt < 2; ++nt) acc[mt][nt] = zf4;
        #pragma unroll
        for (int s = 0; s < 2; ++s) {
            bf16x8 bfr[2];
            #pragma unroll
            for (int nt = 0; nt < 2; ++nt)
                bfr[nt] = *(const bf16x8*)&attrB[(wc * 32 + nt * 16 + tx) * 72 + s * 32 + tg * 8];
            #pragma unroll
            for (int mt = 0; mt < 2; ++mt)
                #pragma unroll
                for (int nt = 0; nt < 2; ++nt)
                    acc[mt][nt] = __builtin_amdgcn_mfma_f32_16x16x32_bf16(af1[mt * 2 + s], bfr[nt], acc[mt][nt], 0, 0, 0);
        }
        // ssp(. + b1) -> a2[r][c]
        #pragma unroll
        for (int mt = 0; mt < 2; ++mt) {
            int c0 = wr * 32 + mt * 16 + tg * 4;
            #pragma unroll
            for (int nt = 0; nt < 2; ++nt) {
                int r = wc * 32 + nt * 16 + tx;
                u16 o0 = f2bf(sspf(acc[mt][nt][0] + b1v[mt * 4 + 0]));
                u16 o1 = f2bf(sspf(acc[mt][nt][1] + b1v[mt * 4 + 1]));
                u16 o2 = f2bf(sspf(acc[mt][nt][2] + b1v[mt * 4 + 2]));
                u16 o3 = f2bf(sspf(acc[mt][nt][3] + b1v[mt * 4 + 3]));
                uint2 pkd = make_uint2((unsigned)o0 | ((unsigned)o1 << 16),
                                       (unsigned)o2 | ((unsigned)o3 << 16));
                *(uint2*)&a2[r * 136 + c0] = pkd;
            }
        }
        __syncthreads();   // B_a: act1 ready; attrB dead

        // ---- GEMM23^T (weights in regs, K=128) ----
        #pragma unroll
        for (int mt = 0; mt < 2; ++mt)
            #pragma unroll
            for (int nt = 0; nt < 2; ++nt) acc[mt][nt] = zf4;
        #pragma unroll
        for (int s = 0; s < 4; ++s) {
            bf16x8 bfr[2];
            #pragma unroll
            for (int nt = 0; nt < 2; ++nt)
                bfr[nt] = *(const bf16x8*)&a2[(wc * 32 + nt * 16 + tx) * 136 + s * 32 + tg * 8];
            #pragma unroll
            for (int mt = 0; mt < 2; ++mt)
                #pragma unroll
                for (int nt = 0; nt < 2; ++nt)
                    acc[mt][nt] = __builtin_amdgcn_mfma_f32_16x16x32_bf16(af2[mt * 4 + s], bfr[nt], acc[mt][nt], 0, 0, 0);
        }
        __syncthreads();   // B_b: all reads of a2 done

        // ---- epilogue: use-site gathers, logits, w=exp, write w*ve f32 ----
        {
            int rr2[2], sn2[2], dn2[2];
            #pragma unroll
            for (int nt = 0; nt < 2; ++nt) {
                rr2[nt] = wc * 32 + nt * 16 + tx;
                sn2[nt] = sls2[cur][rr2[nt]];
                dn2[nt] = dls2[cur][rr2[nt]];
            }
            #pragma unroll
            for (int mt = 0; mt < 2; ++mt) {
                int c0 = wr * 32 + mt * 16 + tg * 4;
                int h = wr * 2 + mt;
                #pragma unroll
                for (int nt = 0; nt < 2; ++nt) {
                    float4 kv = *(const float4*)&kn[(size_t)sn2[nt] * CC + c0];
                    float4 vv = *(const float4*)&vn[(size_t)sn2[nt] * CC + c0];
                    float4 qv = *(const float4*)&qn[(size_t)dn2[nt] * CC + c0];
                    float ep0 = acc[mt][nt][0] + bcv[mt * 4 + 0];
                    float ep1 = acc[mt][nt][1] + bcv[mt * 4 + 1];
                    float ep2 = acc[mt][nt][2] + bcv[mt * 4 + 2];
                    float ep3 = acc[mt][nt][3] + bcv[mt * 4 + 3];
                    float lg = qv.x * (kv.x + ep0) + qv.y * (kv.y + ep1)
                             + qv.z * (kv.z + ep2) + qv.w * (kv.w + ep3);
                    lg += __shfl_xor(lg, 16);
                    lg += __shfl_xor(lg, 32);
                    float wgt = __expf(lg * 0.25f);
                    float4 wv;
                    wv.x = wgt * (vv.x + ep0); wv.y = wgt * (vv.y + ep1);
                    wv.z = wgt * (vv.z + ep2); wv.w = wgt * (vv.w + ep3);
                    if (c0 < 64) *(float4*)&a2f[rr2[nt] * 68 + c0] = wv;
                    else         *(float4*)&wkf[rr2[nt] * 68 + (c0 - 64)] = wv;
                    if (tg == 0) {
                        if (h < 4) a2f[rr2[nt] * 68 + 64 + h] = wgt;
                        else       wkf[rr2[nt] * 68 + 64 + (h - 4)] = wgt;
                    }
                }
            }
        }
        __syncthreads();   // B_c: walk data ready

        // ---- walk (t<272: 2 chunks x 136 ch) || stage next (384<=t<512) ----
        if (t < 272) {
            int ch = t % 136;
            int r0 = (t / 136) * 32;
            const int* dls = dls2[cur];
            float run = 0.0f;
            #pragma unroll 4
            for (int rr = 0; rr < 32; ++rr) {
                int r = r0 + rr;
                float v;
                if (ch < 64)       v = a2f[r * 68 + ch];
                else if (ch < 128) v = wkf[r * 68 + (ch - 64)];
                else if (ch < 132) v = a2f[r * 68 + 64 + (ch - 128)];
                else               v = wkf[r * 68 + 64 + (ch - 132)];
                run += v;
                if (rr == 31 || dls[r + 1] != dls[r]) {
                    int dn = dls[r];
                    if (ch < 128) atomicAdd(&num[(size_t)dn * CC + ch], run);
                    else          atomicAdd(&den[(size_t)dn * HH + (ch - 128)], run);
                    run = 0.0f;
                }
            }
        } else if (t >= 384) {
            int nt2 = tile + gridDim.x;
            if (nt2 < ntiles) stage(nt2, nx, t - 384);
        }
        __syncthreads();   // B_d: close iteration
    }
}

// ---------------- output head ----------------
__global__ __launch_bounds__(64) void k_head(
    const float* __restrict__ h,
    const float* __restrict__ w1, const float* __restrict__ b1,
    const float* __restrict__ w2, const float* __restrict__ b2,
    float* __restrict__ out)
{
    const int n = blockIdx.x;
    const int j = threadIdx.x;
    float acc = 0.0f;
    for (int k = 0; k < CC; ++k)
        acc = fmaf(h[(size_t)n * CC + k], w1[k * 64 + j], acc);
    float m = sspf(acc + b1[j]);
    float o = m * w2[j];
    #pragma unroll
    for (int msk = 32; msk > 0; msk >>= 1) o += __shfl_xor(o, msk);
    if (j == 0) out[n] = o + b2[0];
}

extern "C" void kernel_launch(void* const* d_in, const int* in_sizes, int n_in,
                              void* d_out, int out_size, void* d_ws, size_t ws_size,
                              hipStream_t stream)
{
    const int*   z   = (const int*)d_in[0];
    const float* pos = (const float*)d_in[1];
    const int*   ei  = (const int*)d_in[2];
    const float* emb = (const float*)d_in[3];
    const float* w1  = (const float*)d_in[4];
    const float* b1  = (const float*)d_in[5];
    const float* w2  = (const float*)d_in[6];
    const float* b2  = (const float*)d_in[7];
    const float* wq  = (const float*)d_in[8];
    const float* bq  = (const float*)d_in[9];
    const float* wk  = (const float*)d_in[10];
    const float* bk  = (const float*)d_in[11];
    const float* wv  = (const float*)d_in[12];
    const float* bv  = (const float*)d_in[13];
    const float* we  = (const float*)d_in[14];
    const float* be  = (const float*)d_in[15];
    const float* wsk = (const float*)d_in[16];
    const float* bsk = (const float*)d_in[17];
    const float* wl  = (const float*)d_in[18];
    const float* bl  = (const float*)d_in[19];
    const float* wo1 = (const float*)d_in[20];
    const float* bo1 = (const float*)d_in[21];
    const float* wo2 = (const float*)d_in[22];
    const float* bo2 = (const float*)d_in[23];

    char* p = (char*)d_ws;
    auto alloc = [&](size_t bytes) -> void* {
        void* r = (void*)p; p += (bytes + 255) & ~(size_t)255; return r;
    };
    float* h    = (float*)alloc((size_t)NN * CC * 4);
    float* q    = (float*)alloc((size_t)NN * CC * 4);
    float* kk   = (float*)alloc((size_t)NN * CC * 4);
    float* vv   = (float*)alloc((size_t)NN * CC * 4);
    float* skip = (float*)alloc((size_t)NN * CC * 4);
    float* num  = (float*)alloc((size_t)NN * CC * 4);
    float* den  = (float*)alloc((size_t)NN * HH * 4);
    u16* w1tg  = (u16*)alloc((size_t)LL * 128 * 64 * 2);
    u16* w23tg = (u16*)alloc((size_t)LL * 128 * 128 * 2);
    float* b23g = (float*)alloc((size_t)LL * 128 * 4);
    u16* wn    = (u16*)alloc((size_t)LL * 5 * 128 * 128 * 2);
    int* count  = (int*)alloc((size_t)(NN + 1) * 4);
    int* rowptr = (int*)alloc((size_t)(NN + 1) * 4);
    int* cursor = (int*)alloc((size_t)NN * 4);
    int* srcp   = (int*)alloc((size_t)NE * 4);
    int* dstp   = (int*)alloc((size_t)NE * 4);

    k_zero<<<(NN + 255) / 256, 256, 0, stream>>>(count, NN);
    k_hist<<<(NE + 255) / 256, 256, 0, stream>>>(ei, count);
    k_scan<<<1, 1024, 0, stream>>>(count, rowptr, cursor);
    k_scatter<<<(NE + 255) / 256, 256, 0, stream>>>(ei, cursor, srcp, dstp);
    k_hinit<<<(NN * CC + 255) / 256, 256, 0, stream>>>(z, emb, h);
    k_prep1<<<(LL * 128 * 64 + 255) / 256, 256, 0, stream>>>(w1, w1tg);
    k_prep23<<<LL * 128, 128, 0, stream>>>(w2, we, w23tg);
    k_prepb<<<LL, 128, 0, stream>>>(b2, we, be, b23g);
    k_prepn<<<(LL * 5 * 128 * 128 + 255) / 256, 256, 0, stream>>>(wq, wk, wv, wsk, wl, wn);

    const int NT = (NN + 127) / 128;   // 157
    for (int l = 0; l < LL; ++l) {
        const u16* wnl = wn + (size_t)l * 5 * 16384;
        k_qkvs_mfma<<<NT * 4, 256, 0, stream>>>(h, wnl,
            bq + l * CC, bk + l * CC, bv + l * CC, bsk + l * CC,
            q, kk, vv, skip, num, den, NN);
        k_edge<<<512, 512, 0, stream>>>(srcp, dstp, pos,
            w1tg + (size_t)l * 128 * 64, w23tg + (size_t)l * 128 * 128,
            b1 + l * FF, b23g + l * CC,
            q, kk, vv, num, den, NE / TE2);
        k_upd_mfma<<<NT, 256, 0, stream>>>(num, den, skip,
            wnl + 4 * 16384, bl + l * CC, h, NN);
    }
    k_head<<<NN, 64, 0, stream>>>(h, wo1, bo1, wo2, bo2, (float*)d_out);
}

// Round 10
// 637.158 us; speedup vs baseline: 2.0993x; 2.0993x over previous
//
#include <hip/hip_runtime.h>

#define NN 20000
#define NE 640000
#define CC 128
#define HH 8
#define GG 50
#define FF 128
#define LL 3
#define NTAB 2048
#define DMAX 12.0f

typedef unsigned short u16;
typedef __attribute__((ext_vector_type(8))) short bf16x8;   // 8 bf16 = 4 VGPRs
typedef __attribute__((ext_vector_type(4))) float f32x4;

__device__ __forceinline__ u16 f2bf(float f) {
    union { float f; unsigned int i; } x; x.f = f;
    unsigned int r = x.i + 0x7fffu + ((x.i >> 16) & 1u);
    return (u16)(r >> 16);
}
// ShiftedSoftplus: softplus(x)-log2 via HW exp/log
__device__ __forceinline__ float sspf(float x) {
    return fmaxf(x, 0.0f) + __logf(1.0f + __expf(-fabsf(x))) - 0.69314718055994531f;
}

// ---------------- CSR build (sort edges by dst) ----------------
__global__ void k_zero(int* __restrict__ c, int n) {
    int i = blockIdx.x * 256 + threadIdx.x;
    if (i < n) c[i] = 0;
}

__global__ void k_hist(const int* __restrict__ ei, int* __restrict__ c) {
    int e = blockIdx.x * 256 + threadIdx.x;
    if (e < NE) atomicAdd(&c[ei[NE + e]], 1);
}

__global__ __launch_bounds__(1024) void k_scan(const int* __restrict__ cnt,
                                               int* __restrict__ rowptr,
                                               int* __restrict__ cursor) {
    __shared__ int sums[1024];
    const int t = threadIdx.x;
    int local[20];
    int base = t * 20;
    int s = 0;
    #pragma unroll
    for (int i = 0; i < 20; ++i) {
        int idx = base + i;
        int v = (idx < NN) ? cnt[idx] : 0;
        local[i] = s; s += v;
    }
    sums[t] = s;
    __syncthreads();
    for (int off = 1; off < 1024; off <<= 1) {
        int v = (t >= off) ? sums[t - off] : 0;
        __syncthreads();
        sums[t] += v;
        __syncthreads();
    }
    int excl = (t == 0) ? 0 : sums[t - 1];
    #pragma unroll
    for (int i = 0; i < 20; ++i) {
        int idx = base + i;
        if (idx < NN) { int r = excl + local[i]; rowptr[idx] = r; cursor[idx] = r; }
    }
    if (t == 1023) rowptr[NN] = sums[1023];
}

__global__ void k_scatter(const int* __restrict__ ei, int* __restrict__ cursor,
                          int* __restrict__ srcp, int* __restrict__ dstp) {
    int e = blockIdx.x * 256 + threadIdx.x;
    if (e >= NE) return;
    int s = ei[e], d = ei[NE + e];
    int pp = atomicAdd(&cursor[d], 1);
    srcp[pp] = s; dstp[pp] = d;
}

__global__ void k_hinit(const int* __restrict__ z, const float* __restrict__ emb,
                        float* __restrict__ h) {
    int i = blockIdx.x * 256 + threadIdx.x;
    if (i < NN * CC) h[i] = emb[z[i >> 7] * CC + (i & 127)];
}

// per-edge (i0, frac) for the ep table; d is layer-invariant
__global__ void k_dist(const int* __restrict__ srcp, const int* __restrict__ dstp,
                       const float* __restrict__ pos, float2* __restrict__ ifrac) {
    int e = blockIdx.x * 256 + threadIdx.x;
    if (e >= NE) return;
    int a = srcp[e], b = dstp[e];
    float dx = pos[b * 3 + 0] - pos[a * 3 + 0];
    float dy = pos[b * 3 + 1] - pos[a * 3 + 1];
    float dz = pos[b * 3 + 2] - pos[a * 3 + 2];
    float d = sqrtf(dx * dx + dy * dy + dz * dz + 1e-12f);
    float t = fminf(d * ((float)NTAB / DMAX), (float)NTAB - 1e-3f);
    int i0 = (int)t;
    float2 u; u.x = __int_as_float(i0); u.y = t - (float)i0;
    ifrac[e] = u;
}

// ---------------- weight prep (once per call) ----------------
// W23f[l][k][cp] = sum_c w2[l][k][c] * we[l][c][cp]  (fp32)
__global__ __launch_bounds__(128) void k_prep23(const float* __restrict__ w2,
                                                const float* __restrict__ we,
                                                float* __restrict__ w23f) {
    int l = blockIdx.x >> 7, k = blockIdx.x & 127;
    int cp = threadIdx.x;
    float s = 0.0f;
    for (int c = 0; c < FF; ++c)
        s = fmaf(w2[((size_t)l * FF + k) * FF + c], we[((size_t)l * FF + c) * CC + cp], s);
    w23f[((size_t)l * FF + k) * CC + cp] = s;
}

// b23[l][cp] = be[l][cp] + sum_k b2[l][k] * we[l][k][cp]
__global__ __launch_bounds__(128) void k_prepb(const float* __restrict__ b2,
                                               const float* __restrict__ we,
                                               const float* __restrict__ be,
                                               float* __restrict__ b23g) {
    int l = blockIdx.x;
    int cp = threadIdx.x;
    float s = be[l * CC + cp];
    for (int k = 0; k < FF; ++k)
        s = fmaf(b2[l * FF + k], we[((size_t)l * FF + k) * CC + cp], s);
    b23g[l * CC + cp] = s;
}

// ep table: tab[l][i][cp] = MLP(gauss(d_i)) exact fp32, d_i = i*DMAX/NTAB, i in [0,NTAB]
__global__ __launch_bounds__(128) void k_prept(const float* __restrict__ w1,
                                               const float* __restrict__ b1,
                                               const float* __restrict__ w23f,
                                               const float* __restrict__ b23g,
                                               float* __restrict__ tab) {
    const int l = blockIdx.x / (NTAB + 1);
    const int i = blockIdx.x % (NTAB + 1);
    const int c = threadIdx.x;
    __shared__ float attr[GG];
    __shared__ float hid[FF];
    const float STEP = 10.0f / 49.0f;
    const float COEF = -0.5f / (STEP * STEP);
    float d = (float)i * (DMAX / (float)NTAB);
    if (c < GG) { float df = d - STEP * (float)c; attr[c] = __expf(COEF * df * df); }
    __syncthreads();
    float s = b1[l * FF + c];
    for (int g = 0; g < GG; ++g)
        s = fmaf(attr[g], w1[((size_t)l * GG + g) * FF + c], s);
    hid[c] = sspf(s);
    __syncthreads();
    float o = b23g[l * CC + c];
    for (int k = 0; k < FF; ++k)
        o = fmaf(hid[k], w23f[((size_t)l * FF + k) * CC + c], o);
    tab[((size_t)l * (NTAB + 1) + i) * CC + c] = o;
}

// node weights: wn[((l*5+m)*128 + c)*128 + k] = bf16(W_m[l][k][c]); m: q,k,v,skip,l
__global__ void k_prepn(const float* __restrict__ wq, const float* __restrict__ wk,
                        const float* __restrict__ wv, const float* __restrict__ wsk,
                        const float* __restrict__ wl, u16* __restrict__ wn) {
    int i = blockIdx.x * 256 + threadIdx.x;
    if (i >= LL * 5 * 128 * 128) return;
    int k = i & 127, c = (i >> 7) & 127;
    int lm = i >> 14; int m = lm % 5, l = lm / 5;
    const float* W = (m == 0) ? wq : (m == 1) ? wk : (m == 2) ? wv : (m == 3) ? wsk : wl;
    wn[i] = f2bf(W[((size_t)l * 128 + k) * 128 + c]);
}

// ---------------- MFMA node GEMM: q/k/v/skip (grid = tiles*4, one matrix each) --
__global__ __launch_bounds__(256) void k_qkvs_mfma(
    const float* __restrict__ A, const u16* __restrict__ wnl,
    const float* __restrict__ b0, const float* __restrict__ b1p,
    const float* __restrict__ b2p, const float* __restrict__ b3p,
    float* __restrict__ o0, float* __restrict__ o1,
    float* __restrict__ o2, float* __restrict__ o3, int nrows)
{
    __shared__ __align__(16) short hb[128 * 136];
    __shared__ __align__(16) short wT[128 * 136];
    const int t = threadIdx.x, lane = t & 63, w = t >> 6;
    const int tx = lane & 15, tg = lane >> 4;
    const int m = blockIdx.x & 3, tile = blockIdx.x >> 2;
    const int n0 = tile * 128;
    for (int idx = t; idx < 128 * 32; idx += 256) {
        int r = idx >> 5, kq = idx & 31;
        int n = n0 + r;
        float4 hv;
        if (n < nrows) hv = *(const float4*)&A[(size_t)n * 128 + kq * 4];
        else { hv.x = hv.y = hv.z = hv.w = 0.0f; }
        uint2 pk = make_uint2((unsigned)f2bf(hv.x) | ((unsigned)f2bf(hv.y) << 16),
                              (unsigned)f2bf(hv.z) | ((unsigned)f2bf(hv.w) << 16));
        *(uint2*)&hb[r * 136 + kq * 4] = pk;
    }
    const u16* Wm = wnl + (size_t)m * 16384;
    for (int idx = t; idx < 128 * 16; idx += 256) {
        int c = idx >> 4, oc = idx & 15;
        *(float4*)&wT[c * 136 + oc * 8] = *(const float4*)&Wm[c * 128 + oc * 8];
    }
    __syncthreads();
    const f32x4 zf4 = { 0.0f, 0.0f, 0.0f, 0.0f };
    f32x4 acc[2][8];
    #pragma unroll
    for (int mt = 0; mt < 2; ++mt)
        #pragma unroll
        for (int nt = 0; nt < 8; ++nt) acc[mt][nt] = zf4;
    #pragma unroll
    for (int s = 0; s < 4; ++s) {
        bf16x8 af[2], bfr[8];
        #pragma unroll
        for (int mt = 0; mt < 2; ++mt)
            af[mt] = *(const bf16x8*)&wT[(w * 32 + mt * 16 + tx) * 136 + s * 32 + tg * 8];
        #pragma unroll
        for (int nt = 0; nt < 8; ++nt)
            bfr[nt] = *(const bf16x8*)&hb[(nt * 16 + tx) * 136 + s * 32 + tg * 8];
        #pragma unroll
        for (int mt = 0; mt < 2; ++mt)
            #pragma unroll
            for (int nt = 0; nt < 8; ++nt)
                acc[mt][nt] = __builtin_amdgcn_mfma_f32_16x16x32_bf16(af[mt], bfr[nt], acc[mt][nt], 0, 0, 0);
    }
    const float* Bm = (m == 0) ? b0 : (m == 1) ? b1p : (m == 2) ? b2p : b3p;
    float* Om = (m == 0) ? o0 : (m == 1) ? o1 : (m == 2) ? o2 : o3;
    #pragma unroll
    for (int mt = 0; mt < 2; ++mt) {
        int c0 = w * 32 + mt * 16 + tg * 4;
        float4 bb = *(const float4*)&Bm[c0];
        #pragma unroll
        for (int nt = 0; nt < 8; ++nt) {
            int n = n0 + nt * 16 + tx;
            if (n < nrows) {
                float4 ov;
                ov.x = acc[mt][nt][0] + bb.x; ov.y = acc[mt][nt][1] + bb.y;
                ov.z = acc[mt][nt][2] + bb.z; ov.w = acc[mt][nt][3] + bb.w;
                *(float4*)&Om[(size_t)n * 128 + c0] = ov;
            }
        }
    }
}

// ---------------- node-centric edge aggregation via ep table -------------------
// One wave per dst node; 2 channels/lane. Loop over CSR edges: lerp ep from tab,
// gather k/v[src], 8-lane shfl head logit, exp, online accumulate. No LDS/atomics.
// Writes t = ssp(num/den + skip) directly.
__global__ __launch_bounds__(256) void k_agg(
    const int* __restrict__ rowptr, const int* __restrict__ srcp,
    const float2* __restrict__ ifrac, const float* __restrict__ tab,
    const float* __restrict__ qn, const float* __restrict__ kn,
    const float* __restrict__ vn, const float* __restrict__ skip,
    float* __restrict__ tout)
{
    const int wid = (blockIdx.x * 256 + threadIdx.x) >> 6;   // node id
    if (wid >= NN) return;
    const int l = threadIdx.x & 63;
    const int c0 = l * 2;   // head = c0>>4 = l>>3; 8-lane groups per head
    const float2 q2 = *(const float2*)&qn[(size_t)wid * CC + c0];
    float nx = 0.0f, ny = 0.0f, den = 0.0f;
    const int eend = rowptr[wid + 1];
    for (int e = rowptr[wid]; e < eend; ++e) {
        int src = srcp[e];
        float2 u = ifrac[e];
        int i0 = __float_as_int(u.x);
        const float* tr = &tab[(size_t)i0 * CC + c0];
        float2 t0 = *(const float2*)tr;
        float2 t1 = *(const float2*)(tr + CC);
        float ex = fmaf(u.y, t1.x - t0.x, t0.x);
        float ey = fmaf(u.y, t1.y - t0.y, t0.y);
        float2 k2 = *(const float2*)&kn[(size_t)src * CC + c0];
        float2 v2 = *(const float2*)&vn[(size_t)src * CC + c0];
        float kex = k2.x + ex, key = k2.y + ey;
        float vex = v2.x + ex, vey = v2.y + ey;
        float p = q2.x * kex + q2.y * key;
        p += __shfl_xor(p, 1);
        p += __shfl_xor(p, 2);
        p += __shfl_xor(p, 4);          // sum over the head's 16 channels
        float w = __expf(p * 0.25f);    // scale = 1/sqrt(16); logits tiny, no max
        nx = fmaf(w, vex, nx);
        ny = fmaf(w, vey, ny);
        den += w;
    }
    const float2 sk = *(const float2*)&skip[(size_t)wid * CC + c0];
    float inv = 1.0f / (den + 1e-16f);
    float2 o;
    o.x = sspf(fmaf(nx, inv, sk.x));
    o.y = sspf(fmaf(ny, inv, sk.y));
    *(float2*)&tout[(size_t)wid * CC + c0] = o;
}

// ---------------- MFMA update: GEMM(wl) on t -> h += ---------------------------
__global__ __launch_bounds__(256) void k_upd_mfma(
    const float* __restrict__ tbuf, const u16* __restrict__ wlT,
    const float* __restrict__ Bias, float* __restrict__ h, int nrows)
{
    __shared__ __align__(16) short tb[128 * 136];
    __shared__ __align__(16) short wT[128 * 136];
    const int t = threadIdx.x, lane = t & 63, w = t >> 6;
    const int tx = lane & 15, tg = lane >> 4;
    const int n0 = blockIdx.x * 128;
    for (int idx = t; idx < 128 * 32; idx += 256) {
        int r = idx >> 5, kq = idx & 31;
        int n = n0 + r;
        float4 tv;
        if (n < nrows) tv = *(const float4*)&tbuf[(size_t)n * 128 + kq * 4];
        else { tv.x = tv.y = tv.z = tv.w = 0.0f; }
        uint2 pk = make_uint2((unsigned)f2bf(tv.x) | ((unsigned)f2bf(tv.y) << 16),
                              (unsigned)f2bf(tv.z) | ((unsigned)f2bf(tv.w) << 16));
        *(uint2*)&tb[r * 136 + kq * 4] = pk;
    }
    for (int idx = t; idx < 128 * 16; idx += 256) {
        int c = idx >> 4, oc = idx & 15;
        *(float4*)&wT[c * 136 + oc * 8] = *(const float4*)&wlT[c * 128 + oc * 8];
    }
    __syncthreads();
    const f32x4 zf4 = { 0.0f, 0.0f, 0.0f, 0.0f };
    f32x4 acc[2][8];
    #pragma unroll
    for (int mt = 0; mt < 2; ++mt)
        #pragma unroll
        for (int nt = 0; nt < 8; ++nt) acc[mt][nt] = zf4;
    #pragma unroll
    for (int s = 0; s < 4; ++s) {
        bf16x8 af[2], bfr[8];
        #pragma unroll
        for (int mt = 0; mt < 2; ++mt)
            af[mt] = *(const bf16x8*)&wT[(w * 32 + mt * 16 + tx) * 136 + s * 32 + tg * 8];
        #pragma unroll
        for (int nt = 0; nt < 8; ++nt)
            bfr[nt] = *(const bf16x8*)&tb[(nt * 16 + tx) * 136 + s * 32 + tg * 8];
        #pragma unroll
        for (int mt = 0; mt < 2; ++mt)
            #pragma unroll
            for (int nt = 0; nt < 8; ++nt)
                acc[mt][nt] = __builtin_amdgcn_mfma_f32_16x16x32_bf16(af[mt], bfr[nt], acc[mt][nt], 0, 0, 0);
    }
    #pragma unroll
    for (int mt = 0; mt < 2; ++mt) {
        int c0 = w * 32 + mt * 16 + tg * 4;
        float4 bb = *(const float4*)&Bias[c0];
        #pragma unroll
        for (int nt = 0; nt < 8; ++nt) {
            int n = n0 + nt * 16 + tx;
            if (n < nrows) {
                float4 hv = *(const float4*)&h[(size_t)n * 128 + c0];
                hv.x += acc[mt][nt][0] + bb.x; hv.y += acc[mt][nt][1] + bb.y;
                hv.z += acc[mt][nt][2] + bb.z; hv.w += acc[mt][nt][3] + bb.w;
                *(float4*)&h[(size_t)n * 128 + c0] = hv;
            }
        }
    }
}

// ---------------- output head ----------------
__global__ __launch_bounds__(64) void k_head(
    const float* __restrict__ h,
    const float* __restrict__ w1, const float* __restrict__ b1,
    const float* __restrict__ w2, const float* __restrict__ b2,
    float* __restrict__ out)
{
    const int n = blockIdx.x;
    const int j = threadIdx.x;
    float acc = 0.0f;
    for (int k = 0; k < CC; ++k)
        acc = fmaf(h[(size_t)n * CC + k], w1[k * 64 + j], acc);
    float m = sspf(acc + b1[j]);
    float o = m * w2[j];
    #pragma unroll
    for (int msk = 32; msk > 0; msk >>= 1) o += __shfl_xor(o, msk);
    if (j == 0) out[n] = o + b2[0];
}

extern "C" void kernel_launch(void* const* d_in, const int* in_sizes, int n_in,
                              void* d_out, int out_size, void* d_ws, size_t ws_size,
                              hipStream_t stream)
{
    const int*   z   = (const int*)d_in[0];
    const float* pos = (const float*)d_in[1];
    const int*   ei  = (const int*)d_in[2];
    const float* emb = (const float*)d_in[3];
    const float* w1  = (const float*)d_in[4];
    const float* b1  = (const float*)d_in[5];
    const float* w2  = (const float*)d_in[6];
    const float* b2  = (const float*)d_in[7];
    const float* wq  = (const float*)d_in[8];
    const float* bq  = (const float*)d_in[9];
    const float* wk  = (const float*)d_in[10];
    const float* bk  = (const float*)d_in[11];
    const float* wv  = (const float*)d_in[12];
    const float* bv  = (const float*)d_in[13];
    const float* we  = (const float*)d_in[14];
    const float* be  = (const float*)d_in[15];
    const float* wsk = (const float*)d_in[16];
    const float* bsk = (const float*)d_in[17];
    const float* wl  = (const float*)d_in[18];
    const float* bl  = (const float*)d_in[19];
    const float* wo1 = (const float*)d_in[20];
    const float* bo1 = (const float*)d_in[21];
    const float* wo2 = (const float*)d_in[22];
    const float* bo2 = (const float*)d_in[23];

    char* p = (char*)d_ws;
    auto alloc = [&](size_t bytes) -> void* {
        void* r = (void*)p; p += (bytes + 255) & ~(size_t)255; return r;
    };
    float* h    = (float*)alloc((size_t)NN * CC * 4);
    float* q    = (float*)alloc((size_t)NN * CC * 4);
    float* kk   = (float*)alloc((size_t)NN * CC * 4);
    float* vv   = (float*)alloc((size_t)NN * CC * 4);
    float* skip = (float*)alloc((size_t)NN * CC * 4);
    float* tbuf = (float*)alloc((size_t)NN * CC * 4);
    float* w23f = (float*)alloc((size_t)LL * FF * CC * 4);
    float* b23g = (float*)alloc((size_t)LL * CC * 4);
    float* tab  = (float*)alloc((size_t)LL * (NTAB + 1) * CC * 4);
    u16*   wn   = (u16*)alloc((size_t)LL * 5 * 128 * 128 * 2);
    int* count  = (int*)alloc((size_t)(NN + 1) * 4);
    int* rowptr = (int*)alloc((size_t)(NN + 1) * 4);
    int* cursor = (int*)alloc((size_t)NN * 4);
    int* srcp   = (int*)alloc((size_t)NE * 4);
    int* dstp   = (int*)alloc((size_t)NE * 4);
    float2* ifr = (float2*)alloc((size_t)NE * 8);

    k_zero<<<(NN + 255) / 256, 256, 0, stream>>>(count, NN);
    k_hist<<<(NE + 255) / 256, 256, 0, stream>>>(ei, count);
    k_scan<<<1, 1024, 0, stream>>>(count, rowptr, cursor);
    k_scatter<<<(NE + 255) / 256, 256, 0, stream>>>(ei, cursor, srcp, dstp);
    k_dist<<<(NE + 255) / 256, 256, 0, stream>>>(srcp, dstp, pos, ifr);
    k_hinit<<<(NN * CC + 255) / 256, 256, 0, stream>>>(z, emb, h);
    k_prep23<<<LL * 128, 128, 0, stream>>>(w2, we, w23f);
    k_prepb<<<LL, 128, 0, stream>>>(b2, we, be, b23g);
    k_prept<<<LL * (NTAB + 1), 128, 0, stream>>>(w1, b1, w23f, b23g, tab);
    k_prepn<<<(LL * 5 * 128 * 128 + 255) / 256, 256, 0, stream>>>(wq, wk, wv, wsk, wl, wn);

    const int NT = (NN + 127) / 128;   // 157
    for (int l = 0; l < LL; ++l) {
        const u16* wnl = wn + (size_t)l * 5 * 16384;
        k_qkvs_mfma<<<NT * 4, 256, 0, stream>>>(h, wnl,
            bq + l * CC, bk + l * CC, bv + l * CC, bsk + l * CC,
            q, kk, vv, skip, NN);
        k_agg<<<(NN * 64 + 255) / 256, 256, 0, stream>>>(rowptr, srcp, ifr,
            tab + (size_t)l * (NTAB + 1) * CC,
            q, kk, vv, skip, tbuf);
        k_upd_mfma<<<NT, 256, 0, stream>>>(tbuf,
            wnl + 4 * 16384, bl + l * CC, h, NN);
    }
    k_head<<<NN, 64, 0, stream>>>(h, wo1, bo1, wo2, bo2, (float*)d_out);
}

// Round 11
// 577.689 us; speedup vs baseline: 2.3154x; 1.1029x over previous
//
#include <hip/hip_runtime.h>

#define NN 20000
#define NE 640000
#define CC 128
#define HH 8
#define GG 50
#define FF 128
#define LL 3
#define NTAB 2048
#define DMAX 12.0f

typedef unsigned short u16;
typedef __attribute__((ext_vector_type(8))) short bf16x8;   // 8 bf16 = 4 VGPRs
typedef __attribute__((ext_vector_type(4))) float f32x4;

__device__ __forceinline__ u16 f2bf(float f) {
    union { float f; unsigned int i; } x; x.f = f;
    unsigned int r = x.i + 0x7fffu + ((x.i >> 16) & 1u);
    return (u16)(r >> 16);
}
// ShiftedSoftplus: softplus(x)-log2 via HW exp/log
__device__ __forceinline__ float sspf(float x) {
    return fmaxf(x, 0.0f) + __logf(1.0f + __expf(-fabsf(x))) - 0.69314718055994531f;
}

// ---------------- CSR build (sort edges by dst) ----------------
__global__ void k_zero(int* __restrict__ c, int n) {
    int i = blockIdx.x * 256 + threadIdx.x;
    if (i < n) c[i] = 0;
}

__global__ void k_hist(const int* __restrict__ ei, int* __restrict__ c) {
    int e = blockIdx.x * 256 + threadIdx.x;
    if (e < NE) atomicAdd(&c[ei[NE + e]], 1);
}

__global__ __launch_bounds__(1024) void k_scan(const int* __restrict__ cnt,
                                               int* __restrict__ rowptr,
                                               int* __restrict__ cursor) {
    __shared__ int sums[1024];
    const int t = threadIdx.x;
    int local[20];
    int base = t * 20;
    int s = 0;
    #pragma unroll
    for (int i = 0; i < 20; ++i) {
        int idx = base + i;
        int v = (idx < NN) ? cnt[idx] : 0;
        local[i] = s; s += v;
    }
    sums[t] = s;
    __syncthreads();
    for (int off = 1; off < 1024; off <<= 1) {
        int v = (t >= off) ? sums[t - off] : 0;
        __syncthreads();
        sums[t] += v;
        __syncthreads();
    }
    int excl = (t == 0) ? 0 : sums[t - 1];
    #pragma unroll
    for (int i = 0; i < 20; ++i) {
        int idx = base + i;
        if (idx < NN) { int r = excl + local[i]; rowptr[idx] = r; cursor[idx] = r; }
    }
    if (t == 1023) rowptr[NN] = sums[1023];
}

__global__ void k_scatter(const int* __restrict__ ei, int* __restrict__ cursor,
                          int* __restrict__ srcp, int* __restrict__ dstp) {
    int e = blockIdx.x * 256 + threadIdx.x;
    if (e >= NE) return;
    int s = ei[e], d = ei[NE + e];
    int pp = atomicAdd(&cursor[d], 1);
    srcp[pp] = s; dstp[pp] = d;
}

__global__ void k_hinit(const int* __restrict__ z, const float* __restrict__ emb,
                        float* __restrict__ h) {
    int i = blockIdx.x * 256 + threadIdx.x;
    if (i < NN * CC) h[i] = emb[z[i >> 7] * CC + (i & 127)];
}

// per-edge (i0, frac) for the ep table; d is layer-invariant
__global__ void k_dist(const int* __restrict__ srcp, const int* __restrict__ dstp,
                       const float* __restrict__ pos, float2* __restrict__ ifrac) {
    int e = blockIdx.x * 256 + threadIdx.x;
    if (e >= NE) return;
    int a = srcp[e], b = dstp[e];
    float dx = pos[b * 3 + 0] - pos[a * 3 + 0];
    float dy = pos[b * 3 + 1] - pos[a * 3 + 1];
    float dz = pos[b * 3 + 2] - pos[a * 3 + 2];
    float d = sqrtf(dx * dx + dy * dy + dz * dz + 1e-12f);
    float t = fminf(d * ((float)NTAB / DMAX), (float)NTAB - 1e-3f);
    int i0 = (int)t;
    float2 u; u.x = __int_as_float(i0); u.y = t - (float)i0;
    ifrac[e] = u;
}

// ---------------- weight prep (once per call) ----------------
// W23f[l][k][cp] = sum_c w2[l][k][c] * we[l][c][cp]  (fp32)
__global__ __launch_bounds__(128) void k_prep23(const float* __restrict__ w2,
                                                const float* __restrict__ we,
                                                float* __restrict__ w23f) {
    int l = blockIdx.x >> 7, k = blockIdx.x & 127;
    int cp = threadIdx.x;
    float s = 0.0f;
    for (int c = 0; c < FF; ++c)
        s = fmaf(w2[((size_t)l * FF + k) * FF + c], we[((size_t)l * FF + c) * CC + cp], s);
    w23f[((size_t)l * FF + k) * CC + cp] = s;
}

// b23[l][cp] = be[l][cp] + sum_k b2[l][k] * we[l][k][cp]
__global__ __launch_bounds__(128) void k_prepb(const float* __restrict__ b2,
                                               const float* __restrict__ we,
                                               const float* __restrict__ be,
                                               float* __restrict__ b23g) {
    int l = blockIdx.x;
    int cp = threadIdx.x;
    float s = be[l * CC + cp];
    for (int k = 0; k < FF; ++k)
        s = fmaf(b2[l * FF + k], we[((size_t)l * FF + k) * CC + cp], s);
    b23g[l * CC + cp] = s;
}

// ep table: tab[l][i][cp] = MLP(gauss(d_i)) exact fp32, d_i = i*DMAX/NTAB, i in [0,NTAB]
__global__ __launch_bounds__(128) void k_prept(const float* __restrict__ w1,
                                               const float* __restrict__ b1,
                                               const float* __restrict__ w23f,
                                               const float* __restrict__ b23g,
                                               float* __restrict__ tab) {
    const int l = blockIdx.x / (NTAB + 1);
    const int i = blockIdx.x % (NTAB + 1);
    const int c = threadIdx.x;
    __shared__ float attr[GG];
    __shared__ float hid[FF];
    const float STEP = 10.0f / 49.0f;
    const float COEF = -0.5f / (STEP * STEP);
    float d = (float)i * (DMAX / (float)NTAB);
    if (c < GG) { float df = d - STEP * (float)c; attr[c] = __expf(COEF * df * df); }
    __syncthreads();
    float s = b1[l * FF + c];
    for (int g = 0; g < GG; ++g)
        s = fmaf(attr[g], w1[((size_t)l * GG + g) * FF + c], s);
    hid[c] = sspf(s);
    __syncthreads();
    float o = b23g[l * CC + c];
    for (int k = 0; k < FF; ++k)
        o = fmaf(hid[k], w23f[((size_t)l * FF + k) * CC + c], o);
    tab[((size_t)l * (NTAB + 1) + i) * CC + c] = o;
}

// node weights: wn[((l*5+m)*128 + c)*128 + k] = bf16(W_m[l][k][c]); m: q,k,v,skip,l
__global__ void k_prepn(const float* __restrict__ wq, const float* __restrict__ wk,
                        const float* __restrict__ wv, const float* __restrict__ wsk,
                        const float* __restrict__ wl, u16* __restrict__ wn) {
    int i = blockIdx.x * 256 + threadIdx.x;
    if (i >= LL * 5 * 128 * 128) return;
    int k = i & 127, c = (i >> 7) & 127;
    int lm = i >> 14; int m = lm % 5, l = lm / 5;
    const float* W = (m == 0) ? wq : (m == 1) ? wk : (m == 2) ? wv : (m == 3) ? wsk : wl;
    wn[i] = f2bf(W[((size_t)l * 128 + k) * 128 + c]);
}

// ---------------- MFMA node GEMM: q/k/v/skip (grid = tiles*4, one matrix each) --
__global__ __launch_bounds__(256) void k_qkvs_mfma(
    const float* __restrict__ A, const u16* __restrict__ wnl,
    const float* __restrict__ b0, const float* __restrict__ b1p,
    const float* __restrict__ b2p, const float* __restrict__ b3p,
    float* __restrict__ o0, float* __restrict__ o1,
    float* __restrict__ o2, float* __restrict__ o3, int nrows)
{
    __shared__ __align__(16) short hb[128 * 136];
    __shared__ __align__(16) short wT[128 * 136];
    const int t = threadIdx.x, lane = t & 63, w = t >> 6;
    const int tx = lane & 15, tg = lane >> 4;
    const int m = blockIdx.x & 3, tile = blockIdx.x >> 2;
    const int n0 = tile * 128;
    for (int idx = t; idx < 128 * 32; idx += 256) {
        int r = idx >> 5, kq = idx & 31;
        int n = n0 + r;
        float4 hv;
        if (n < nrows) hv = *(const float4*)&A[(size_t)n * 128 + kq * 4];
        else { hv.x = hv.y = hv.z = hv.w = 0.0f; }
        uint2 pk = make_uint2((unsigned)f2bf(hv.x) | ((unsigned)f2bf(hv.y) << 16),
                              (unsigned)f2bf(hv.z) | ((unsigned)f2bf(hv.w) << 16));
        *(uint2*)&hb[r * 136 + kq * 4] = pk;
    }
    const u16* Wm = wnl + (size_t)m * 16384;
    for (int idx = t; idx < 128 * 16; idx += 256) {
        int c = idx >> 4, oc = idx & 15;
        *(float4*)&wT[c * 136 + oc * 8] = *(const float4*)&Wm[c * 128 + oc * 8];
    }
    __syncthreads();
    const f32x4 zf4 = { 0.0f, 0.0f, 0.0f, 0.0f };
    f32x4 acc[2][8];
    #pragma unroll
    for (int mt = 0; mt < 2; ++mt)
        #pragma unroll
        for (int nt = 0; nt < 8; ++nt) acc[mt][nt] = zf4;
    #pragma unroll
    for (int s = 0; s < 4; ++s) {
        bf16x8 af[2], bfr[8];
        #pragma unroll
        for (int mt = 0; mt < 2; ++mt)
            af[mt] = *(const bf16x8*)&wT[(w * 32 + mt * 16 + tx) * 136 + s * 32 + tg * 8];
        #pragma unroll
        for (int nt = 0; nt < 8; ++nt)
            bfr[nt] = *(const bf16x8*)&hb[(nt * 16 + tx) * 136 + s * 32 + tg * 8];
        #pragma unroll
        for (int mt = 0; mt < 2; ++mt)
            #pragma unroll
            for (int nt = 0; nt < 8; ++nt)
                acc[mt][nt] = __builtin_amdgcn_mfma_f32_16x16x32_bf16(af[mt], bfr[nt], acc[mt][nt], 0, 0, 0);
    }
    const float* Bm = (m == 0) ? b0 : (m == 1) ? b1p : (m == 2) ? b2p : b3p;
    float* Om = (m == 0) ? o0 : (m == 1) ? o1 : (m == 2) ? o2 : o3;
    #pragma unroll
    for (int mt = 0; mt < 2; ++mt) {
        int c0 = w * 32 + mt * 16 + tg * 4;
        float4 bb = *(const float4*)&Bm[c0];
        #pragma unroll
        for (int nt = 0; nt < 8; ++nt) {
            int n = n0 + nt * 16 + tx;
            if (n < nrows) {
                float4 ov;
                ov.x = acc[mt][nt][0] + bb.x; ov.y = acc[mt][nt][1] + bb.y;
                ov.z = acc[mt][nt][2] + bb.z; ov.w = acc[mt][nt][3] + bb.w;
                *(float4*)&Om[(size_t)n * 128 + c0] = ov;
            }
        }
    }
}

// ---------------- node-centric edge aggregation via ep table -------------------
// One wave per dst node; 2 channels/lane. 4-edge batched pipeline: load indices,
// issue all 16 gathers, then compute in edge order (bitwise-identical result).
__global__ __launch_bounds__(256) void k_agg(
    const int* __restrict__ rowptr, const int* __restrict__ srcp,
    const float2* __restrict__ ifrac, const float* __restrict__ tab,
    const float* __restrict__ qn, const float* __restrict__ kn,
    const float* __restrict__ vn, const float* __restrict__ skip,
    float* __restrict__ tout)
{
    const int wid = (blockIdx.x * 256 + threadIdx.x) >> 6;   // node id
    if (wid >= NN) return;
    const int l = threadIdx.x & 63;
    const int c0 = l * 2;   // head = l>>3; 8-lane groups per head
    const float2 q2 = *(const float2*)&qn[(size_t)wid * CC + c0];
    float nx = 0.0f, ny = 0.0f, den = 0.0f;
    const int estart = rowptr[wid], eend = rowptr[wid + 1];

    // one edge: all inputs already in registers
    auto edge = [&](float2 u, float2 t0, float2 t1, float2 k2, float2 v2) {
        float ex = fmaf(u.y, t1.x - t0.x, t0.x);
        float ey = fmaf(u.y, t1.y - t0.y, t0.y);
        float kex = k2.x + ex, key = k2.y + ey;
        float vex = v2.x + ex, vey = v2.y + ey;
        float p = q2.x * kex + q2.y * key;
        p += __shfl_xor(p, 1);
        p += __shfl_xor(p, 2);
        p += __shfl_xor(p, 4);          // sum over the head's 16 channels
        float w = __expf(p * 0.25f);    // scale = 1/sqrt(16); logits tiny, no max
        nx = fmaf(w, vex, nx);
        ny = fmaf(w, vey, ny);
        den += w;
    };

    int e = estart;
    for (; e + 4 <= eend; e += 4) {
        // batch-load indices (8 independent loads)
        int s0 = srcp[e], s1 = srcp[e + 1], s2 = srcp[e + 2], s3 = srcp[e + 3];
        float2 u0 = ifrac[e], u1 = ifrac[e + 1], u2 = ifrac[e + 2], u3 = ifrac[e + 3];
        // issue all 16 gathers back-to-back (fully independent)
        const float* tr0 = &tab[(size_t)__float_as_int(u0.x) * CC + c0];
        const float* tr1 = &tab[(size_t)__float_as_int(u1.x) * CC + c0];
        const float* tr2 = &tab[(size_t)__float_as_int(u2.x) * CC + c0];
        const float* tr3 = &tab[(size_t)__float_as_int(u3.x) * CC + c0];
        float2 t00 = *(const float2*)tr0;
        float2 t01 = *(const float2*)(tr0 + CC);
        float2 t10 = *(const float2*)tr1;
        float2 t11 = *(const float2*)(tr1 + CC);
        float2 t20 = *(const float2*)tr2;
        float2 t21 = *(const float2*)(tr2 + CC);
        float2 t30 = *(const float2*)tr3;
        float2 t31 = *(const float2*)(tr3 + CC);
        float2 ka0 = *(const float2*)&kn[(size_t)s0 * CC + c0];
        float2 ka1 = *(const float2*)&kn[(size_t)s1 * CC + c0];
        float2 ka2 = *(const float2*)&kn[(size_t)s2 * CC + c0];
        float2 ka3 = *(const float2*)&kn[(size_t)s3 * CC + c0];
        float2 va0 = *(const float2*)&vn[(size_t)s0 * CC + c0];
        float2 va1 = *(const float2*)&vn[(size_t)s1 * CC + c0];
        float2 va2 = *(const float2*)&vn[(size_t)s2 * CC + c0];
        float2 va3 = *(const float2*)&vn[(size_t)s3 * CC + c0];
        // compute in edge order -> accumulation order unchanged
        edge(u0, t00, t01, ka0, va0);
        edge(u1, t10, t11, ka1, va1);
        edge(u2, t20, t21, ka2, va2);
        edge(u3, t30, t31, ka3, va3);
    }
    for (; e < eend; ++e) {
        int src = srcp[e];
        float2 u = ifrac[e];
        const float* tr = &tab[(size_t)__float_as_int(u.x) * CC + c0];
        float2 t0 = *(const float2*)tr;
        float2 t1 = *(const float2*)(tr + CC);
        float2 k2 = *(const float2*)&kn[(size_t)src * CC + c0];
        float2 v2 = *(const float2*)&vn[(size_t)src * CC + c0];
        edge(u, t0, t1, k2, v2);
    }

    const float2 sk = *(const float2*)&skip[(size_t)wid * CC + c0];
    float inv = 1.0f / (den + 1e-16f);
    float2 o;
    o.x = sspf(fmaf(nx, inv, sk.x));
    o.y = sspf(fmaf(ny, inv, sk.y));
    *(float2*)&tout[(size_t)wid * CC + c0] = o;
}

// ---------------- MFMA update: GEMM(wl) on t -> h += ---------------------------
__global__ __launch_bounds__(256) void k_upd_mfma(
    const float* __restrict__ tbuf, const u16* __restrict__ wlT,
    const float* __restrict__ Bias, float* __restrict__ h, int nrows)
{
    __shared__ __align__(16) short tb[128 * 136];
    __shared__ __align__(16) short wT[128 * 136];
    const int t = threadIdx.x, lane = t & 63, w = t >> 6;
    const int tx = lane & 15, tg = lane >> 4;
    const int n0 = blockIdx.x * 128;
    for (int idx = t; idx < 128 * 32; idx += 256) {
        int r = idx >> 5, kq = idx & 31;
        int n = n0 + r;
        float4 tv;
        if (n < nrows) tv = *(const float4*)&tbuf[(size_t)n * 128 + kq * 4];
        else { tv.x = tv.y = tv.z = tv.w = 0.0f; }
        uint2 pk = make_uint2((unsigned)f2bf(tv.x) | ((unsigned)f2bf(tv.y) << 16),
                              (unsigned)f2bf(tv.z) | ((unsigned)f2bf(tv.w) << 16));
        *(uint2*)&tb[r * 136 + kq * 4] = pk;
    }
    for (int idx = t; idx < 128 * 16; idx += 256) {
        int c = idx >> 4, oc = idx & 15;
        *(float4*)&wT[c * 136 + oc * 8] = *(const float4*)&wlT[c * 128 + oc * 8];
    }
    __syncthreads();
    const f32x4 zf4 = { 0.0f, 0.0f, 0.0f, 0.0f };
    f32x4 acc[2][8];
    #pragma unroll
    for (int mt = 0; mt < 2; ++mt)
        #pragma unroll
        for (int nt = 0; nt < 8; ++nt) acc[mt][nt] = zf4;
    #pragma unroll
    for (int s = 0; s < 4; ++s) {
        bf16x8 af[2], bfr[8];
        #pragma unroll
        for (int mt = 0; mt < 2; ++mt)
            af[mt] = *(const bf16x8*)&wT[(w * 32 + mt * 16 + tx) * 136 + s * 32 + tg * 8];
        #pragma unroll
        for (int nt = 0; nt < 8; ++nt)
            bfr[nt] = *(const bf16x8*)&tb[(nt * 16 + tx) * 136 + s * 32 + tg * 8];
        #pragma unroll
        for (int mt = 0; mt < 2; ++mt)
            #pragma unroll
            for (int nt = 0; nt < 8; ++nt)
                acc[mt][nt] = __builtin_amdgcn_mfma_f32_16x16x32_bf16(af[mt], bfr[nt], acc[mt][nt], 0, 0, 0);
    }
    #pragma unroll
    for (int mt = 0; mt < 2; ++mt) {
        int c0 = w * 32 + mt * 16 + tg * 4;
        float4 bb = *(const float4*)&Bias[c0];
        #pragma unroll
        for (int nt = 0; nt < 8; ++nt) {
            int n = n0 + nt * 16 + tx;
            if (n < nrows) {
                float4 hv = *(const float4*)&h[(size_t)n * 128 + c0];
                hv.x += acc[mt][nt][0] + bb.x; hv.y += acc[mt][nt][1] + bb.y;
                hv.z += acc[mt][nt][2] + bb.z; hv.w += acc[mt][nt][3] + bb.w;
                *(float4*)&h[(size_t)n * 128 + c0] = hv;
            }
        }
    }
}

// ---------------- output head ----------------
__global__ __launch_bounds__(64) void k_head(
    const float* __restrict__ h,
    const float* __restrict__ w1, const float* __restrict__ b1,
    const float* __restrict__ w2, const float* __restrict__ b2,
    float* __restrict__ out)
{
    const int n = blockIdx.x;
    const int j = threadIdx.x;
    float acc = 0.0f;
    for (int k = 0; k < CC; ++k)
        acc = fmaf(h[(size_t)n * CC + k], w1[k * 64 + j], acc);
    float m = sspf(acc + b1[j]);
    float o = m * w2[j];
    #pragma unroll
    for (int msk = 32; msk > 0; msk >>= 1) o += __shfl_xor(o, msk);
    if (j == 0) out[n] = o + b2[0];
}

extern "C" void kernel_launch(void* const* d_in, const int* in_sizes, int n_in,
                              void* d_out, int out_size, void* d_ws, size_t ws_size,
                              hipStream_t stream)
{
    const int*   z   = (const int*)d_in[0];
    const float* pos = (const float*)d_in[1];
    const int*   ei  = (const int*)d_in[2];
    const float* emb = (const float*)d_in[3];
    const float* w1  = (const float*)d_in[4];
    const float* b1  = (const float*)d_in[5];
    const float* w2  = (const float*)d_in[6];
    const float* b2  = (const float*)d_in[7];
    const float* wq  = (const float*)d_in[8];
    const float* bq  = (const float*)d_in[9];
    const float* wk  = (const float*)d_in[10];
    const float* bk  = (const float*)d_in[11];
    const float* wv  = (const float*)d_in[12];
    const float* bv  = (const float*)d_in[13];
    const float* we  = (const float*)d_in[14];
    const float* be  = (const float*)d_in[15];
    const float* wsk = (const float*)d_in[16];
    const float* bsk = (const float*)d_in[17];
    const float* wl  = (const float*)d_in[18];
    const float* bl  = (const float*)d_in[19];
    const float* wo1 = (const float*)d_in[20];
    const float* bo1 = (const float*)d_in[21];
    const float* wo2 = (const float*)d_in[22];
    const float* bo2 = (const float*)d_in[23];

    char* p = (char*)d_ws;
    auto alloc = [&](size_t bytes) -> void* {
        void* r = (void*)p; p += (bytes + 255) & ~(size_t)255; return r;
    };
    float* h    = (float*)alloc((size_t)NN * CC * 4);
    float* q    = (float*)alloc((size_t)NN * CC * 4);
    float* kk   = (float*)alloc((size_t)NN * CC * 4);
    float* vv   = (float*)alloc((size_t)NN * CC * 4);
    float* skip = (float*)alloc((size_t)NN * CC * 4);
    float* tbuf = (float*)alloc((size_t)NN * CC * 4);
    float* w23f = (float*)alloc((size_t)LL * FF * CC * 4);
    float* b23g = (float*)alloc((size_t)LL * CC * 4);
    float* tab  = (float*)alloc((size_t)LL * (NTAB + 1) * CC * 4);
    u16*   wn   = (u16*)alloc((size_t)LL * 5 * 128 * 128 * 2);
    int* count  = (int*)alloc((size_t)(NN + 1) * 4);
    int* rowptr = (int*)alloc((size_t)(NN + 1) * 4);
    int* cursor = (int*)alloc((size_t)NN * 4);
    int* srcp   = (int*)alloc((size_t)NE * 4);
    int* dstp   = (int*)alloc((size_t)NE * 4);
    float2* ifr = (float2*)alloc((size_t)NE * 8);

    k_zero<<<(NN + 255) / 256, 256, 0, stream>>>(count, NN);
    k_hist<<<(NE + 255) / 256, 256, 0, stream>>>(ei, count);
    k_scan<<<1, 1024, 0, stream>>>(count, rowptr, cursor);
    k_scatter<<<(NE + 255) / 256, 256, 0, stream>>>(ei, cursor, srcp, dstp);
    k_dist<<<(NE + 255) / 256, 256, 0, stream>>>(srcp, dstp, pos, ifr);
    k_hinit<<<(NN * CC + 255) / 256, 256, 0, stream>>>(z, emb, h);
    k_prep23<<<LL * 128, 128, 0, stream>>>(w2, we, w23f);
    k_prepb<<<LL, 128, 0, stream>>>(b2, we, be, b23g);
    k_prept<<<LL * (NTAB + 1), 128, 0, stream>>>(w1, b1, w23f, b23g, tab);
    k_prepn<<<(LL * 5 * 128 * 128 + 255) / 256, 256, 0, stream>>>(wq, wk, wv, wsk, wl, wn);

    const int NT = (NN + 127) / 128;   // 157
    for (int l = 0; l < LL; ++l) {
        const u16* wnl = wn + (size_t)l * 5 * 16384;
        k_qkvs_mfma<<<NT * 4, 256, 0, stream>>>(h, wnl,
            bq + l * CC, bk + l * CC, bv + l * CC, bsk + l * CC,
            q, kk, vv, skip, NN);
        k_agg<<<(NN * 64 + 255) / 256, 256, 0, stream>>>(rowptr, srcp, ifr,
            tab + (size_t)l * (NTAB + 1) * CC,
            q, kk, vv, skip, tbuf);
        k_upd_mfma<<<NT, 256, 0, stream>>>(tbuf,
            wnl + 4 * 16384, bl + l * CC, h, NN);
    }
    k_head<<<NN, 64, 0, stream>>>(h, wo1, bo1, wo2, bo2, (float*)d_out);
}

// Round 13
// 479.506 us; speedup vs baseline: 2.7896x; 1.2048x over previous
//
#include <hip/hip_runtime.h>

#define NN 20000
#define NE 640000
#define CC 128
#define HH 8
#define GG 50
#define FF 128
#define LL 3
#define NTAB 2048
#define DMAX 12.0f

typedef unsigned short u16;
typedef __attribute__((ext_vector_type(8))) short bf16x8;   // 8 bf16 = 4 VGPRs
typedef __attribute__((ext_vector_type(4))) float f32x4;

__device__ __forceinline__ u16 f2bf(float f) {
    union { float f; unsigned int i; } x; x.f = f;
    unsigned int r = x.i + 0x7fffu + ((x.i >> 16) & 1u);
    return (u16)(r >> 16);
}
// ShiftedSoftplus: softplus(x)-log2 via HW exp/log
__device__ __forceinline__ float sspf(float x) {
    return fmaxf(x, 0.0f) + __logf(1.0f + __expf(-fabsf(x))) - 0.69314718055994531f;
}

// ---------------- CSR build (sort edges by dst) ----------------
__global__ void k_zero(int* __restrict__ c, int n) {
    int i = blockIdx.x * 256 + threadIdx.x;
    if (i < n) c[i] = 0;
}

__global__ void k_hist(const int* __restrict__ ei, int* __restrict__ c) {
    int e = blockIdx.x * 256 + threadIdx.x;
    if (e < NE) atomicAdd(&c[ei[NE + e]], 1);
}

__global__ __launch_bounds__(1024) void k_scan(const int* __restrict__ cnt,
                                               int* __restrict__ rowptr,
                                               int* __restrict__ cursor) {
    __shared__ int sums[1024];
    const int t = threadIdx.x;
    int local[20];
    int base = t * 20;
    int s = 0;
    #pragma unroll
    for (int i = 0; i < 20; ++i) {
        int idx = base + i;
        int v = (idx < NN) ? cnt[idx] : 0;
        local[i] = s; s += v;
    }
    sums[t] = s;
    __syncthreads();
    for (int off = 1; off < 1024; off <<= 1) {
        int v = (t >= off) ? sums[t - off] : 0;
        __syncthreads();
        sums[t] += v;
        __syncthreads();
    }
    int excl = (t == 0) ? 0 : sums[t - 1];
    #pragma unroll
    for (int i = 0; i < 20; ++i) {
        int idx = base + i;
        if (idx < NN) { int r = excl + local[i]; rowptr[idx] = r; cursor[idx] = r; }
    }
    if (t == 1023) rowptr[NN] = sums[1023];
}

__global__ void k_scatter(const int* __restrict__ ei, int* __restrict__ cursor,
                          int* __restrict__ srcp, int* __restrict__ dstp) {
    int e = blockIdx.x * 256 + threadIdx.x;
    if (e >= NE) return;
    int s = ei[e], d = ei[NE + e];
    int pp = atomicAdd(&cursor[d], 1);
    srcp[pp] = s; dstp[pp] = d;
}

__global__ void k_hinit(const int* __restrict__ z, const float* __restrict__ emb,
                        float* __restrict__ h) {
    int i = blockIdx.x * 256 + threadIdx.x;
    if (i < NN * CC) h[i] = emb[z[i >> 7] * CC + (i & 127)];
}

// per-edge record: {src, i0<<16 | frac16}; d is layer-invariant
__global__ void k_erec(const int* __restrict__ srcp, const int* __restrict__ dstp,
                       const float* __restrict__ pos, int2* __restrict__ erec) {
    int e = blockIdx.x * 256 + threadIdx.x;
    if (e >= NE) return;
    int a = srcp[e], b = dstp[e];
    float dx = pos[b * 3 + 0] - pos[a * 3 + 0];
    float dy = pos[b * 3 + 1] - pos[a * 3 + 1];
    float dz = pos[b * 3 + 2] - pos[a * 3 + 2];
    float d = sqrtf(dx * dx + dy * dy + dz * dz + 1e-12f);
    float t = fminf(d * ((float)NTAB / DMAX), (float)NTAB - 1e-3f);
    int i0 = (int)t;
    int fr = (int)((t - (float)i0) * 65536.0f);
    fr = min(fr, 65535);
    int2 r; r.x = a; r.y = (i0 << 16) | fr;
    erec[e] = r;
}

// ---------------- weight prep (once per call) ----------------
// W23f[l][k][cp] = sum_c w2[l][k][c] * we[l][c][cp]  (fp32)
__global__ __launch_bounds__(128) void k_prep23(const float* __restrict__ w2,
                                                const float* __restrict__ we,
                                                float* __restrict__ w23f) {
    int l = blockIdx.x >> 7, k = blockIdx.x & 127;
    int cp = threadIdx.x;
    float s = 0.0f;
    for (int c = 0; c < FF; ++c)
        s = fmaf(w2[((size_t)l * FF + k) * FF + c], we[((size_t)l * FF + c) * CC + cp], s);
    w23f[((size_t)l * FF + k) * CC + cp] = s;
}

// b23[l][cp] = be[l][cp] + sum_k b2[l][k] * we[l][k][cp]
__global__ __launch_bounds__(128) void k_prepb(const float* __restrict__ b2,
                                               const float* __restrict__ we,
                                               const float* __restrict__ be,
                                               float* __restrict__ b23g) {
    int l = blockIdx.x;
    int cp = threadIdx.x;
    float s = be[l * CC + cp];
    for (int k = 0; k < FF; ++k)
        s = fmaf(b2[l * FF + k], we[((size_t)l * FF + k) * CC + cp], s);
    b23g[l * CC + cp] = s;
}

// ep table: tab[l][i][cp] = MLP(gauss(d_i)) exact fp32, d_i = i*DMAX/NTAB, i in [0,NTAB]
__global__ __launch_bounds__(128) void k_prept(const float* __restrict__ w1,
                                               const float* __restrict__ b1,
                                               const float* __restrict__ w23f,
                                               const float* __restrict__ b23g,
                                               float* __restrict__ tab) {
    const int l = blockIdx.x / (NTAB + 1);
    const int i = blockIdx.x % (NTAB + 1);
    const int c = threadIdx.x;
    __shared__ float attr[GG];
    __shared__ float hid[FF];
    const float STEP = 10.0f / 49.0f;
    const float COEF = -0.5f / (STEP * STEP);
    float d = (float)i * (DMAX / (float)NTAB);
    if (c < GG) { float df = d - STEP * (float)c; attr[c] = __expf(COEF * df * df); }
    __syncthreads();
    float s = b1[l * FF + c];
    for (int g = 0; g < GG; ++g)
        s = fmaf(attr[g], w1[((size_t)l * GG + g) * FF + c], s);
    hid[c] = sspf(s);
    __syncthreads();
    float o = b23g[l * CC + c];
    for (int k = 0; k < FF; ++k)
        o = fmaf(hid[k], w23f[((size_t)l * FF + k) * CC + c], o);
    tab[((size_t)l * (NTAB + 1) + i) * CC + c] = o;
}

// pack table pairs: tabp[l][i][(c>>1)*4 + (c&1)] = tab[i][c]; [+2] = tab[i+1][c]
__global__ void k_packt(const float* __restrict__ tab, float* __restrict__ tabp) {
    int idx = blockIdx.x * 256 + threadIdx.x;
    if (idx >= LL * NTAB * 128) return;
    int c = idx & 127;
    int i = (idx >> 7) % NTAB;
    int l = idx / (NTAB * 128);
    float v0 = tab[((size_t)l * (NTAB + 1) + i) * CC + c];
    float v1 = tab[((size_t)l * (NTAB + 1) + i + 1) * CC + c];
    size_t base = ((size_t)l * NTAB + i) * 256 + (size_t)(c >> 1) * 4 + (c & 1);
    tabp[base] = v0;
    tabp[base + 2] = v1;
}

// node weights: wn[((l*5+m)*128 + c)*128 + k] = bf16(W_m[l][k][c]); m: q,k,v,skip,l
__global__ void k_prepn(const float* __restrict__ wq, const float* __restrict__ wk,
                        const float* __restrict__ wv, const float* __restrict__ wsk,
                        const float* __restrict__ wl, u16* __restrict__ wn) {
    int i = blockIdx.x * 256 + threadIdx.x;
    if (i >= LL * 5 * 128 * 128) return;
    int k = i & 127, c = (i >> 7) & 127;
    int lm = i >> 14; int m = lm % 5, l = lm / 5;
    const float* W = (m == 0) ? wq : (m == 1) ? wk : (m == 2) ? wv : (m == 3) ? wsk : wl;
    wn[i] = f2bf(W[((size_t)l * 128 + k) * 128 + c]);
}

// ---------------- MFMA node GEMM: q/k/v/skip (grid = tiles*4, one matrix each) --
// A-fragments (weights) loaded straight from L2 (no LDS staging).
// m==0 -> q (f32); m==1 -> k pairs into kvw; m==2 -> v pairs; m==3 -> skip (f32).
// kvw layout: per node 128 u32 (64 uint2): u32[n*128 + c] = k-pair(c,c+1) for even c,
//             u32[n*128 + c + 1] = v-pair(c,c+1).
__global__ __launch_bounds__(256) void k_qkvs_mfma(
    const float* __restrict__ A, const u16* __restrict__ wnl,
    const float* __restrict__ b0, const float* __restrict__ b1p,
    const float* __restrict__ b2p, const float* __restrict__ b3p,
    float* __restrict__ o_q, unsigned int* __restrict__ kvw,
    float* __restrict__ o_skip, int nrows)
{
    __shared__ __align__(16) short hb[128 * 136];
    const int t = threadIdx.x, lane = t & 63, w = t >> 6;
    const int tx = lane & 15, tg = lane >> 4;
    const int m = blockIdx.x & 3, tile = blockIdx.x >> 2;
    const int n0 = tile * 128;
    for (int idx = t; idx < 128 * 32; idx += 256) {
        int r = idx >> 5, kq = idx & 31;
        int n = n0 + r;
        float4 hv;
        if (n < nrows) hv = *(const float4*)&A[(size_t)n * 128 + kq * 4];
        else { hv.x = hv.y = hv.z = hv.w = 0.0f; }
        uint2 pk = make_uint2((unsigned)f2bf(hv.x) | ((unsigned)f2bf(hv.y) << 16),
                              (unsigned)f2bf(hv.z) | ((unsigned)f2bf(hv.w) << 16));
        *(uint2*)&hb[r * 136 + kq * 4] = pk;
    }
    __syncthreads();
    const u16* Wm = wnl + (size_t)m * 16384;
    const f32x4 zf4 = { 0.0f, 0.0f, 0.0f, 0.0f };
    f32x4 acc[2][8];
    #pragma unroll
    for (int mt = 0; mt < 2; ++mt)
        #pragma unroll
        for (int nt = 0; nt < 8; ++nt) acc[mt][nt] = zf4;
    #pragma unroll
    for (int s = 0; s < 4; ++s) {
        bf16x8 af[2], bfr[8];
        #pragma unroll
        for (int mt = 0; mt < 2; ++mt)
            af[mt] = *(const bf16x8*)&Wm[(size_t)(w * 32 + mt * 16 + tx) * 128 + s * 32 + tg * 8];
        #pragma unroll
        for (int nt = 0; nt < 8; ++nt)
            bfr[nt] = *(const bf16x8*)&hb[(nt * 16 + tx) * 136 + s * 32 + tg * 8];
        #pragma unroll
        for (int mt = 0; mt < 2; ++mt)
            #pragma unroll
            for (int nt = 0; nt < 8; ++nt)
                acc[mt][nt] = __builtin_amdgcn_mfma_f32_16x16x32_bf16(af[mt], bfr[nt], acc[mt][nt], 0, 0, 0);
    }
    const float* Bm = (m == 0) ? b0 : (m == 1) ? b1p : (m == 2) ? b2p : b3p;
    if (m == 0 || m == 3) {
        float* Om = (m == 0) ? o_q : o_skip;
        #pragma unroll
        for (int mt = 0; mt < 2; ++mt) {
            int c0 = w * 32 + mt * 16 + tg * 4;
            float4 bb = *(const float4*)&Bm[c0];
            #pragma unroll
            for (int nt = 0; nt < 8; ++nt) {
                int n = n0 + nt * 16 + tx;
                if (n < nrows) {
                    float4 ov;
                    ov.x = acc[mt][nt][0] + bb.x; ov.y = acc[mt][nt][1] + bb.y;
                    ov.z = acc[mt][nt][2] + bb.z; ov.w = acc[mt][nt][3] + bb.w;
                    *(float4*)&Om[(size_t)n * 128 + c0] = ov;
                }
            }
        }
    } else {
        const int off = (m == 1) ? 0 : 1;   // k-pairs at even u32 slots, v at odd
        #pragma unroll
        for (int mt = 0; mt < 2; ++mt) {
            int c0 = w * 32 + mt * 16 + tg * 4;
            float4 bb = *(const float4*)&Bm[c0];
            #pragma unroll
            for (int nt = 0; nt < 8; ++nt) {
                int n = n0 + nt * 16 + tx;
                if (n < nrows) {
                    unsigned p01 = (unsigned)f2bf(acc[mt][nt][0] + bb.x)
                                 | ((unsigned)f2bf(acc[mt][nt][1] + bb.y) << 16);
                    unsigned p23 = (unsigned)f2bf(acc[mt][nt][2] + bb.z)
                                 | ((unsigned)f2bf(acc[mt][nt][3] + bb.w) << 16);
                    size_t base = (size_t)n * 128 + c0;   // u32 index; stride 128/node
                    kvw[base + off] = p01;
                    kvw[base + 2 + off] = p23;
                }
            }
        }
    }
}

// ---------------- node-centric edge aggregation via packed table ---------------
// One wave per dst node; 2 channels/lane. Per edge: 1 uniform 8B erec +
// 1 uint2 kv-gather (bf16 pairs, 512B/row) + 1 float4 tab-pair load. 8-edge batches.
__global__ __launch_bounds__(256) void k_agg(
    const int* __restrict__ rowptr, const int2* __restrict__ erec,
    const float* __restrict__ tabp, const float* __restrict__ qn,
    const unsigned int* __restrict__ kvw, const float* __restrict__ skip,
    float* __restrict__ tout)
{
    const int wid = (blockIdx.x * 256 + threadIdx.x) >> 6;   // node id
    if (wid >= NN) return;
    const int ln = threadIdx.x & 63;
    const int c0 = ln * 2;   // head = ln>>3
    const float2 q2 = *(const float2*)&qn[(size_t)wid * CC + c0];
    float nx = 0.0f, ny = 0.0f, den = 0.0f;
    int e = rowptr[wid];
    const int eend = rowptr[wid + 1];
    const float FS = 1.52587890625e-5f;   // 1/65536

    auto edge = [&](uint2 kv, float4 tp, float fr) {
        float ex = fmaf(fr, tp.z - tp.x, tp.x);
        float ey = fmaf(fr, tp.w - tp.y, tp.y);
        float kex = __uint_as_float(kv.x << 16) + ex;
        float key = __uint_as_float(kv.x & 0xffff0000u) + ey;
        float vex = __uint_as_float(kv.y << 16) + ex;
        float vey = __uint_as_float(kv.y & 0xffff0000u) + ey;
        float p = fmaf(q2.x, kex, q2.y * key);
        p += __shfl_xor(p, 1);
        p += __shfl_xor(p, 2);
        p += __shfl_xor(p, 4);          // sum over the head's 16 channels
        float w = __expf(p * 0.25f);    // scale = 1/sqrt(16); logits tiny, no max
        nx = fmaf(w, vex, nx);
        ny = fmaf(w, vey, ny);
        den += w;
    };

    for (; e + 8 <= eend; e += 8) {
        int2 r0 = erec[e + 0], r1 = erec[e + 1], r2 = erec[e + 2], r3 = erec[e + 3];
        int2 r4 = erec[e + 4], r5 = erec[e + 5], r6 = erec[e + 6], r7 = erec[e + 7];
        uint2 kv0 = *(const uint2*)&kvw[(size_t)r0.x * 128 + c0];
        uint2 kv1 = *(const uint2*)&kvw[(size_t)r1.x * 128 + c0];
        uint2 kv2 = *(const uint2*)&kvw[(size_t)r2.x * 128 + c0];
        uint2 kv3 = *(const uint2*)&kvw[(size_t)r3.x * 128 + c0];
        uint2 kv4 = *(const uint2*)&kvw[(size_t)r4.x * 128 + c0];
        uint2 kv5 = *(const uint2*)&kvw[(size_t)r5.x * 128 + c0];
        uint2 kv6 = *(const uint2*)&kvw[(size_t)r6.x * 128 + c0];
        uint2 kv7 = *(const uint2*)&kvw[(size_t)r7.x * 128 + c0];
        float4 tp0 = *(const float4*)&tabp[(size_t)(r0.y >> 16) * 256 + ln * 4];
        float4 tp1 = *(const float4*)&tabp[(size_t)(r1.y >> 16) * 256 + ln * 4];
        float4 tp2 = *(const float4*)&tabp[(size_t)(r2.y >> 16) * 256 + ln * 4];
        float4 tp3 = *(const float4*)&tabp[(size_t)(r3.y >> 16) * 256 + ln * 4];
        float4 tp4 = *(const float4*)&tabp[(size_t)(r4.y >> 16) * 256 + ln * 4];
        float4 tp5 = *(const float4*)&tabp[(size_t)(r5.y >> 16) * 256 + ln * 4];
        float4 tp6 = *(const float4*)&tabp[(size_t)(r6.y >> 16) * 256 + ln * 4];
        float4 tp7 = *(const float4*)&tabp[(size_t)(r7.y >> 16) * 256 + ln * 4];
        edge(kv0, tp0, (float)(r0.y & 0xffff) * FS);
        edge(kv1, tp1, (float)(r1.y & 0xffff) * FS);
        edge(kv2, tp2, (float)(r2.y & 0xffff) * FS);
        edge(kv3, tp3, (float)(r3.y & 0xffff) * FS);
        edge(kv4, tp4, (float)(r4.y & 0xffff) * FS);
        edge(kv5, tp5, (float)(r5.y & 0xffff) * FS);
        edge(kv6, tp6, (float)(r6.y & 0xffff) * FS);
        edge(kv7, tp7, (float)(r7.y & 0xffff) * FS);
    }
    for (; e < eend; ++e) {
        int2 r = erec[e];
        uint2 kv = *(const uint2*)&kvw[(size_t)r.x * 128 + c0];
        float4 tp = *(const float4*)&tabp[(size_t)(r.y >> 16) * 256 + ln * 4];
        edge(kv, tp, (float)(r.y & 0xffff) * FS);
    }

    const float2 sk = *(const float2*)&skip[(size_t)wid * CC + c0];
    float inv = 1.0f / (den + 1e-16f);
    float2 o;
    o.x = sspf(fmaf(nx, inv, sk.x));
    o.y = sspf(fmaf(ny, inv, sk.y));
    *(float2*)&tout[(size_t)wid * CC + c0] = o;
}

// ---------------- MFMA update: GEMM(wl) on t -> h += ---------------------------
__global__ __launch_bounds__(256) void k_upd_mfma(
    const float* __restrict__ tbuf, const u16* __restrict__ wlT,
    const float* __restrict__ Bias, float* __restrict__ h, int nrows)
{
    __shared__ __align__(16) short tb[128 * 136];
    const int t = threadIdx.x, lane = t & 63, w = t >> 6;
    const int tx = lane & 15, tg = lane >> 4;
    const int n0 = blockIdx.x * 128;
    for (int idx = t; idx < 128 * 32; idx += 256) {
        int r = idx >> 5, kq = idx & 31;
        int n = n0 + r;
        float4 tv;
        if (n < nrows) tv = *(const float4*)&tbuf[(size_t)n * 128 + kq * 4];
        else { tv.x = tv.y = tv.z = tv.w = 0.0f; }
        uint2 pk = make_uint2((unsigned)f2bf(tv.x) | ((unsigned)f2bf(tv.y) << 16),
                              (unsigned)f2bf(tv.z) | ((unsigned)f2bf(tv.w) << 16));
        *(uint2*)&tb[r * 136 + kq * 4] = pk;
    }
    __syncthreads();
    const f32x4 zf4 = { 0.0f, 0.0f, 0.0f, 0.0f };
    f32x4 acc[2][8];
    #pragma unroll
    for (int mt = 0; mt < 2; ++mt)
        #pragma unroll
        for (int nt = 0; nt < 8; ++nt) acc[mt][nt] = zf4;
    #pragma unroll
    for (int s = 0; s < 4; ++s) {
        bf16x8 af[2], bfr[8];
        #pragma unroll
        for (int mt = 0; mt < 2; ++mt)
            af[mt] = *(const bf16x8*)&wlT[(size_t)(w * 32 + mt * 16 + tx) * 128 + s * 32 + tg * 8];
        #pragma unroll
        for (int nt = 0; nt < 8; ++nt)
            bfr[nt] = *(const bf16x8*)&tb[(nt * 16 + tx) * 136 + s * 32 + tg * 8];
        #pragma unroll
        for (int mt = 0; mt < 2; ++mt)
            #pragma unroll
            for (int nt = 0; nt < 8; ++nt)
                acc[mt][nt] = __builtin_amdgcn_mfma_f32_16x16x32_bf16(af[mt], bfr[nt], acc[mt][nt], 0, 0, 0);
    }
    #pragma unroll
    for (int mt = 0; mt < 2; ++mt) {
        int c0 = w * 32 + mt * 16 + tg * 4;
        float4 bb = *(const float4*)&Bias[c0];
        #pragma unroll
        for (int nt = 0; nt < 8; ++nt) {
            int n = n0 + nt * 16 + tx;
            if (n < nrows) {
                float4 hv = *(const float4*)&h[(size_t)n * 128 + c0];
                hv.x += acc[mt][nt][0] + bb.x; hv.y += acc[mt][nt][1] + bb.y;
                hv.z += acc[mt][nt][2] + bb.z; hv.w += acc[mt][nt][3] + bb.w;
                *(float4*)&h[(size_t)n * 128 + c0] = hv;
            }
        }
    }
}

// ---------------- output head ----------------
__global__ __launch_bounds__(64) void k_head(
    const float* __restrict__ h,
    const float* __restrict__ w1, const float* __restrict__ b1,
    const float* __restrict__ w2, const float* __restrict__ b2,
    float* __restrict__ out)
{
    const int n = blockIdx.x;
    const int j = threadIdx.x;
    float acc = 0.0f;
    for (int k = 0; k < CC; ++k)
        acc = fmaf(h[(size_t)n * CC + k], w1[k * 64 + j], acc);
    float m = sspf(acc + b1[j]);
    float o = m * w2[j];
    #pragma unroll
    for (int msk = 32; msk > 0; msk >>= 1) o += __shfl_xor(o, msk);
    if (j == 0) out[n] = o + b2[0];
}

extern "C" void kernel_launch(void* const* d_in, const int* in_sizes, int n_in,
                              void* d_out, int out_size, void* d_ws, size_t ws_size,
                              hipStream_t stream)
{
    const int*   z   = (const int*)d_in[0];
    const float* pos = (const float*)d_in[1];
    const int*   ei  = (const int*)d_in[2];
    const float* emb = (const float*)d_in[3];
    const float* w1  = (const float*)d_in[4];
    const float* b1  = (const float*)d_in[5];
    const float* w2  = (const float*)d_in[6];
    const float* b2  = (const float*)d_in[7];
    const float* wq  = (const float*)d_in[8];
    const float* bq  = (const float*)d_in[9];
    const float* wk  = (const float*)d_in[10];
    const float* bk  = (const float*)d_in[11];
    const float* wv  = (const float*)d_in[12];
    const float* bv  = (const float*)d_in[13];
    const float* we  = (const float*)d_in[14];
    const float* be  = (const float*)d_in[15];
    const float* wsk = (const float*)d_in[16];
    const float* bsk = (const float*)d_in[17];
    const float* wl  = (const float*)d_in[18];
    const float* bl  = (const float*)d_in[19];
    const float* wo1 = (const float*)d_in[20];
    const float* bo1 = (const float*)d_in[21];
    const float* wo2 = (const float*)d_in[22];
    const float* bo2 = (const float*)d_in[23];

    char* p = (char*)d_ws;
    auto alloc = [&](size_t bytes) -> void* {
        void* r = (void*)p; p += (bytes + 255) & ~(size_t)255; return r;
    };
    float* h    = (float*)alloc((size_t)NN * CC * 4);
    float* q    = (float*)alloc((size_t)NN * CC * 4);
    float* skip = (float*)alloc((size_t)NN * CC * 4);
    float* tbuf = (float*)alloc((size_t)NN * CC * 4);
    unsigned int* kvw = (unsigned int*)alloc((size_t)NN * 128 * 4);  // bf16 k/v pairs, 128 u32/node
    float* w23f = (float*)alloc((size_t)LL * FF * CC * 4);
    float* b23g = (float*)alloc((size_t)LL * CC * 4);
    float* tab  = (float*)alloc((size_t)LL * (NTAB + 1) * CC * 4);
    float* tabp = (float*)alloc((size_t)LL * NTAB * 256 * 4);
    u16*   wn   = (u16*)alloc((size_t)LL * 5 * 128 * 128 * 2);
    int* count  = (int*)alloc((size_t)(NN + 1) * 4);
    int* rowptr = (int*)alloc((size_t)(NN + 1) * 4);
    int* cursor = (int*)alloc((size_t)NN * 4);
    int* srcp   = (int*)alloc((size_t)NE * 4);
    int* dstp   = (int*)alloc((size_t)NE * 4);
    int2* erec  = (int2*)alloc((size_t)NE * 8);

    k_zero<<<(NN + 255) / 256, 256, 0, stream>>>(count, NN);
    k_hist<<<(NE + 255) / 256, 256, 0, stream>>>(ei, count);
    k_scan<<<1, 1024, 0, stream>>>(count, rowptr, cursor);
    k_scatter<<<(NE + 255) / 256, 256, 0, stream>>>(ei, cursor, srcp, dstp);
    k_erec<<<(NE + 255) / 256, 256, 0, stream>>>(srcp, dstp, pos, erec);
    k_hinit<<<(NN * CC + 255) / 256, 256, 0, stream>>>(z, emb, h);
    k_prep23<<<LL * 128, 128, 0, stream>>>(w2, we, w23f);
    k_prepb<<<LL, 128, 0, stream>>>(b2, we, be, b23g);
    k_prept<<<LL * (NTAB + 1), 128, 0, stream>>>(w1, b1, w23f, b23g, tab);
    k_packt<<<(LL * NTAB * 128 + 255) / 256, 256, 0, stream>>>(tab, tabp);
    k_prepn<<<(LL * 5 * 128 * 128 + 255) / 256, 256, 0, stream>>>(wq, wk, wv, wsk, wl, wn);

    const int NT = (NN + 127) / 128;   // 157
    for (int l = 0; l < LL; ++l) {
        const u16* wnl = wn + (size_t)l * 5 * 16384;
        k_qkvs_mfma<<<NT * 4, 256, 0, stream>>>(h, wnl,
            bq + l * CC, bk + l * CC, bv + l * CC, bsk + l * CC,
            q, kvw, skip, NN);
        k_agg<<<(NN * 64 + 255) / 256, 256, 0, stream>>>(rowptr, erec,
            tabp + (size_t)l * NTAB * 256,
            q, kvw, skip, tbuf);
        k_upd_mfma<<<NT, 256, 0, stream>>>(tbuf,
            wnl + 4 * 16384, bl + l * CC, h, NN);
    }
    k_head<<<NN, 64, 0, stream>>>(h, wo1, bo1, wo2, bo2, (float*)d_out);
}

// Round 14
// 442.065 us; speedup vs baseline: 3.0258x; 1.0847x over previous
//
#include <hip/hip_runtime.h>

#define NN 20000
#define NE 640000
#define CC 128
#define HH 8
#define GG 50
#define FF 128
#define LL 3
#define NTAB 2048
#define DMAX 12.0f

typedef unsigned short u16;
typedef __attribute__((ext_vector_type(8))) short bf16x8;   // 8 bf16 = 4 VGPRs
typedef __attribute__((ext_vector_type(4))) float f32x4;

__device__ __forceinline__ u16 f2bf(float f) {
    union { float f; unsigned int i; } x; x.f = f;
    unsigned int r = x.i + 0x7fffu + ((x.i >> 16) & 1u);
    return (u16)(r >> 16);
}
// ShiftedSoftplus: softplus(x)-log2 via HW exp/log
__device__ __forceinline__ float sspf(float x) {
    return fmaxf(x, 0.0f) + __logf(1.0f + __expf(-fabsf(x))) - 0.69314718055994531f;
}

// ---------------- CSR build (sort edges by dst) ----------------
__global__ void k_zero(int* __restrict__ c, int n) {
    int i = blockIdx.x * 256 + threadIdx.x;
    if (i < n) c[i] = 0;
}

__global__ void k_hist(const int* __restrict__ ei, int* __restrict__ c) {
    int e = blockIdx.x * 256 + threadIdx.x;
    if (e < NE) atomicAdd(&c[ei[NE + e]], 1);
}

__global__ __launch_bounds__(1024) void k_scan(const int* __restrict__ cnt,
                                               int* __restrict__ rowptr,
                                               int* __restrict__ cursor) {
    __shared__ int sums[1024];
    const int t = threadIdx.x;
    int local[20];
    int base = t * 20;
    int s = 0;
    #pragma unroll
    for (int i = 0; i < 20; ++i) {
        int idx = base + i;
        int v = (idx < NN) ? cnt[idx] : 0;
        local[i] = s; s += v;
    }
    sums[t] = s;
    __syncthreads();
    for (int off = 1; off < 1024; off <<= 1) {
        int v = (t >= off) ? sums[t - off] : 0;
        __syncthreads();
        sums[t] += v;
        __syncthreads();
    }
    int excl = (t == 0) ? 0 : sums[t - 1];
    #pragma unroll
    for (int i = 0; i < 20; ++i) {
        int idx = base + i;
        if (idx < NN) { int r = excl + local[i]; rowptr[idx] = r; cursor[idx] = r; }
    }
    if (t == 1023) rowptr[NN] = sums[1023];
}

__global__ void k_scatter(const int* __restrict__ ei, int* __restrict__ cursor,
                          int* __restrict__ srcp, int* __restrict__ dstp) {
    int e = blockIdx.x * 256 + threadIdx.x;
    if (e >= NE) return;
    int s = ei[e], d = ei[NE + e];
    int pp = atomicAdd(&cursor[d], 1);
    srcp[pp] = s; dstp[pp] = d;
}

// per-edge record: {src, i0<<16 | frac16}; d is layer-invariant
__global__ void k_erec(const int* __restrict__ srcp, const int* __restrict__ dstp,
                       const float* __restrict__ pos, int2* __restrict__ erec) {
    int e = blockIdx.x * 256 + threadIdx.x;
    if (e >= NE) return;
    int a = srcp[e], b = dstp[e];
    float dx = pos[b * 3 + 0] - pos[a * 3 + 0];
    float dy = pos[b * 3 + 1] - pos[a * 3 + 1];
    float dz = pos[b * 3 + 2] - pos[a * 3 + 2];
    float d = sqrtf(dx * dx + dy * dy + dz * dz + 1e-12f);
    float t = fminf(d * ((float)NTAB / DMAX), (float)NTAB - 1e-3f);
    int i0 = (int)t;
    int fr = (int)((t - (float)i0) * 65536.0f);
    fr = min(fr, 65535);
    int2 r; r.x = a; r.y = (i0 << 16) | fr;
    erec[e] = r;
}

// ---------------- weight prep (once per call) ----------------
// W23f[l][k][cp] = sum_c w2[l][k][c] * we[l][c][cp]  (fp32)
__global__ __launch_bounds__(128) void k_prep23(const float* __restrict__ w2,
                                                const float* __restrict__ we,
                                                float* __restrict__ w23f) {
    int l = blockIdx.x >> 7, k = blockIdx.x & 127;
    int cp = threadIdx.x;
    float s = 0.0f;
    for (int c = 0; c < FF; ++c)
        s = fmaf(w2[((size_t)l * FF + k) * FF + c], we[((size_t)l * FF + c) * CC + cp], s);
    w23f[((size_t)l * FF + k) * CC + cp] = s;
}

// b23[l][cp] = be[l][cp] + sum_k b2[l][k] * we[l][k][cp]
__global__ __launch_bounds__(128) void k_prepb(const float* __restrict__ b2,
                                               const float* __restrict__ we,
                                               const float* __restrict__ be,
                                               float* __restrict__ b23g) {
    int l = blockIdx.x;
    int cp = threadIdx.x;
    float s = be[l * CC + cp];
    for (int k = 0; k < FF; ++k)
        s = fmaf(b2[l * FF + k], we[((size_t)l * FF + k) * CC + cp], s);
    b23g[l * CC + cp] = s;
}

// ep table: tab[l][i][cp] = MLP(gauss(d_i)) exact fp32, d_i = i*DMAX/NTAB, i in [0,NTAB]
__global__ __launch_bounds__(128) void k_prept(const float* __restrict__ w1,
                                               const float* __restrict__ b1,
                                               const float* __restrict__ w23f,
                                               const float* __restrict__ b23g,
                                               float* __restrict__ tab) {
    const int l = blockIdx.x / (NTAB + 1);
    const int i = blockIdx.x % (NTAB + 1);
    const int c = threadIdx.x;
    __shared__ float attr[GG];
    __shared__ float hid[FF];
    const float STEP = 10.0f / 49.0f;
    const float COEF = -0.5f / (STEP * STEP);
    float d = (float)i * (DMAX / (float)NTAB);
    if (c < GG) { float df = d - STEP * (float)c; attr[c] = __expf(COEF * df * df); }
    __syncthreads();
    float s = b1[l * FF + c];
    for (int g = 0; g < GG; ++g)
        s = fmaf(attr[g], w1[((size_t)l * GG + g) * FF + c], s);
    hid[c] = sspf(s);
    __syncthreads();
    float o = b23g[l * CC + c];
    for (int k = 0; k < FF; ++k)
        o = fmaf(hid[k], w23f[((size_t)l * FF + k) * CC + c], o);
    tab[((size_t)l * (NTAB + 1) + i) * CC + c] = o;
}

// pack table pairs to bf16: tabq[l][i][ln] = uint2{ bf16(t_i[c0])|bf16(t_i[c0+1])<<16,
//                                                   bf16(t_{i+1}[c0])|bf16(t_{i+1}[c0+1])<<16 }
__global__ void k_packt(const float* __restrict__ tab, uint2* __restrict__ tabq) {
    int idx = blockIdx.x * 256 + threadIdx.x;
    if (idx >= LL * NTAB * 64) return;
    int ln = idx & 63;
    int i = (idx >> 6) % NTAB;
    int l = idx / (NTAB * 64);
    int c0 = ln * 2;
    const float* t0 = &tab[((size_t)l * (NTAB + 1) + i) * CC + c0];
    const float* t1 = t0 + CC;
    uint2 o;
    o.x = (unsigned)f2bf(t0[0]) | ((unsigned)f2bf(t0[1]) << 16);
    o.y = (unsigned)f2bf(t1[0]) | ((unsigned)f2bf(t1[1]) << 16);
    tabq[((size_t)l * NTAB + i) * 64 + ln] = o;
}

// node weights: wn[((l*5+m)*128 + c)*128 + k] = bf16(W_m[l][k][c]); m: q,k,v,skip,l
__global__ void k_prepn(const float* __restrict__ wq, const float* __restrict__ wk,
                        const float* __restrict__ wv, const float* __restrict__ wsk,
                        const float* __restrict__ wl, u16* __restrict__ wn) {
    int i = blockIdx.x * 256 + threadIdx.x;
    if (i >= LL * 5 * 128 * 128) return;
    int k = i & 127, c = (i >> 7) & 127;
    int lm = i >> 14; int m = lm % 5, l = lm / 5;
    const float* W = (m == 0) ? wq : (m == 1) ? wk : (m == 2) ? wv : (m == 3) ? wsk : wl;
    wn[i] = f2bf(W[((size_t)l * 128 + k) * 128 + c]);
}

// ---------------- fused node kernel ----------------
// MODE 0: hb <- emb[z] (also writes h);       then 4 GEMMs -> q,kvw,skip
// MODE 1: tb <- tbuf; h += tb@wl (hb <- new h); then 4 GEMMs -> q,kvw,skip
// MODE 2: tb <- tbuf; h += tb@wl               (no next-layer GEMMs)
// kvw layout: per node 128 u32; u32[n*128+c]=k-pair(c,c+1) even c, [+1]=v-pair.
template<int MODE>
__global__ __launch_bounds__(256) void k_node(
    const int* __restrict__ z, const float* __restrict__ emb,
    const float* __restrict__ tbuf,
    const u16* __restrict__ wlT, const float* __restrict__ bl,
    float* __restrict__ h,
    const u16* __restrict__ wq4,
    const float* __restrict__ bq, const float* __restrict__ bk,
    const float* __restrict__ bv, const float* __restrict__ bs,
    float* __restrict__ o_q, unsigned int* __restrict__ kvw,
    float* __restrict__ o_skip, int nrows)
{
    __shared__ __align__(16) short tb[128 * 136];
    __shared__ __align__(16) short hb[128 * 136];
    const int t = threadIdx.x, lane = t & 63, w = t >> 6;
    const int tx = lane & 15, tg = lane >> 4;
    const int n0 = blockIdx.x * 128;
    const f32x4 zf4 = { 0.0f, 0.0f, 0.0f, 0.0f };

    if (MODE == 0) {
        for (int idx = t; idx < 128 * 32; idx += 256) {
            int r = idx >> 5, kq = idx & 31;
            int n = n0 + r;
            float4 hv;
            if (n < nrows) {
                hv = *(const float4*)&emb[(size_t)z[n] * CC + kq * 4];
                *(float4*)&h[(size_t)n * CC + kq * 4] = hv;
            } else { hv.x = hv.y = hv.z = hv.w = 0.0f; }
            uint2 pk = make_uint2((unsigned)f2bf(hv.x) | ((unsigned)f2bf(hv.y) << 16),
                                  (unsigned)f2bf(hv.z) | ((unsigned)f2bf(hv.w) << 16));
            *(uint2*)&hb[r * 136 + kq * 4] = pk;
        }
        __syncthreads();
    } else {
        for (int idx = t; idx < 128 * 32; idx += 256) {
            int r = idx >> 5, kq = idx & 31;
            int n = n0 + r;
            float4 tv;
            if (n < nrows) tv = *(const float4*)&tbuf[(size_t)n * 128 + kq * 4];
            else { tv.x = tv.y = tv.z = tv.w = 0.0f; }
            uint2 pk = make_uint2((unsigned)f2bf(tv.x) | ((unsigned)f2bf(tv.y) << 16),
                                  (unsigned)f2bf(tv.z) | ((unsigned)f2bf(tv.w) << 16));
            *(uint2*)&tb[r * 136 + kq * 4] = pk;
        }
        __syncthreads();
        // GEMM tb @ wl -> new h; write h (f32) and hb (bf16)
        f32x4 acc[2][8];
        #pragma unroll
        for (int mt = 0; mt < 2; ++mt)
            #pragma unroll
            for (int nt = 0; nt < 8; ++nt) acc[mt][nt] = zf4;
        #pragma unroll
        for (int s = 0; s < 4; ++s) {
            bf16x8 af[2], bfr[8];
            #pragma unroll
            for (int mt = 0; mt < 2; ++mt)
                af[mt] = *(const bf16x8*)&wlT[(size_t)(w * 32 + mt * 16 + tx) * 128 + s * 32 + tg * 8];
            #pragma unroll
            for (int nt = 0; nt < 8; ++nt)
                bfr[nt] = *(const bf16x8*)&tb[(nt * 16 + tx) * 136 + s * 32 + tg * 8];
            #pragma unroll
            for (int mt = 0; mt < 2; ++mt)
                #pragma unroll
                for (int nt = 0; nt < 8; ++nt)
                    acc[mt][nt] = __builtin_amdgcn_mfma_f32_16x16x32_bf16(af[mt], bfr[nt], acc[mt][nt], 0, 0, 0);
        }
        #pragma unroll
        for (int mt = 0; mt < 2; ++mt) {
            int c0 = w * 32 + mt * 16 + tg * 4;
            float4 bb = *(const float4*)&bl[c0];
            #pragma unroll
            for (int nt = 0; nt < 8; ++nt) {
                int n = n0 + nt * 16 + tx;
                if (n < nrows) {
                    float4 hv = *(const float4*)&h[(size_t)n * 128 + c0];
                    hv.x += acc[mt][nt][0] + bb.x; hv.y += acc[mt][nt][1] + bb.y;
                    hv.z += acc[mt][nt][2] + bb.z; hv.w += acc[mt][nt][3] + bb.w;
                    *(float4*)&h[(size_t)n * 128 + c0] = hv;
                    if (MODE == 1) {
                        uint2 pk = make_uint2((unsigned)f2bf(hv.x) | ((unsigned)f2bf(hv.y) << 16),
                                              (unsigned)f2bf(hv.z) | ((unsigned)f2bf(hv.w) << 16));
                        *(uint2*)&hb[(nt * 16 + tx) * 136 + c0] = pk;
                    }
                }
            }
        }
        if (MODE == 1) __syncthreads();
    }

    if (MODE <= 1) {
        // 4 GEMMs from hb: m=0 q, m=1 k-pairs, m=2 v-pairs, m=3 skip
        #pragma unroll
        for (int m = 0; m < 4; ++m) {
            f32x4 acc[2][8];
            #pragma unroll
            for (int mt = 0; mt < 2; ++mt)
                #pragma unroll
                for (int nt = 0; nt < 8; ++nt) acc[mt][nt] = zf4;
            const u16* Wm = wq4 + (size_t)m * 16384;
            #pragma unroll
            for (int s = 0; s < 4; ++s) {
                bf16x8 af[2], bfr[8];
                #pragma unroll
                for (int mt = 0; mt < 2; ++mt)
                    af[mt] = *(const bf16x8*)&Wm[(size_t)(w * 32 + mt * 16 + tx) * 128 + s * 32 + tg * 8];
                #pragma unroll
                for (int nt = 0; nt < 8; ++nt)
                    bfr[nt] = *(const bf16x8*)&hb[(nt * 16 + tx) * 136 + s * 32 + tg * 8];
                #pragma unroll
                for (int mt = 0; mt < 2; ++mt)
                    #pragma unroll
                    for (int nt = 0; nt < 8; ++nt)
                        acc[mt][nt] = __builtin_amdgcn_mfma_f32_16x16x32_bf16(af[mt], bfr[nt], acc[mt][nt], 0, 0, 0);
            }
            const float* Bm = (m == 0) ? bq : (m == 1) ? bk : (m == 2) ? bv : bs;
            if (m == 0 || m == 3) {
                float* Om = (m == 0) ? o_q : o_skip;
                #pragma unroll
                for (int mt = 0; mt < 2; ++mt) {
                    int c0 = w * 32 + mt * 16 + tg * 4;
                    float4 bb = *(const float4*)&Bm[c0];
                    #pragma unroll
                    for (int nt = 0; nt < 8; ++nt) {
                        int n = n0 + nt * 16 + tx;
                        if (n < nrows) {
                            float4 ov;
                            ov.x = acc[mt][nt][0] + bb.x; ov.y = acc[mt][nt][1] + bb.y;
                            ov.z = acc[mt][nt][2] + bb.z; ov.w = acc[mt][nt][3] + bb.w;
                            *(float4*)&Om[(size_t)n * 128 + c0] = ov;
                        }
                    }
                }
            } else {
                const int off = (m == 1) ? 0 : 1;
                #pragma unroll
                for (int mt = 0; mt < 2; ++mt) {
                    int c0 = w * 32 + mt * 16 + tg * 4;
                    float4 bb = *(const float4*)&Bm[c0];
                    #pragma unroll
                    for (int nt = 0; nt < 8; ++nt) {
                        int n = n0 + nt * 16 + tx;
                        if (n < nrows) {
                            unsigned p01 = (unsigned)f2bf(acc[mt][nt][0] + bb.x)
                                         | ((unsigned)f2bf(acc[mt][nt][1] + bb.y) << 16);
                            unsigned p23 = (unsigned)f2bf(acc[mt][nt][2] + bb.z)
                                         | ((unsigned)f2bf(acc[mt][nt][3] + bb.w) << 16);
                            size_t base = (size_t)n * 128 + c0;
                            kvw[base + off] = p01;
                            kvw[base + 2 + off] = p23;
                        }
                    }
                }
            }
        }
    }
}

// ---------------- node-centric edge aggregation via packed bf16 table ----------
// One wave per dst node; 2 channels/lane. Per edge: 1 uniform 8B erec +
// 1 uint2 kv-gather + 1 uint2 tab-pair (bf16). 8-edge batches.
__global__ __launch_bounds__(256) void k_agg(
    const int* __restrict__ rowptr, const int2* __restrict__ erec,
    const uint2* __restrict__ tabq, const float* __restrict__ qn,
    const unsigned int* __restrict__ kvw, const float* __restrict__ skip,
    float* __restrict__ tout)
{
    const int wid = (blockIdx.x * 256 + threadIdx.x) >> 6;   // node id
    if (wid >= NN) return;
    const int ln = threadIdx.x & 63;
    const int c0 = ln * 2;   // head = ln>>3
    const float2 q2 = *(const float2*)&qn[(size_t)wid * CC + c0];
    float nx = 0.0f, ny = 0.0f, den = 0.0f;
    int e = rowptr[wid];
    const int eend = rowptr[wid + 1];
    const float FS = 1.52587890625e-5f;   // 1/65536

    auto edge = [&](uint2 kv, uint2 tp, float fr) {
        float t0x = __uint_as_float(tp.x << 16);
        float t0y = __uint_as_float(tp.x & 0xffff0000u);
        float t1x = __uint_as_float(tp.y << 16);
        float t1y = __uint_as_float(tp.y & 0xffff0000u);
        float ex = fmaf(fr, t1x - t0x, t0x);
        float ey = fmaf(fr, t1y - t0y, t0y);
        float kex = __uint_as_float(kv.x << 16) + ex;
        float key = __uint_as_float(kv.x & 0xffff0000u) + ey;
        float vex = __uint_as_float(kv.y << 16) + ex;
        float vey = __uint_as_float(kv.y & 0xffff0000u) + ey;
        float p = fmaf(q2.x, kex, q2.y * key);
        p += __shfl_xor(p, 1);
        p += __shfl_xor(p, 2);
        p += __shfl_xor(p, 4);          // sum over the head's 16 channels
        float w = __expf(p * 0.25f);    // scale = 1/sqrt(16); logits tiny, no max
        nx = fmaf(w, vex, nx);
        ny = fmaf(w, vey, ny);
        den += w;
    };

    for (; e + 8 <= eend; e += 8) {
        int2 r0 = erec[e + 0], r1 = erec[e + 1], r2 = erec[e + 2], r3 = erec[e + 3];
        int2 r4 = erec[e + 4], r5 = erec[e + 5], r6 = erec[e + 6], r7 = erec[e + 7];
        uint2 kv0 = *(const uint2*)&kvw[(size_t)r0.x * 128 + c0];
        uint2 kv1 = *(const uint2*)&kvw[(size_t)r1.x * 128 + c0];
        uint2 kv2 = *(const uint2*)&kvw[(size_t)r2.x * 128 + c0];
        uint2 kv3 = *(const uint2*)&kvw[(size_t)r3.x * 128 + c0];
        uint2 kv4 = *(const uint2*)&kvw[(size_t)r4.x * 128 + c0];
        uint2 kv5 = *(const uint2*)&kvw[(size_t)r5.x * 128 + c0];
        uint2 kv6 = *(const uint2*)&kvw[(size_t)r6.x * 128 + c0];
        uint2 kv7 = *(const uint2*)&kvw[(size_t)r7.x * 128 + c0];
        uint2 tp0 = tabq[(size_t)(r0.y >> 16) * 64 + ln];
        uint2 tp1 = tabq[(size_t)(r1.y >> 16) * 64 + ln];
        uint2 tp2 = tabq[(size_t)(r2.y >> 16) * 64 + ln];
        uint2 tp3 = tabq[(size_t)(r3.y >> 16) * 64 + ln];
        uint2 tp4 = tabq[(size_t)(r4.y >> 16) * 64 + ln];
        uint2 tp5 = tabq[(size_t)(r5.y >> 16) * 64 + ln];
        uint2 tp6 = tabq[(size_t)(r6.y >> 16) * 64 + ln];
        uint2 tp7 = tabq[(size_t)(r7.y >> 16) * 64 + ln];
        edge(kv0, tp0, (float)(r0.y & 0xffff) * FS);
        edge(kv1, tp1, (float)(r1.y & 0xffff) * FS);
        edge(kv2, tp2, (float)(r2.y & 0xffff) * FS);
        edge(kv3, tp3, (float)(r3.y & 0xffff) * FS);
        edge(kv4, tp4, (float)(r4.y & 0xffff) * FS);
        edge(kv5, tp5, (float)(r5.y & 0xffff) * FS);
        edge(kv6, tp6, (float)(r6.y & 0xffff) * FS);
        edge(kv7, tp7, (float)(r7.y & 0xffff) * FS);
    }
    for (; e < eend; ++e) {
        int2 r = erec[e];
        uint2 kv = *(const uint2*)&kvw[(size_t)r.x * 128 + c0];
        uint2 tp = tabq[(size_t)(r.y >> 16) * 64 + ln];
        edge(kv, tp, (float)(r.y & 0xffff) * FS);
    }

    const float2 sk = *(const float2*)&skip[(size_t)wid * CC + c0];
    float inv = 1.0f / (den + 1e-16f);
    float2 o;
    o.x = sspf(fmaf(nx, inv, sk.x));
    o.y = sspf(fmaf(ny, inv, sk.y));
    *(float2*)&tout[(size_t)wid * CC + c0] = o;
}

// ---------------- output head ----------------
__global__ __launch_bounds__(64) void k_head(
    const float* __restrict__ h,
    const float* __restrict__ w1, const float* __restrict__ b1,
    const float* __restrict__ w2, const float* __restrict__ b2,
    float* __restrict__ out)
{
    const int n = blockIdx.x;
    const int j = threadIdx.x;
    float acc = 0.0f;
    for (int k = 0; k < CC; ++k)
        acc = fmaf(h[(size_t)n * CC + k], w1[k * 64 + j], acc);
    float m = sspf(acc + b1[j]);
    float o = m * w2[j];
    #pragma unroll
    for (int msk = 32; msk > 0; msk >>= 1) o += __shfl_xor(o, msk);
    if (j == 0) out[n] = o + b2[0];
}

extern "C" void kernel_launch(void* const* d_in, const int* in_sizes, int n_in,
                              void* d_out, int out_size, void* d_ws, size_t ws_size,
                              hipStream_t stream)
{
    const int*   z   = (const int*)d_in[0];
    const float* pos = (const float*)d_in[1];
    const int*   ei  = (const int*)d_in[2];
    const float* emb = (const float*)d_in[3];
    const float* w1  = (const float*)d_in[4];
    const float* b1  = (const float*)d_in[5];
    const float* w2  = (const float*)d_in[6];
    const float* b2  = (const float*)d_in[7];
    const float* wq  = (const float*)d_in[8];
    const float* bq  = (const float*)d_in[9];
    const float* wk  = (const float*)d_in[10];
    const float* bk  = (const float*)d_in[11];
    const float* wv  = (const float*)d_in[12];
    const float* bv  = (const float*)d_in[13];
    const float* we  = (const float*)d_in[14];
    const float* be  = (const float*)d_in[15];
    const float* wsk = (const float*)d_in[16];
    const float* bsk = (const float*)d_in[17];
    const float* wl  = (const float*)d_in[18];
    const float* bl  = (const float*)d_in[19];
    const float* wo1 = (const float*)d_in[20];
    const float* bo1 = (const float*)d_in[21];
    const float* wo2 = (const float*)d_in[22];
    const float* bo2 = (const float*)d_in[23];

    char* p = (char*)d_ws;
    auto alloc = [&](size_t bytes) -> void* {
        void* r = (void*)p; p += (bytes + 255) & ~(size_t)255; return r;
    };
    float* h    = (float*)alloc((size_t)NN * CC * 4);
    float* q    = (float*)alloc((size_t)NN * CC * 4);
    float* skip = (float*)alloc((size_t)NN * CC * 4);
    float* tbuf = (float*)alloc((size_t)NN * CC * 4);
    unsigned int* kvw = (unsigned int*)alloc((size_t)NN * 128 * 4);  // bf16 k/v pairs
    float* w23f = (float*)alloc((size_t)LL * FF * CC * 4);
    float* b23g = (float*)alloc((size_t)LL * CC * 4);
    float* tab  = (float*)alloc((size_t)LL * (NTAB + 1) * CC * 4);
    uint2* tabq = (uint2*)alloc((size_t)LL * NTAB * 64 * 8);
    u16*   wn   = (u16*)alloc((size_t)LL * 5 * 128 * 128 * 2);
    int* count  = (int*)alloc((size_t)(NN + 1) * 4);
    int* rowptr = (int*)alloc((size_t)(NN + 1) * 4);
    int* cursor = (int*)alloc((size_t)NN * 4);
    int* srcp   = (int*)alloc((size_t)NE * 4);
    int* dstp   = (int*)alloc((size_t)NE * 4);
    int2* erec  = (int2*)alloc((size_t)NE * 8);

    k_zero<<<(NN + 255) / 256, 256, 0, stream>>>(count, NN);
    k_hist<<<(NE + 255) / 256, 256, 0, stream>>>(ei, count);
    k_scan<<<1, 1024, 0, stream>>>(count, rowptr, cursor);
    k_scatter<<<(NE + 255) / 256, 256, 0, stream>>>(ei, cursor, srcp, dstp);
    k_erec<<<(NE + 255) / 256, 256, 0, stream>>>(srcp, dstp, pos, erec);
    k_prep23<<<LL * 128, 128, 0, stream>>>(w2, we, w23f);
    k_prepb<<<LL, 128, 0, stream>>>(b2, we, be, b23g);
    k_prept<<<LL * (NTAB + 1), 128, 0, stream>>>(w1, b1, w23f, b23g, tab);
    k_packt<<<(LL * NTAB * 64 + 255) / 256, 256, 0, stream>>>(tab, tabq);
    k_prepn<<<(LL * 5 * 128 * 128 + 255) / 256, 256, 0, stream>>>(wq, wk, wv, wsk, wl, wn);

    const int NT = (NN + 127) / 128;   // 157
    // layer 0 q/k/v/skip from emb[z] (writes h too)
    k_node<0><<<NT, 256, 0, stream>>>(z, emb, nullptr, nullptr, nullptr, h,
        wn, bq, bk, bv, bsk, q, kvw, skip, NN);
    for (int l = 0; l < LL; ++l) {
        k_agg<<<(NN * 64 + 255) / 256, 256, 0, stream>>>(rowptr, erec,
            tabq + (size_t)l * NTAB * 64, q, kvw, skip, tbuf);
        const u16* wnl = wn + (size_t)l * 5 * 16384;
        if (l < LL - 1) {
            const u16* wnn = wn + (size_t)(l + 1) * 5 * 16384;
            k_node<1><<<NT, 256, 0, stream>>>(nullptr, nullptr, tbuf,
                wnl + 4 * 16384, bl + l * CC, h,
                wnn, bq + (l + 1) * CC, bk + (l + 1) * CC,
                bv + (l + 1) * CC, bsk + (l + 1) * CC,
                q, kvw, skip, NN);
        } else {
            k_node<2><<<NT, 256, 0, stream>>>(nullptr, nullptr, tbuf,
                wnl + 4 * 16384, bl + l * CC, h,
                nullptr, nullptr, nullptr, nullptr, nullptr,
                nullptr, nullptr, nullptr, NN);
        }
    }
    k_head<<<NN, 64, 0, stream>>>(h, wo1, bo1, wo2, bo2, (float*)d_out);
}

// Round 15
// 417.545 us; speedup vs baseline: 3.2035x; 1.0587x over previous
//
#include <hip/hip_runtime.h>

#define NN 20000
#define NE 640000
#define CC 128
#define HH 8
#define GG 50
#define FF 128
#define LL 3
#define NTAB 2048
#define DMAX 12.0f

typedef unsigned short u16;
typedef __attribute__((ext_vector_type(8))) short bf16x8;   // 8 bf16 = 4 VGPRs
typedef __attribute__((ext_vector_type(4))) float f32x4;

__device__ __forceinline__ u16 f2bf(float f) {
    union { float f; unsigned int i; } x; x.f = f;
    unsigned int r = x.i + 0x7fffu + ((x.i >> 16) & 1u);
    return (u16)(r >> 16);
}
// ShiftedSoftplus: softplus(x)-log2 via HW exp/log
__device__ __forceinline__ float sspf(float x) {
    return fmaxf(x, 0.0f) + __logf(1.0f + __expf(-fabsf(x))) - 0.69314718055994531f;
}

// ---------------- CSR build (sort edges by dst; far edges first per node) ------
__global__ void k_zero(int* __restrict__ c, int n) {
    int i = blockIdx.x * 256 + threadIdx.x;
    if (i < n) c[i] = 0;
}

__device__ __forceinline__ float edist(const float* __restrict__ pos, int a, int b) {
    float dx = pos[b * 3 + 0] - pos[a * 3 + 0];
    float dy = pos[b * 3 + 1] - pos[a * 3 + 1];
    float dz = pos[b * 3 + 2] - pos[a * 3 + 2];
    return sqrtf(dx * dx + dy * dy + dz * dz + 1e-12f);
}

__global__ void k_hist(const int* __restrict__ ei, const float* __restrict__ pos,
                       int* __restrict__ cnt, int* __restrict__ cntF) {
    int e = blockIdx.x * 256 + threadIdx.x;
    if (e >= NE) return;
    int a = ei[e], b = ei[NE + e];
    atomicAdd(&cnt[b], 1);
    float tt = edist(pos, a, b) * ((float)NTAB / DMAX);
    if (tt >= (float)(NTAB - 1)) atomicAdd(&cntF[b], 1);
}

__global__ __launch_bounds__(1024) void k_scan(const int* __restrict__ cnt,
                                               int* __restrict__ rowptr,
                                               int* __restrict__ curF) {
    __shared__ int sums[1024];
    const int t = threadIdx.x;
    int local[20];
    int base = t * 20;
    int s = 0;
    #pragma unroll
    for (int i = 0; i < 20; ++i) {
        int idx = base + i;
        int v = (idx < NN) ? cnt[idx] : 0;
        local[i] = s; s += v;
    }
    sums[t] = s;
    __syncthreads();
    for (int off = 1; off < 1024; off <<= 1) {
        int v = (t >= off) ? sums[t - off] : 0;
        __syncthreads();
        sums[t] += v;
        __syncthreads();
    }
    int excl = (t == 0) ? 0 : sums[t - 1];
    #pragma unroll
    for (int i = 0; i < 20; ++i) {
        int idx = base + i;
        if (idx < NN) { int r = excl + local[i]; rowptr[idx] = r; curF[idx] = r; }
    }
    if (t == 1023) rowptr[NN] = sums[1023];
}

__global__ void k_mid(const int* __restrict__ rowptr, const int* __restrict__ cntF,
                      int* __restrict__ rowmid, int* __restrict__ curN) {
    int n = blockIdx.x * 256 + threadIdx.x;
    if (n < NN) { int m = rowptr[n] + cntF[n]; rowmid[n] = m; curN[n] = m; }
}

// far edges -> [rowptr, rowmid) need only src; near -> [rowmid, rowptr+1) get erec
__global__ void k_scatter(const int* __restrict__ ei, const float* __restrict__ pos,
                          int* __restrict__ curF, int* __restrict__ curN,
                          int* __restrict__ srcp, int2* __restrict__ erec) {
    int e = blockIdx.x * 256 + threadIdx.x;
    if (e >= NE) return;
    int a = ei[e], b = ei[NE + e];
    float tt = edist(pos, a, b) * ((float)NTAB / DMAX);
    bool far = tt >= (float)(NTAB - 1);
    int pp = atomicAdd(far ? &curF[b] : &curN[b], 1);
    srcp[pp] = a;
    if (!far) {
        int i0 = (int)tt;
        int fr = min((int)((tt - (float)i0) * 65536.0f), 65535);
        int2 r; r.x = a; r.y = (i0 << 16) | fr;
        erec[pp] = r;
    }
}

// ---------------- weight prep (once per call) ----------------
// W23f[l][k][cp] = sum_c w2[l][k][c] * we[l][c][cp]  (fp32)
__global__ __launch_bounds__(128) void k_prep23(const float* __restrict__ w2,
                                                const float* __restrict__ we,
                                                float* __restrict__ w23f) {
    int l = blockIdx.x >> 7, k = blockIdx.x & 127;
    int cp = threadIdx.x;
    float s = 0.0f;
    for (int c = 0; c < FF; ++c)
        s = fmaf(w2[((size_t)l * FF + k) * FF + c], we[((size_t)l * FF + c) * CC + cp], s);
    w23f[((size_t)l * FF + k) * CC + cp] = s;
}

// b23[l][cp] = be[l][cp] + sum_k b2[l][k] * we[l][k][cp]
__global__ __launch_bounds__(128) void k_prepb(const float* __restrict__ b2,
                                               const float* __restrict__ we,
                                               const float* __restrict__ be,
                                               float* __restrict__ b23g) {
    int l = blockIdx.x;
    int cp = threadIdx.x;
    float s = be[l * CC + cp];
    for (int k = 0; k < FF; ++k)
        s = fmaf(b2[l * FF + k], we[((size_t)l * FF + k) * CC + cp], s);
    b23g[l * CC + cp] = s;
}

// ep table: tab[l][i][cp] = MLP(gauss(d_i)) exact fp32, i in [0,NTAB] (d=NTAB*step -> attr=0)
__global__ __launch_bounds__(128) void k_prept(const float* __restrict__ w1,
                                               const float* __restrict__ b1,
                                               const float* __restrict__ w23f,
                                               const float* __restrict__ b23g,
                                               float* __restrict__ tab) {
    const int l = blockIdx.x / (NTAB + 1);
    const int i = blockIdx.x % (NTAB + 1);
    const int c = threadIdx.x;
    __shared__ float attr[GG];
    __shared__ float hid[FF];
    const float STEP = 10.0f / 49.0f;
    const float COEF = -0.5f / (STEP * STEP);
    float d = (float)i * (DMAX / (float)NTAB);
    if (c < GG) { float df = d - STEP * (float)c; attr[c] = __expf(COEF * df * df); }
    __syncthreads();
    float s = b1[l * FF + c];
    for (int g = 0; g < GG; ++g)
        s = fmaf(attr[g], w1[((size_t)l * GG + g) * FF + c], s);
    hid[c] = sspf(s);
    __syncthreads();
    float o = b23g[l * CC + c];
    for (int k = 0; k < FF; ++k)
        o = fmaf(hid[k], w23f[((size_t)l * FF + k) * CC + c], o);
    tab[((size_t)l * (NTAB + 1) + i) * CC + c] = o;
}

// bf16 DELTA table pairs: tabq[l][i][ln] = { bf16(tab[i]-ep_inf) pair, bf16(tab[i+1]-ep_inf) pair }
__global__ void k_packt(const float* __restrict__ tab, uint2* __restrict__ tabq) {
    int idx = blockIdx.x * 256 + threadIdx.x;
    if (idx >= LL * NTAB * 64) return;
    int ln = idx & 63;
    int i = (idx >> 6) % NTAB;
    int l = idx / (NTAB * 64);
    int c0 = ln * 2;
    const float* t0 = &tab[((size_t)l * (NTAB + 1) + i) * CC + c0];
    const float* t1 = t0 + CC;
    const float* ti = &tab[((size_t)l * (NTAB + 1) + NTAB) * CC + c0];
    uint2 o;
    o.x = (unsigned)f2bf(t0[0] - ti[0]) | ((unsigned)f2bf(t0[1] - ti[1]) << 16);
    o.y = (unsigned)f2bf(t1[0] - ti[0]) | ((unsigned)f2bf(t1[1] - ti[1]) << 16);
    tabq[((size_t)l * NTAB + i) * 64 + ln] = o;
}

// fold ep_inf into k/v biases: bkf = bk + ep_inf, bvf = bv + ep_inf
__global__ __launch_bounds__(128) void k_foldb(const float* __restrict__ bk,
                                               const float* __restrict__ bv,
                                               const float* __restrict__ tab,
                                               float* __restrict__ bkf,
                                               float* __restrict__ bvf) {
    int l = blockIdx.x, c = threadIdx.x;
    float ep = tab[((size_t)l * (NTAB + 1) + NTAB) * CC + c];
    bkf[l * CC + c] = bk[l * CC + c] + ep;
    bvf[l * CC + c] = bv[l * CC + c] + ep;
}

// node weights: wn[((l*5+m)*128 + c)*128 + k] = bf16(W_m[l][k][c]); m: q,k,v,skip,l
__global__ void k_prepn(const float* __restrict__ wq, const float* __restrict__ wk,
                        const float* __restrict__ wv, const float* __restrict__ wsk,
                        const float* __restrict__ wl, u16* __restrict__ wn) {
    int i = blockIdx.x * 256 + threadIdx.x;
    if (i >= LL * 5 * 128 * 128) return;
    int k = i & 127, c = (i >> 7) & 127;
    int lm = i >> 14; int m = lm % 5, l = lm / 5;
    const float* W = (m == 0) ? wq : (m == 1) ? wk : (m == 2) ? wv : (m == 3) ? wsk : wl;
    wn[i] = f2bf(W[((size_t)l * 128 + k) * 128 + c]);
}

// ---------------- fused node kernel ----------------
// MODE 0: hb <- emb[z] (also writes h);         then 4 GEMMs -> q,kvw,skip
// MODE 1: tb <- tbuf; h += tb@wl (hb <- new h); then 4 GEMMs -> q,kvw,skip
// MODE 2: tb <- tbuf; h += tb@wl               (no next-layer GEMMs)
// kvw layout: per node 128 u32; u32[n*128+c]=k-pair(c,c+1) even c, [+1]=v-pair.
// NOTE: k/v biases passed in are ep_inf-folded.
template<int MODE>
__global__ __launch_bounds__(256) void k_node(
    const int* __restrict__ z, const float* __restrict__ emb,
    const float* __restrict__ tbuf,
    const u16* __restrict__ wlT, const float* __restrict__ bl,
    float* __restrict__ h,
    const u16* __restrict__ wq4,
    const float* __restrict__ bq, const float* __restrict__ bk,
    const float* __restrict__ bv, const float* __restrict__ bs,
    float* __restrict__ o_q, unsigned int* __restrict__ kvw,
    float* __restrict__ o_skip, int nrows)
{
    __shared__ __align__(16) short tb[128 * 136];
    __shared__ __align__(16) short hb[128 * 136];
    const int t = threadIdx.x, lane = t & 63, w = t >> 6;
    const int tx = lane & 15, tg = lane >> 4;
    const int n0 = blockIdx.x * 128;
    const f32x4 zf4 = { 0.0f, 0.0f, 0.0f, 0.0f };

    if (MODE == 0) {
        for (int idx = t; idx < 128 * 32; idx += 256) {
            int r = idx >> 5, kq = idx & 31;
            int n = n0 + r;
            float4 hv;
            if (n < nrows) {
                hv = *(const float4*)&emb[(size_t)z[n] * CC + kq * 4];
                *(float4*)&h[(size_t)n * CC + kq * 4] = hv;
            } else { hv.x = hv.y = hv.z = hv.w = 0.0f; }
            uint2 pk = make_uint2((unsigned)f2bf(hv.x) | ((unsigned)f2bf(hv.y) << 16),
                                  (unsigned)f2bf(hv.z) | ((unsigned)f2bf(hv.w) << 16));
            *(uint2*)&hb[r * 136 + kq * 4] = pk;
        }
        __syncthreads();
    } else {
        for (int idx = t; idx < 128 * 32; idx += 256) {
            int r = idx >> 5, kq = idx & 31;
            int n = n0 + r;
            float4 tv;
            if (n < nrows) tv = *(const float4*)&tbuf[(size_t)n * 128 + kq * 4];
            else { tv.x = tv.y = tv.z = tv.w = 0.0f; }
            uint2 pk = make_uint2((unsigned)f2bf(tv.x) | ((unsigned)f2bf(tv.y) << 16),
                                  (unsigned)f2bf(tv.z) | ((unsigned)f2bf(tv.w) << 16));
            *(uint2*)&tb[r * 136 + kq * 4] = pk;
        }
        __syncthreads();
        // GEMM tb @ wl -> new h; write h (f32) and hb (bf16)
        f32x4 acc[2][8];
        #pragma unroll
        for (int mt = 0; mt < 2; ++mt)
            #pragma unroll
            for (int nt = 0; nt < 8; ++nt) acc[mt][nt] = zf4;
        #pragma unroll
        for (int s = 0; s < 4; ++s) {
            bf16x8 af[2], bfr[8];
            #pragma unroll
            for (int mt = 0; mt < 2; ++mt)
                af[mt] = *(const bf16x8*)&wlT[(size_t)(w * 32 + mt * 16 + tx) * 128 + s * 32 + tg * 8];
            #pragma unroll
            for (int nt = 0; nt < 8; ++nt)
                bfr[nt] = *(const bf16x8*)&tb[(nt * 16 + tx) * 136 + s * 32 + tg * 8];
            #pragma unroll
            for (int mt = 0; mt < 2; ++mt)
                #pragma unroll
                for (int nt = 0; nt < 8; ++nt)
                    acc[mt][nt] = __builtin_amdgcn_mfma_f32_16x16x32_bf16(af[mt], bfr[nt], acc[mt][nt], 0, 0, 0);
        }
        #pragma unroll
        for (int mt = 0; mt < 2; ++mt) {
            int c0 = w * 32 + mt * 16 + tg * 4;
            float4 bb = *(const float4*)&bl[c0];
            #pragma unroll
            for (int nt = 0; nt < 8; ++nt) {
                int n = n0 + nt * 16 + tx;
                if (n < nrows) {
                    float4 hv = *(const float4*)&h[(size_t)n * 128 + c0];
                    hv.x += acc[mt][nt][0] + bb.x; hv.y += acc[mt][nt][1] + bb.y;
                    hv.z += acc[mt][nt][2] + bb.z; hv.w += acc[mt][nt][3] + bb.w;
                    *(float4*)&h[(size_t)n * 128 + c0] = hv;
                    if (MODE == 1) {
                        uint2 pk = make_uint2((unsigned)f2bf(hv.x) | ((unsigned)f2bf(hv.y) << 16),
                                              (unsigned)f2bf(hv.z) | ((unsigned)f2bf(hv.w) << 16));
                        *(uint2*)&hb[(nt * 16 + tx) * 136 + c0] = pk;
                    }
                }
            }
        }
        if (MODE == 1) __syncthreads();
    }

    if (MODE <= 1) {
        // 4 GEMMs from hb: m=0 q, m=1 k-pairs, m=2 v-pairs, m=3 skip
        #pragma unroll
        for (int m = 0; m < 4; ++m) {
            f32x4 acc[2][8];
            #pragma unroll
            for (int mt = 0; mt < 2; ++mt)
                #pragma unroll
                for (int nt = 0; nt < 8; ++nt) acc[mt][nt] = zf4;
            const u16* Wm = wq4 + (size_t)m * 16384;
            #pragma unroll
            for (int s = 0; s < 4; ++s) {
                bf16x8 af[2], bfr[8];
                #pragma unroll
                for (int mt = 0; mt < 2; ++mt)
                    af[mt] = *(const bf16x8*)&Wm[(size_t)(w * 32 + mt * 16 + tx) * 128 + s * 32 + tg * 8];
                #pragma unroll
                for (int nt = 0; nt < 8; ++nt)
                    bfr[nt] = *(const bf16x8*)&hb[(nt * 16 + tx) * 136 + s * 32 + tg * 8];
                #pragma unroll
                for (int mt = 0; mt < 2; ++mt)
                    #pragma unroll
                    for (int nt = 0; nt < 8; ++nt)
                        acc[mt][nt] = __builtin_amdgcn_mfma_f32_16x16x32_bf16(af[mt], bfr[nt], acc[mt][nt], 0, 0, 0);
            }
            const float* Bm = (m == 0) ? bq : (m == 1) ? bk : (m == 2) ? bv : bs;
            if (m == 0 || m == 3) {
                float* Om = (m == 0) ? o_q : o_skip;
                #pragma unroll
                for (int mt = 0; mt < 2; ++mt) {
                    int c0 = w * 32 + mt * 16 + tg * 4;
                    float4 bb = *(const float4*)&Bm[c0];
                    #pragma unroll
                    for (int nt = 0; nt < 8; ++nt) {
                        int n = n0 + nt * 16 + tx;
                        if (n < nrows) {
                            float4 ov;
                            ov.x = acc[mt][nt][0] + bb.x; ov.y = acc[mt][nt][1] + bb.y;
                            ov.z = acc[mt][nt][2] + bb.z; ov.w = acc[mt][nt][3] + bb.w;
                            *(float4*)&Om[(size_t)n * 128 + c0] = ov;
                        }
                    }
                }
            } else {
                const int off = (m == 1) ? 0 : 1;
                #pragma unroll
                for (int mt = 0; mt < 2; ++mt) {
                    int c0 = w * 32 + mt * 16 + tg * 4;
                    float4 bb = *(const float4*)&Bm[c0];
                    #pragma unroll
                    for (int nt = 0; nt < 8; ++nt) {
                        int n = n0 + nt * 16 + tx;
                        if (n < nrows) {
                            unsigned p01 = (unsigned)f2bf(acc[mt][nt][0] + bb.x)
                                         | ((unsigned)f2bf(acc[mt][nt][1] + bb.y) << 16);
                            unsigned p23 = (unsigned)f2bf(acc[mt][nt][2] + bb.z)
                                         | ((unsigned)f2bf(acc[mt][nt][3] + bb.w) << 16);
                            size_t base = (size_t)n * 128 + c0;
                            kvw[base + off] = p01;
                            kvw[base + 2 + off] = p23;
                        }
                    }
                }
            }
        }
    }
}

// ---------------- node-centric edge aggregation --------------------------------
// One wave per dst node; 2 channels/lane. Edges sorted far-first per node.
// Far edge (d>=DMAX): ep folded into kvw biases -> 1 kv gather + dot + exp.
// Near edge: + bf16 delta-table lerp. q pre-scaled by 0.25*log2(e); exp2f.
__global__ __launch_bounds__(256) void k_agg(
    const int* __restrict__ rowptr, const int* __restrict__ rowmid,
    const int* __restrict__ srcp, const int2* __restrict__ erec,
    const uint2* __restrict__ tabq, const float* __restrict__ qn,
    const unsigned int* __restrict__ kvw, const float* __restrict__ skip,
    float* __restrict__ tout)
{
    int wid0 = (blockIdx.x * 256 + threadIdx.x) >> 6;   // node id
    if (wid0 >= NN) return;
    const int wid = __builtin_amdgcn_readfirstlane(wid0);   // SGPR -> scalar loads
    const int ln = threadIdx.x & 63;
    const int c0 = ln * 2;   // head = ln>>3
    const float SC = 0.25f * 1.4426950408889634f;
    float2 q2 = *(const float2*)&qn[(size_t)wid * CC + c0];
    q2.x *= SC; q2.y *= SC;
    float nx = 0.0f, ny = 0.0f, den = 0.0f;
    int e = rowptr[wid];
    const int emid = rowmid[wid];
    const int eend = rowptr[wid + 1];
    const float FS = 1.52587890625e-5f;   // 1/65536

    auto edgeF = [&](uint2 kv) {
        float kex = __uint_as_float(kv.x << 16);
        float key = __uint_as_float(kv.x & 0xffff0000u);
        float vex = __uint_as_float(kv.y << 16);
        float vey = __uint_as_float(kv.y & 0xffff0000u);
        float p = fmaf(q2.x, kex, q2.y * key);
        p += __shfl_xor(p, 1);
        p += __shfl_xor(p, 2);
        p += __shfl_xor(p, 4);          // sum over the head's 16 channels
        float w = exp2f(p);
        nx = fmaf(w, vex, nx);
        ny = fmaf(w, vey, ny);
        den += w;
    };
    auto edgeN = [&](uint2 kv, uint2 tp, float fr) {
        float t0x = __uint_as_float(tp.x << 16);
        float t0y = __uint_as_float(tp.x & 0xffff0000u);
        float t1x = __uint_as_float(tp.y << 16);
        float t1y = __uint_as_float(tp.y & 0xffff0000u);
        float ex = fmaf(fr, t1x - t0x, t0x);
        float ey = fmaf(fr, t1y - t0y, t0y);
        float kex = __uint_as_float(kv.x << 16) + ex;
        float key = __uint_as_float(kv.x & 0xffff0000u) + ey;
        float vex = __uint_as_float(kv.y << 16) + ex;
        float vey = __uint_as_float(kv.y & 0xffff0000u) + ey;
        float p = fmaf(q2.x, kex, q2.y * key);
        p += __shfl_xor(p, 1);
        p += __shfl_xor(p, 2);
        p += __shfl_xor(p, 4);
        float w = exp2f(p);
        nx = fmaf(w, vex, nx);
        ny = fmaf(w, vey, ny);
        den += w;
    };

    // ---- far edges, 8-deep ----
    for (; e + 8 <= emid; e += 8) {
        int s0 = srcp[e + 0], s1 = srcp[e + 1], s2 = srcp[e + 2], s3 = srcp[e + 3];
        int s4 = srcp[e + 4], s5 = srcp[e + 5], s6 = srcp[e + 6], s7 = srcp[e + 7];
        uint2 kv0 = *(const uint2*)&kvw[(size_t)s0 * 128 + c0];
        uint2 kv1 = *(const uint2*)&kvw[(size_t)s1 * 128 + c0];
        uint2 kv2 = *(const uint2*)&kvw[(size_t)s2 * 128 + c0];
        uint2 kv3 = *(const uint2*)&kvw[(size_t)s3 * 128 + c0];
        uint2 kv4 = *(const uint2*)&kvw[(size_t)s4 * 128 + c0];
        uint2 kv5 = *(const uint2*)&kvw[(size_t)s5 * 128 + c0];
        uint2 kv6 = *(const uint2*)&kvw[(size_t)s6 * 128 + c0];
        uint2 kv7 = *(const uint2*)&kvw[(size_t)s7 * 128 + c0];
        edgeF(kv0); edgeF(kv1); edgeF(kv2); edgeF(kv3);
        edgeF(kv4); edgeF(kv5); edgeF(kv6); edgeF(kv7);
    }
    for (; e < emid; ++e) {
        uint2 kv = *(const uint2*)&kvw[(size_t)srcp[e] * 128 + c0];
        edgeF(kv);
    }
    // ---- near edges, 4-deep ----
    for (; e + 4 <= eend; e += 4) {
        int2 r0 = erec[e + 0], r1 = erec[e + 1], r2 = erec[e + 2], r3 = erec[e + 3];
        uint2 kv0 = *(const uint2*)&kvw[(size_t)r0.x * 128 + c0];
        uint2 kv1 = *(const uint2*)&kvw[(size_t)r1.x * 128 + c0];
        uint2 kv2 = *(const uint2*)&kvw[(size_t)r2.x * 128 + c0];
        uint2 kv3 = *(const uint2*)&kvw[(size_t)r3.x * 128 + c0];
        uint2 tp0 = tabq[(size_t)(r0.y >> 16) * 64 + ln];
        uint2 tp1 = tabq[(size_t)(r1.y >> 16) * 64 + ln];
        uint2 tp2 = tabq[(size_t)(r2.y >> 16) * 64 + ln];
        uint2 tp3 = tabq[(size_t)(r3.y >> 16) * 64 + ln];
        edgeN(kv0, tp0, (float)(r0.y & 0xffff) * FS);
        edgeN(kv1, tp1, (float)(r1.y & 0xffff) * FS);
        edgeN(kv2, tp2, (float)(r2.y & 0xffff) * FS);
        edgeN(kv3, tp3, (float)(r3.y & 0xffff) * FS);
    }
    for (; e < eend; ++e) {
        int2 r = erec[e];
        uint2 kv = *(const uint2*)&kvw[(size_t)r.x * 128 + c0];
        uint2 tp = tabq[(size_t)(r.y >> 16) * 64 + ln];
        edgeN(kv, tp, (float)(r.y & 0xffff) * FS);
    }

    const float2 sk = *(const float2*)&skip[(size_t)wid * CC + c0];
    float inv = 1.0f / (den + 1e-16f);
    float2 o;
    o.x = sspf(fmaf(nx, inv, sk.x));
    o.y = sspf(fmaf(ny, inv, sk.y));
    *(float2*)&tout[(size_t)wid * CC + c0] = o;
}

// ---------------- output head ----------------
__global__ __launch_bounds__(64) void k_head(
    const float* __restrict__ h,
    const float* __restrict__ w1, const float* __restrict__ b1,
    const float* __restrict__ w2, const float* __restrict__ b2,
    float* __restrict__ out)
{
    const int n = blockIdx.x;
    const int j = threadIdx.x;
    float acc = 0.0f;
    for (int k = 0; k < CC; ++k)
        acc = fmaf(h[(size_t)n * CC + k], w1[k * 64 + j], acc);
    float m = sspf(acc + b1[j]);
    float o = m * w2[j];
    #pragma unroll
    for (int msk = 32; msk > 0; msk >>= 1) o += __shfl_xor(o, msk);
    if (j == 0) out[n] = o + b2[0];
}

extern "C" void kernel_launch(void* const* d_in, const int* in_sizes, int n_in,
                              void* d_out, int out_size, void* d_ws, size_t ws_size,
                              hipStream_t stream)
{
    const int*   z   = (const int*)d_in[0];
    const float* pos = (const float*)d_in[1];
    const int*   ei  = (const int*)d_in[2];
    const float* emb = (const float*)d_in[3];
    const float* w1  = (const float*)d_in[4];
    const float* b1  = (const float*)d_in[5];
    const float* w2  = (const float*)d_in[6];
    const float* b2  = (const float*)d_in[7];
    const float* wq  = (const float*)d_in[8];
    const float* bq  = (const float*)d_in[9];
    const float* wk  = (const float*)d_in[10];
    const float* bk  = (const float*)d_in[11];
    const float* wv  = (const float*)d_in[12];
    const float* bv  = (const float*)d_in[13];
    const float* we  = (const float*)d_in[14];
    const float* be  = (const float*)d_in[15];
    const float* wsk = (const float*)d_in[16];
    const float* bsk = (const float*)d_in[17];
    const float* wl  = (const float*)d_in[18];
    const float* bl  = (const float*)d_in[19];
    const float* wo1 = (const float*)d_in[20];
    const float* bo1 = (const float*)d_in[21];
    const float* wo2 = (const float*)d_in[22];
    const float* bo2 = (const float*)d_in[23];

    char* p = (char*)d_ws;
    auto alloc = [&](size_t bytes) -> void* {
        void* r = (void*)p; p += (bytes + 255) & ~(size_t)255; return r;
    };
    float* h    = (float*)alloc((size_t)NN * CC * 4);
    float* q    = (float*)alloc((size_t)NN * CC * 4);
    float* skip = (float*)alloc((size_t)NN * CC * 4);
    float* tbuf = (float*)alloc((size_t)NN * CC * 4);
    unsigned int* kvw = (unsigned int*)alloc((size_t)NN * 128 * 4);  // bf16 k/v pairs
    float* w23f = (float*)alloc((size_t)LL * FF * CC * 4);
    float* b23g = (float*)alloc((size_t)LL * CC * 4);
    float* tab  = (float*)alloc((size_t)LL * (NTAB + 1) * CC * 4);
    uint2* tabq = (uint2*)alloc((size_t)LL * NTAB * 64 * 8);
    float* bkf  = (float*)alloc((size_t)LL * CC * 4);
    float* bvf  = (float*)alloc((size_t)LL * CC * 4);
    u16*   wn   = (u16*)alloc((size_t)LL * 5 * 128 * 128 * 2);
    int* cnt2   = (int*)alloc((size_t)2 * NN * 4);     // cnt | cntF
    int* rowptr = (int*)alloc((size_t)(NN + 1) * 4);
    int* rowmid = (int*)alloc((size_t)NN * 4);
    int* curF   = (int*)alloc((size_t)NN * 4);
    int* curN   = (int*)alloc((size_t)NN * 4);
    int* srcp   = (int*)alloc((size_t)NE * 4);
    int2* erec  = (int2*)alloc((size_t)NE * 8);
    int* cnt  = cnt2;
    int* cntF = cnt2 + NN;

    k_zero<<<(2 * NN + 255) / 256, 256, 0, stream>>>(cnt2, 2 * NN);
    k_hist<<<(NE + 255) / 256, 256, 0, stream>>>(ei, pos, cnt, cntF);
    k_scan<<<1, 1024, 0, stream>>>(cnt, rowptr, curF);
    k_mid<<<(NN + 255) / 256, 256, 0, stream>>>(rowptr, cntF, rowmid, curN);
    k_scatter<<<(NE + 255) / 256, 256, 0, stream>>>(ei, pos, curF, curN, srcp, erec);
    k_prep23<<<LL * 128, 128, 0, stream>>>(w2, we, w23f);
    k_prepb<<<LL, 128, 0, stream>>>(b2, we, be, b23g);
    k_prept<<<LL * (NTAB + 1), 128, 0, stream>>>(w1, b1, w23f, b23g, tab);
    k_packt<<<(LL * NTAB * 64 + 255) / 256, 256, 0, stream>>>(tab, tabq);
    k_foldb<<<LL, 128, 0, stream>>>(bk, bv, tab, bkf, bvf);
    k_prepn<<<(LL * 5 * 128 * 128 + 255) / 256, 256, 0, stream>>>(wq, wk, wv, wsk, wl, wn);

    const int NT = (NN + 127) / 128;   // 157
    // layer 0 q/k/v/skip from emb[z] (writes h too)
    k_node<0><<<NT, 256, 0, stream>>>(z, emb, nullptr, nullptr, nullptr, h,
        wn, bq, bkf, bvf, bsk, q, kvw, skip, NN);
    for (int l = 0; l < LL; ++l) {
        k_agg<<<(NN * 64 + 255) / 256, 256, 0, stream>>>(rowptr, rowmid, srcp, erec,
            tabq + (size_t)l * NTAB * 64, q, kvw, skip, tbuf);
        const u16* wnl = wn + (size_t)l * 5 * 16384;
        if (l < LL - 1) {
            const u16* wnn = wn + (size_t)(l + 1) * 5 * 16384;
            k_node<1><<<NT, 256, 0, stream>>>(nullptr, nullptr, tbuf,
                wnl + 4 * 16384, bl + l * CC, h,
                wnn, bq + (l + 1) * CC, bkf + (l + 1) * CC,
                bvf + (l + 1) * CC, bsk + (l + 1) * CC,
                q, kvw, skip, NN);
        } else {
            k_node<2><<<NT, 256, 0, stream>>>(nullptr, nullptr, tbuf,
                wnl + 4 * 16384, bl + l * CC, h,
                nullptr, nullptr, nullptr, nullptr, nullptr,
                nullptr, nullptr, nullptr, NN);
        }
    }
    k_head<<<NN, 64, 0, stream>>>(h, wo1, bo1, wo2, bo2, (float*)d_out);
}

// Round 16
// 394.588 us; speedup vs baseline: 3.3899x; 1.0582x over previous
//
#include <hip/hip_runtime.h>

#define NN 20000
#define NE 640000
#define CC 128
#define HH 8
#define GG 50
#define FF 128
#define LL 3
#define NTAB 2048
#define DMAX 12.0f

typedef unsigned short u16;
typedef __attribute__((ext_vector_type(8))) short bf16x8;   // 8 bf16 = 4 VGPRs
typedef __attribute__((ext_vector_type(4))) float f32x4;

__device__ __forceinline__ u16 f2bf(float f) {
    union { float f; unsigned int i; } x; x.f = f;
    unsigned int r = x.i + 0x7fffu + ((x.i >> 16) & 1u);
    return (u16)(r >> 16);
}
// ShiftedSoftplus: softplus(x)-log2 via HW exp/log
__device__ __forceinline__ float sspf(float x) {
    return fmaxf(x, 0.0f) + __logf(1.0f + __expf(-fabsf(x))) - 0.69314718055994531f;
}

// ---------------- CSR build (sort edges by dst; far edges first per node) ------
__global__ void k_zero(int* __restrict__ c, int n) {
    int i = blockIdx.x * 256 + threadIdx.x;
    if (i < n) c[i] = 0;
}

__global__ void k_pos4(const float* __restrict__ pos, float4* __restrict__ pos4) {
    int n = blockIdx.x * 256 + threadIdx.x;
    if (n < NN) {
        float4 v;
        v.x = pos[n * 3 + 0]; v.y = pos[n * 3 + 1]; v.z = pos[n * 3 + 2]; v.w = 0.0f;
        pos4[n] = v;
    }
}

// one pass: distance record + per-node histograms (cnt always, cntN if near)
// drec[e] = -1 (far) or (i0<<16)|frac16 (near; i0<=2046 so never -1)
__global__ void k_dist(const int* __restrict__ ei, const float4* __restrict__ pos4,
                       int* __restrict__ cnt, int* __restrict__ cntN,
                       int* __restrict__ drec) {
    int e = blockIdx.x * 256 + threadIdx.x;
    if (e >= NE) return;
    int a = ei[e], b = ei[NE + e];
    float4 pa = pos4[a], pb = pos4[b];
    float dx = pb.x - pa.x, dy = pb.y - pa.y, dz = pb.z - pa.z;
    float d = sqrtf(dx * dx + dy * dy + dz * dz + 1e-12f);
    float tt = d * ((float)NTAB / DMAX);
    bool far = tt >= (float)(NTAB - 1);
    int rec = -1;
    if (!far) {
        int i0 = (int)tt;
        int fr = min((int)((tt - (float)i0) * 65536.0f), 65535);
        rec = (i0 << 16) | fr;
    }
    drec[e] = rec;
    atomicAdd(&cnt[b], 1);
    if (!far) atomicAdd(&cntN[b], 1);
}

__global__ __launch_bounds__(1024) void k_scan(const int* __restrict__ cnt,
                                               int* __restrict__ rowptr,
                                               int* __restrict__ curF) {
    __shared__ int sums[1024];
    const int t = threadIdx.x;
    int local[20];
    int base = t * 20;
    int s = 0;
    #pragma unroll
    for (int i = 0; i < 20; ++i) {
        int idx = base + i;
        int v = (idx < NN) ? cnt[idx] : 0;
        local[i] = s; s += v;
    }
    sums[t] = s;
    __syncthreads();
    for (int off = 1; off < 1024; off <<= 1) {
        int v = (t >= off) ? sums[t - off] : 0;
        __syncthreads();
        sums[t] += v;
        __syncthreads();
    }
    int excl = (t == 0) ? 0 : sums[t - 1];
    #pragma unroll
    for (int i = 0; i < 20; ++i) {
        int idx = base + i;
        if (idx < NN) { int r = excl + local[i]; rowptr[idx] = r; curF[idx] = r; }
    }
    if (t == 1023) rowptr[NN] = sums[1023];
}

// rowmid[n] = rowptr[n+1] - cntN[n]; near cursor starts at rowmid
__global__ void k_mid(const int* __restrict__ rowptr, const int* __restrict__ cntN,
                      int* __restrict__ rowmid, int* __restrict__ curN) {
    int n = blockIdx.x * 256 + threadIdx.x;
    if (n < NN) { int m = rowptr[n + 1] - cntN[n]; rowmid[n] = m; curN[n] = m; }
}

// far edges -> [rowptr, rowmid) need only src; near -> [rowmid, rowptr+1) get erec
__global__ void k_scatter(const int* __restrict__ ei, const int* __restrict__ drec,
                          int* __restrict__ curF, int* __restrict__ curN,
                          int* __restrict__ srcp, int2* __restrict__ erec) {
    int e = blockIdx.x * 256 + threadIdx.x;
    if (e >= NE) return;
    int a = ei[e], b = ei[NE + e];
    int rec = drec[e];
    bool far = (rec == -1);
    int pp = atomicAdd(far ? &curF[b] : &curN[b], 1);
    srcp[pp] = a;
    if (!far) { int2 r; r.x = a; r.y = rec; erec[pp] = r; }
}

// ---------------- weight prep (once per call) ----------------
// W23f[l][k][cp] = sum_c w2[l][k][c] * we[l][c][cp]  (fp32)
__global__ __launch_bounds__(128) void k_prep23(const float* __restrict__ w2,
                                                const float* __restrict__ we,
                                                float* __restrict__ w23f) {
    int l = blockIdx.x >> 7, k = blockIdx.x & 127;
    int cp = threadIdx.x;
    float s = 0.0f;
    for (int c = 0; c < FF; ++c)
        s = fmaf(w2[((size_t)l * FF + k) * FF + c], we[((size_t)l * FF + c) * CC + cp], s);
    w23f[((size_t)l * FF + k) * CC + cp] = s;
}

// b23[l][cp] = be[l][cp] + sum_k b2[l][k] * we[l][k][cp]
__global__ __launch_bounds__(128) void k_prepb(const float* __restrict__ b2,
                                               const float* __restrict__ we,
                                               const float* __restrict__ be,
                                               float* __restrict__ b23g) {
    int l = blockIdx.x;
    int cp = threadIdx.x;
    float s = be[l * CC + cp];
    for (int k = 0; k < FF; ++k)
        s = fmaf(b2[l * FF + k], we[((size_t)l * FF + k) * CC + cp], s);
    b23g[l * CC + cp] = s;
}

// ep table: tab[l][i][cp] = MLP(gauss(d_i)) exact fp32, i in [0,NTAB]
__global__ __launch_bounds__(128) void k_prept(const float* __restrict__ w1,
                                               const float* __restrict__ b1,
                                               const float* __restrict__ w23f,
                                               const float* __restrict__ b23g,
                                               float* __restrict__ tab) {
    const int l = blockIdx.x / (NTAB + 1);
    const int i = blockIdx.x % (NTAB + 1);
    const int c = threadIdx.x;
    __shared__ float attr[GG];
    __shared__ float hid[FF];
    const float STEP = 10.0f / 49.0f;
    const float COEF = -0.5f / (STEP * STEP);
    float d = (float)i * (DMAX / (float)NTAB);
    if (c < GG) { float df = d - STEP * (float)c; attr[c] = __expf(COEF * df * df); }
    __syncthreads();
    float s = b1[l * FF + c];
    for (int g = 0; g < GG; ++g)
        s = fmaf(attr[g], w1[((size_t)l * GG + g) * FF + c], s);
    hid[c] = sspf(s);
    __syncthreads();
    float o = b23g[l * CC + c];
    for (int k = 0; k < FF; ++k)
        o = fmaf(hid[k], w23f[((size_t)l * FF + k) * CC + c], o);
    tab[((size_t)l * (NTAB + 1) + i) * CC + c] = o;
}

// bf16 DELTA table pairs: tabq[l][i][ln] = { bf16(tab[i]-ep_inf) pair, bf16(tab[i+1]-ep_inf) pair }
__global__ void k_packt(const float* __restrict__ tab, uint2* __restrict__ tabq) {
    int idx = blockIdx.x * 256 + threadIdx.x;
    if (idx >= LL * NTAB * 64) return;
    int ln = idx & 63;
    int i = (idx >> 6) % NTAB;
    int l = idx / (NTAB * 64);
    int c0 = ln * 2;
    const float* t0 = &tab[((size_t)l * (NTAB + 1) + i) * CC + c0];
    const float* t1 = t0 + CC;
    const float* ti = &tab[((size_t)l * (NTAB + 1) + NTAB) * CC + c0];
    uint2 o;
    o.x = (unsigned)f2bf(t0[0] - ti[0]) | ((unsigned)f2bf(t0[1] - ti[1]) << 16);
    o.y = (unsigned)f2bf(t1[0] - ti[0]) | ((unsigned)f2bf(t1[1] - ti[1]) << 16);
    tabq[((size_t)l * NTAB + i) * 64 + ln] = o;
}

// fold ep_inf into k/v biases: bkf = bk + ep_inf, bvf = bv + ep_inf
__global__ __launch_bounds__(128) void k_foldb(const float* __restrict__ bk,
                                               const float* __restrict__ bv,
                                               const float* __restrict__ tab,
                                               float* __restrict__ bkf,
                                               float* __restrict__ bvf) {
    int l = blockIdx.x, c = threadIdx.x;
    float ep = tab[((size_t)l * (NTAB + 1) + NTAB) * CC + c];
    bkf[l * CC + c] = bk[l * CC + c] + ep;
    bvf[l * CC + c] = bv[l * CC + c] + ep;
}

// node weights: wn[((l*5+m)*128 + c)*128 + k] = bf16(W_m[l][k][c]); m: q,k,v,skip,l
__global__ void k_prepn(const float* __restrict__ wq, const float* __restrict__ wk,
                        const float* __restrict__ wv, const float* __restrict__ wsk,
                        const float* __restrict__ wl, u16* __restrict__ wn) {
    int i = blockIdx.x * 256 + threadIdx.x;
    if (i >= LL * 5 * 128 * 128) return;
    int k = i & 127, c = (i >> 7) & 127;
    int lm = i >> 14; int m = lm % 5, l = lm / 5;
    const float* W = (m == 0) ? wq : (m == 1) ? wk : (m == 2) ? wv : (m == 3) ? wsk : wl;
    wn[i] = f2bf(W[((size_t)l * 128 + k) * 128 + c]);
}

// ---------------- fused node kernel (64-row tiles, 313 blocks) ----------------
// MODE 0: hb <- emb[z] (also writes h);         then 4 GEMMs -> q,kvw,skip
// MODE 1: tb <- tbuf; h += tb@wl (hb <- new h); then 4 GEMMs -> q,kvw,skip
// MODE 2: tb <- tbuf; h += tb@wl               (no next-layer GEMMs)
// kvw layout: per node 128 u32; u32[n*128+c]=k-pair(c,c+1) even c, [+1]=v-pair.
// NOTE: k/v biases passed in are ep_inf-folded.
template<int MODE>
__global__ __launch_bounds__(256) void k_node(
    const int* __restrict__ z, const float* __restrict__ emb,
    const float* __restrict__ tbuf,
    const u16* __restrict__ wlT, const float* __restrict__ bl,
    float* __restrict__ h,
    const u16* __restrict__ wq4,
    const float* __restrict__ bq, const float* __restrict__ bk,
    const float* __restrict__ bv, const float* __restrict__ bs,
    float* __restrict__ o_q, unsigned int* __restrict__ kvw,
    float* __restrict__ o_skip, int nrows)
{
    __shared__ __align__(16) short tb[64 * 136];
    __shared__ __align__(16) short hb[64 * 136];
    const int t = threadIdx.x, lane = t & 63, w = t >> 6;
    const int tx = lane & 15, tg = lane >> 4;
    const int n0 = blockIdx.x * 64;
    const f32x4 zf4 = { 0.0f, 0.0f, 0.0f, 0.0f };

    if (MODE == 0) {
        for (int idx = t; idx < 64 * 32; idx += 256) {
            int r = idx >> 5, kq = idx & 31;
            int n = n0 + r;
            float4 hv;
            if (n < nrows) {
                hv = *(const float4*)&emb[(size_t)z[n] * CC + kq * 4];
                *(float4*)&h[(size_t)n * CC + kq * 4] = hv;
            } else { hv.x = hv.y = hv.z = hv.w = 0.0f; }
            uint2 pk = make_uint2((unsigned)f2bf(hv.x) | ((unsigned)f2bf(hv.y) << 16),
                                  (unsigned)f2bf(hv.z) | ((unsigned)f2bf(hv.w) << 16));
            *(uint2*)&hb[r * 136 + kq * 4] = pk;
        }
        __syncthreads();
    } else {
        for (int idx = t; idx < 64 * 32; idx += 256) {
            int r = idx >> 5, kq = idx & 31;
            int n = n0 + r;
            float4 tv;
            if (n < nrows) tv = *(const float4*)&tbuf[(size_t)n * 128 + kq * 4];
            else { tv.x = tv.y = tv.z = tv.w = 0.0f; }
            uint2 pk = make_uint2((unsigned)f2bf(tv.x) | ((unsigned)f2bf(tv.y) << 16),
                                  (unsigned)f2bf(tv.z) | ((unsigned)f2bf(tv.w) << 16));
            *(uint2*)&tb[r * 136 + kq * 4] = pk;
        }
        __syncthreads();
        // GEMM tb @ wl -> new h; write h (f32) and hb (bf16)
        f32x4 acc[2][4];
        #pragma unroll
        for (int mt = 0; mt < 2; ++mt)
            #pragma unroll
            for (int nt = 0; nt < 4; ++nt) acc[mt][nt] = zf4;
        #pragma unroll
        for (int s = 0; s < 4; ++s) {
            bf16x8 af[2], bfr[4];
            #pragma unroll
            for (int mt = 0; mt < 2; ++mt)
                af[mt] = *(const bf16x8*)&wlT[(size_t)(w * 32 + mt * 16 + tx) * 128 + s * 32 + tg * 8];
            #pragma unroll
            for (int nt = 0; nt < 4; ++nt)
                bfr[nt] = *(const bf16x8*)&tb[(nt * 16 + tx) * 136 + s * 32 + tg * 8];
            #pragma unroll
            for (int mt = 0; mt < 2; ++mt)
                #pragma unroll
                for (int nt = 0; nt < 4; ++nt)
                    acc[mt][nt] = __builtin_amdgcn_mfma_f32_16x16x32_bf16(af[mt], bfr[nt], acc[mt][nt], 0, 0, 0);
        }
        #pragma unroll
        for (int mt = 0; mt < 2; ++mt) {
            int c0 = w * 32 + mt * 16 + tg * 4;
            float4 bb = *(const float4*)&bl[c0];
            #pragma unroll
            for (int nt = 0; nt < 4; ++nt) {
                int n = n0 + nt * 16 + tx;
                if (n < nrows) {
                    float4 hv = *(const float4*)&h[(size_t)n * 128 + c0];
                    hv.x += acc[mt][nt][0] + bb.x; hv.y += acc[mt][nt][1] + bb.y;
                    hv.z += acc[mt][nt][2] + bb.z; hv.w += acc[mt][nt][3] + bb.w;
                    *(float4*)&h[(size_t)n * 128 + c0] = hv;
                    if (MODE == 1) {
                        uint2 pk = make_uint2((unsigned)f2bf(hv.x) | ((unsigned)f2bf(hv.y) << 16),
                                              (unsigned)f2bf(hv.z) | ((unsigned)f2bf(hv.w) << 16));
                        *(uint2*)&hb[(nt * 16 + tx) * 136 + c0] = pk;
                    }
                }
            }
        }
        if (MODE == 1) __syncthreads();
    }

    if (MODE <= 1) {
        // 4 GEMMs from hb: m=0 q, m=1 k-pairs, m=2 v-pairs, m=3 skip
        #pragma unroll
        for (int m = 0; m < 4; ++m) {
            f32x4 acc[2][4];
            #pragma unroll
            for (int mt = 0; mt < 2; ++mt)
                #pragma unroll
                for (int nt = 0; nt < 4; ++nt) acc[mt][nt] = zf4;
            const u16* Wm = wq4 + (size_t)m * 16384;
            #pragma unroll
            for (int s = 0; s < 4; ++s) {
                bf16x8 af[2], bfr[4];
                #pragma unroll
                for (int mt = 0; mt < 2; ++mt)
                    af[mt] = *(const bf16x8*)&Wm[(size_t)(w * 32 + mt * 16 + tx) * 128 + s * 32 + tg * 8];
                #pragma unroll
                for (int nt = 0; nt < 4; ++nt)
                    bfr[nt] = *(const bf16x8*)&hb[(nt * 16 + tx) * 136 + s * 32 + tg * 8];
                #pragma unroll
                for (int mt = 0; mt < 2; ++mt)
                    #pragma unroll
                    for (int nt = 0; nt < 4; ++nt)
                        acc[mt][nt] = __builtin_amdgcn_mfma_f32_16x16x32_bf16(af[mt], bfr[nt], acc[mt][nt], 0, 0, 0);
            }
            const float* Bm = (m == 0) ? bq : (m == 1) ? bk : (m == 2) ? bv : bs;
            if (m == 0 || m == 3) {
                float* Om = (m == 0) ? o_q : o_skip;
                #pragma unroll
                for (int mt = 0; mt < 2; ++mt) {
                    int c0 = w * 32 + mt * 16 + tg * 4;
                    float4 bb = *(const float4*)&Bm[c0];
                    #pragma unroll
                    for (int nt = 0; nt < 4; ++nt) {
                        int n = n0 + nt * 16 + tx;
                        if (n < nrows) {
                            float4 ov;
                            ov.x = acc[mt][nt][0] + bb.x; ov.y = acc[mt][nt][1] + bb.y;
                            ov.z = acc[mt][nt][2] + bb.z; ov.w = acc[mt][nt][3] + bb.w;
                            *(float4*)&Om[(size_t)n * 128 + c0] = ov;
                        }
                    }
                }
            } else {
                const int off = (m == 1) ? 0 : 1;
                #pragma unroll
                for (int mt = 0; mt < 2; ++mt) {
                    int c0 = w * 32 + mt * 16 + tg * 4;
                    float4 bb = *(const float4*)&Bm[c0];
                    #pragma unroll
                    for (int nt = 0; nt < 4; ++nt) {
                        int n = n0 + nt * 16 + tx;
                        if (n < nrows) {
                            unsigned p01 = (unsigned)f2bf(acc[mt][nt][0] + bb.x)
                                         | ((unsigned)f2bf(acc[mt][nt][1] + bb.y) << 16);
                            unsigned p23 = (unsigned)f2bf(acc[mt][nt][2] + bb.z)
                                         | ((unsigned)f2bf(acc[mt][nt][3] + bb.w) << 16);
                            size_t base = (size_t)n * 128 + c0;
                            kvw[base + off] = p01;
                            kvw[base + 2 + off] = p23;
                        }
                    }
                }
            }
        }
    }
}

// ---------------- node-centric edge aggregation --------------------------------
// One wave per dst node; 2 channels/lane. Edges sorted far-first per node.
// Far edge (d>=DMAX): ep folded into kvw biases -> 1 kv gather + dot + exp.
// Near edge: + bf16 delta-table lerp. q pre-scaled by 0.25*log2(e); exp2f.
__global__ __launch_bounds__(256) void k_agg(
    const int* __restrict__ rowptr, const int* __restrict__ rowmid,
    const int* __restrict__ srcp, const int2* __restrict__ erec,
    const uint2* __restrict__ tabq, const float* __restrict__ qn,
    const unsigned int* __restrict__ kvw, const float* __restrict__ skip,
    float* __restrict__ tout)
{
    int wid0 = (blockIdx.x * 256 + threadIdx.x) >> 6;   // node id
    if (wid0 >= NN) return;
    const int wid = __builtin_amdgcn_readfirstlane(wid0);   // SGPR -> scalar loads
    const int ln = threadIdx.x & 63;
    const int c0 = ln * 2;   // head = ln>>3
    const float SC = 0.25f * 1.4426950408889634f;
    float2 q2 = *(const float2*)&qn[(size_t)wid * CC + c0];
    q2.x *= SC; q2.y *= SC;
    float nx = 0.0f, ny = 0.0f, den = 0.0f;
    int e = rowptr[wid];
    const int emid = rowmid[wid];
    const int eend = rowptr[wid + 1];
    const float FS = 1.52587890625e-5f;   // 1/65536

    auto edgeF = [&](uint2 kv) {
        float kex = __uint_as_float(kv.x << 16);
        float key = __uint_as_float(kv.x & 0xffff0000u);
        float vex = __uint_as_float(kv.y << 16);
        float vey = __uint_as_float(kv.y & 0xffff0000u);
        float p = fmaf(q2.x, kex, q2.y * key);
        p += __shfl_xor(p, 1);
        p += __shfl_xor(p, 2);
        p += __shfl_xor(p, 4);          // sum over the head's 16 channels
        float w = exp2f(p);
        nx = fmaf(w, vex, nx);
        ny = fmaf(w, vey, ny);
        den += w;
    };
    auto edgeN = [&](uint2 kv, uint2 tp, float fr) {
        float t0x = __uint_as_float(tp.x << 16);
        float t0y = __uint_as_float(tp.x & 0xffff0000u);
        float t1x = __uint_as_float(tp.y << 16);
        float t1y = __uint_as_float(tp.y & 0xffff0000u);
        float ex = fmaf(fr, t1x - t0x, t0x);
        float ey = fmaf(fr, t1y - t0y, t0y);
        float kex = __uint_as_float(kv.x << 16) + ex;
        float key = __uint_as_float(kv.x & 0xffff0000u) + ey;
        float vex = __uint_as_float(kv.y << 16) + ex;
        float vey = __uint_as_float(kv.y & 0xffff0000u) + ey;
        float p = fmaf(q2.x, kex, q2.y * key);
        p += __shfl_xor(p, 1);
        p += __shfl_xor(p, 2);
        p += __shfl_xor(p, 4);
        float w = exp2f(p);
        nx = fmaf(w, vex, nx);
        ny = fmaf(w, vey, ny);
        den += w;
    };

    // ---- far edges, 8-deep ----
    for (; e + 8 <= emid; e += 8) {
        int s0 = srcp[e + 0], s1 = srcp[e + 1], s2 = srcp[e + 2], s3 = srcp[e + 3];
        int s4 = srcp[e + 4], s5 = srcp[e + 5], s6 = srcp[e + 6], s7 = srcp[e + 7];
        uint2 kv0 = *(const uint2*)&kvw[(size_t)s0 * 128 + c0];
        uint2 kv1 = *(const uint2*)&kvw[(size_t)s1 * 128 + c0];
        uint2 kv2 = *(const uint2*)&kvw[(size_t)s2 * 128 + c0];
        uint2 kv3 = *(const uint2*)&kvw[(size_t)s3 * 128 + c0];
        uint2 kv4 = *(const uint2*)&kvw[(size_t)s4 * 128 + c0];
        uint2 kv5 = *(const uint2*)&kvw[(size_t)s5 * 128 + c0];
        uint2 kv6 = *(const uint2*)&kvw[(size_t)s6 * 128 + c0];
        uint2 kv7 = *(const uint2*)&kvw[(size_t)s7 * 128 + c0];
        edgeF(kv0); edgeF(kv1); edgeF(kv2); edgeF(kv3);
        edgeF(kv4); edgeF(kv5); edgeF(kv6); edgeF(kv7);
    }
    for (; e < emid; ++e) {
        uint2 kv = *(const uint2*)&kvw[(size_t)srcp[e] * 128 + c0];
        edgeF(kv);
    }
    // ---- near edges, 4-deep ----
    for (; e + 4 <= eend; e += 4) {
        int2 r0 = erec[e + 0], r1 = erec[e + 1], r2 = erec[e + 2], r3 = erec[e + 3];
        uint2 kv0 = *(const uint2*)&kvw[(size_t)r0.x * 128 + c0];
        uint2 kv1 = *(const uint2*)&kvw[(size_t)r1.x * 128 + c0];
        uint2 kv2 = *(const uint2*)&kvw[(size_t)r2.x * 128 + c0];
        uint2 kv3 = *(const uint2*)&kvw[(size_t)r3.x * 128 + c0];
        uint2 tp0 = tabq[(size_t)(r0.y >> 16) * 64 + ln];
        uint2 tp1 = tabq[(size_t)(r1.y >> 16) * 64 + ln];
        uint2 tp2 = tabq[(size_t)(r2.y >> 16) * 64 + ln];
        uint2 tp3 = tabq[(size_t)(r3.y >> 16) * 64 + ln];
        edgeN(kv0, tp0, (float)(r0.y & 0xffff) * FS);
        edgeN(kv1, tp1, (float)(r1.y & 0xffff) * FS);
        edgeN(kv2, tp2, (float)(r2.y & 0xffff) * FS);
        edgeN(kv3, tp3, (float)(r3.y & 0xffff) * FS);
    }
    for (; e < eend; ++e) {
        int2 r = erec[e];
        uint2 kv = *(const uint2*)&kvw[(size_t)r.x * 128 + c0];
        uint2 tp = tabq[(size_t)(r.y >> 16) * 64 + ln];
        edgeN(kv, tp, (float)(r.y & 0xffff) * FS);
    }

    const float2 sk = *(const float2*)&skip[(size_t)wid * CC + c0];
    float inv = 1.0f / (den + 1e-16f);
    float2 o;
    o.x = sspf(fmaf(nx, inv, sk.x));
    o.y = sspf(fmaf(ny, inv, sk.y));
    *(float2*)&tout[(size_t)wid * CC + c0] = o;
}

// ---------------- output head ----------------
__global__ __launch_bounds__(64) void k_head(
    const float* __restrict__ h,
    const float* __restrict__ w1, const float* __restrict__ b1,
    const float* __restrict__ w2, const float* __restrict__ b2,
    float* __restrict__ out)
{
    const int n = blockIdx.x;
    const int j = threadIdx.x;
    float acc = 0.0f;
    for (int k = 0; k < CC; ++k)
        acc = fmaf(h[(size_t)n * CC + k], w1[k * 64 + j], acc);
    float m = sspf(acc + b1[j]);
    float o = m * w2[j];
    #pragma unroll
    for (int msk = 32; msk > 0; msk >>= 1) o += __shfl_xor(o, msk);
    if (j == 0) out[n] = o + b2[0];
}

extern "C" void kernel_launch(void* const* d_in, const int* in_sizes, int n_in,
                              void* d_out, int out_size, void* d_ws, size_t ws_size,
                              hipStream_t stream)
{
    const int*   z   = (const int*)d_in[0];
    const float* pos = (const float*)d_in[1];
    const int*   ei  = (const int*)d_in[2];
    const float* emb = (const float*)d_in[3];
    const float* w1  = (const float*)d_in[4];
    const float* b1  = (const float*)d_in[5];
    const float* w2  = (const float*)d_in[6];
    const float* b2  = (const float*)d_in[7];
    const float* wq  = (const float*)d_in[8];
    const float* bq  = (const float*)d_in[9];
    const float* wk  = (const float*)d_in[10];
    const float* bk  = (const float*)d_in[11];
    const float* wv  = (const float*)d_in[12];
    const float* bv  = (const float*)d_in[13];
    const float* we  = (const float*)d_in[14];
    const float* be  = (const float*)d_in[15];
    const float* wsk = (const float*)d_in[16];
    const float* bsk = (const float*)d_in[17];
    const float* wl  = (const float*)d_in[18];
    const float* bl  = (const float*)d_in[19];
    const float* wo1 = (const float*)d_in[20];
    const float* bo1 = (const float*)d_in[21];
    const float* wo2 = (const float*)d_in[22];
    const float* bo2 = (const float*)d_in[23];

    char* p = (char*)d_ws;
    auto alloc = [&](size_t bytes) -> void* {
        void* r = (void*)p; p += (bytes + 255) & ~(size_t)255; return r;
    };
    float* h    = (float*)alloc((size_t)NN * CC * 4);
    float* q    = (float*)alloc((size_t)NN * CC * 4);
    float* skip = (float*)alloc((size_t)NN * CC * 4);
    float* tbuf = (float*)alloc((size_t)NN * CC * 4);
    unsigned int* kvw = (unsigned int*)alloc((size_t)NN * 128 * 4);  // bf16 k/v pairs
    float4* pos4 = (float4*)alloc((size_t)NN * 16);
    float* w23f = (float*)alloc((size_t)LL * FF * CC * 4);
    float* b23g = (float*)alloc((size_t)LL * CC * 4);
    float* tab  = (float*)alloc((size_t)LL * (NTAB + 1) * CC * 4);
    uint2* tabq = (uint2*)alloc((size_t)LL * NTAB * 64 * 8);
    float* bkf  = (float*)alloc((size_t)LL * CC * 4);
    float* bvf  = (float*)alloc((size_t)LL * CC * 4);
    u16*   wn   = (u16*)alloc((size_t)LL * 5 * 128 * 128 * 2);
    int* cnt2   = (int*)alloc((size_t)2 * NN * 4);     // cnt | cntN
    int* rowptr = (int*)alloc((size_t)(NN + 1) * 4);
    int* rowmid = (int*)alloc((size_t)NN * 4);
    int* curF   = (int*)alloc((size_t)NN * 4);
    int* curN   = (int*)alloc((size_t)NN * 4);
    int* srcp   = (int*)alloc((size_t)NE * 4);
    int* drec   = (int*)alloc((size_t)NE * 4);
    int2* erec  = (int2*)alloc((size_t)NE * 8);
    int* cnt  = cnt2;
    int* cntN = cnt2 + NN;

    k_zero<<<(2 * NN + 255) / 256, 256, 0, stream>>>(cnt2, 2 * NN);
    k_pos4<<<(NN + 255) / 256, 256, 0, stream>>>(pos, pos4);
    k_dist<<<(NE + 255) / 256, 256, 0, stream>>>(ei, pos4, cnt, cntN, drec);
    k_scan<<<1, 1024, 0, stream>>>(cnt, rowptr, curF);
    k_mid<<<(NN + 255) / 256, 256, 0, stream>>>(rowptr, cntN, rowmid, curN);
    k_scatter<<<(NE + 255) / 256, 256, 0, stream>>>(ei, drec, curF, curN, srcp, erec);
    k_prep23<<<LL * 128, 128, 0, stream>>>(w2, we, w23f);
    k_prepb<<<LL, 128, 0, stream>>>(b2, we, be, b23g);
    k_prept<<<LL * (NTAB + 1), 128, 0, stream>>>(w1, b1, w23f, b23g, tab);
    k_packt<<<(LL * NTAB * 64 + 255) / 256, 256, 0, stream>>>(tab, tabq);
    k_foldb<<<LL, 128, 0, stream>>>(bk, bv, tab, bkf, bvf);
    k_prepn<<<(LL * 5 * 128 * 128 + 255) / 256, 256, 0, stream>>>(wq, wk, wv, wsk, wl, wn);

    const int NT = (NN + 63) / 64;   // 313
    // layer 0 q/k/v/skip from emb[z] (writes h too)
    k_node<0><<<NT, 256, 0, stream>>>(z, emb, nullptr, nullptr, nullptr, h,
        wn, bq, bkf, bvf, bsk, q, kvw, skip, NN);
    for (int l = 0; l < LL; ++l) {
        k_agg<<<(NN * 64 + 255) / 256, 256, 0, stream>>>(rowptr, rowmid, srcp, erec,
            tabq + (size_t)l * NTAB * 64, q, kvw, skip, tbuf);
        const u16* wnl = wn + (size_t)l * 5 * 16384;
        if (l < LL - 1) {
            const u16* wnn = wn + (size_t)(l + 1) * 5 * 16384;
            k_node<1><<<NT, 256, 0, stream>>>(nullptr, nullptr, tbuf,
                wnl + 4 * 16384, bl + l * CC, h,
                wnn, bq + (l + 1) * CC, bkf + (l + 1) * CC,
                bvf + (l + 1) * CC, bsk + (l + 1) * CC,
                q, kvw, skip, NN);
        } else {
            k_node<2><<<NT, 256, 0, stream>>>(nullptr, nullptr, tbuf,
                wnl + 4 * 16384, bl + l * CC, h,
                nullptr, nullptr, nullptr, nullptr, nullptr,
                nullptr, nullptr, nullptr, NN);
        }
    }
    k_head<<<NN, 64, 0, stream>>>(h, wo1, bo1, wo2, bo2, (float*)d_out);
}

// Round 17
// 382.524 us; speedup vs baseline: 3.4968x; 1.0315x over previous
//
#include <hip/hip_runtime.h>

#define NN 20000
#define NE 640000
#define CC 128
#define HH 8
#define GG 50
#define FF 128
#define LL 3
#define NTAB 2048
#define DMAX 12.0f

typedef unsigned short u16;
typedef __attribute__((ext_vector_type(8))) short bf16x8;   // 8 bf16 = 4 VGPRs
typedef __attribute__((ext_vector_type(4))) float f32x4;

__device__ __forceinline__ u16 f2bf(float f) {
    union { float f; unsigned int i; } x; x.f = f;
    unsigned int r = x.i + 0x7fffu + ((x.i >> 16) & 1u);
    return (u16)(r >> 16);
}
// ShiftedSoftplus: softplus(x)-log2 via HW exp/log
__device__ __forceinline__ float sspf(float x) {
    return fmaxf(x, 0.0f) + __logf(1.0f + __expf(-fabsf(x))) - 0.69314718055994531f;
}

// ---------------- CSR build (sort edges by dst; far edges first per node) ------
// pos4 + zero packed counts in one kernel
__global__ void k_pos4(const float* __restrict__ pos, float4* __restrict__ pos4,
                       int* __restrict__ packed) {
    int n = blockIdx.x * 256 + threadIdx.x;
    if (n < NN) {
        float4 v;
        v.x = pos[n * 3 + 0]; v.y = pos[n * 3 + 1]; v.z = pos[n * 3 + 2]; v.w = 0.0f;
        pos4[n] = v;
        packed[n] = 0;
    }
}

// 4 edges/thread: distance record + packed histogram (cnt lo16, cntN hi16)
// drec[e] = -1 (far) or (i0<<16)|frac16 (near; i0<=2046 so never -1)
__global__ void k_dist(const int* __restrict__ ei, const float4* __restrict__ pos4,
                       int* __restrict__ packed, int* __restrict__ drec) {
    int base = (blockIdx.x * 256 + threadIdx.x) * 4;
    if (base >= NE) return;
    int aa[4], bb[4], rec[4];
    #pragma unroll
    for (int j = 0; j < 4; ++j) {
        int e = base + j;
        aa[j] = ei[e]; bb[j] = ei[NE + e];
    }
    float4 pa[4], pb[4];
    #pragma unroll
    for (int j = 0; j < 4; ++j) { pa[j] = pos4[aa[j]]; pb[j] = pos4[bb[j]]; }
    #pragma unroll
    for (int j = 0; j < 4; ++j) {
        float dx = pb[j].x - pa[j].x, dy = pb[j].y - pa[j].y, dz = pb[j].z - pa[j].z;
        float d = sqrtf(dx * dx + dy * dy + dz * dz + 1e-12f);
        float tt = d * ((float)NTAB / DMAX);
        bool far = tt >= (float)(NTAB - 1);
        int r = -1;
        if (!far) {
            int i0 = (int)tt;
            int fr = min((int)((tt - (float)i0) * 65536.0f), 65535);
            r = (i0 << 16) | fr;
        }
        rec[j] = r;
        drec[base + j] = r;
        atomicAdd(&packed[bb[j]], far ? 1 : 0x10001);   // no return -> fire & forget
    }
}

__global__ __launch_bounds__(1024) void k_scan(const int* __restrict__ packed,
                                               int* __restrict__ rowptr,
                                               int* __restrict__ curF) {
    __shared__ int sums[1024];
    const int t = threadIdx.x;
    int local[20];
    int base = t * 20;
    int s = 0;
    #pragma unroll
    for (int i = 0; i < 20; ++i) {
        int idx = base + i;
        int v = (idx < NN) ? (packed[idx] & 0xffff) : 0;
        local[i] = s; s += v;
    }
    sums[t] = s;
    __syncthreads();
    for (int off = 1; off < 1024; off <<= 1) {
        int v = (t >= off) ? sums[t - off] : 0;
        __syncthreads();
        sums[t] += v;
        __syncthreads();
    }
    int excl = (t == 0) ? 0 : sums[t - 1];
    #pragma unroll
    for (int i = 0; i < 20; ++i) {
        int idx = base + i;
        if (idx < NN) { int r = excl + local[i]; rowptr[idx] = r; curF[idx] = r; }
    }
    if (t == 1023) rowptr[NN] = sums[1023];
}

// rowmid[n] = rowptr[n+1] - cntN[n]; near cursor starts at rowmid
__global__ void k_mid(const int* __restrict__ rowptr, const int* __restrict__ packed,
                      int* __restrict__ rowmid, int* __restrict__ curN) {
    int n = blockIdx.x * 256 + threadIdx.x;
    if (n < NN) {
        int m = rowptr[n + 1] - (((unsigned)packed[n]) >> 16);
        rowmid[n] = m; curN[n] = m;
    }
}

// 4 edges/thread: far -> [rowptr, rowmid) src only; near -> [rowmid, ...) + erec
__global__ void k_scatter(const int* __restrict__ ei, const int* __restrict__ drec,
                          int* __restrict__ curF, int* __restrict__ curN,
                          int* __restrict__ srcp, int2* __restrict__ erec) {
    int base = (blockIdx.x * 256 + threadIdx.x) * 4;
    if (base >= NE) return;
    int aa[4], bb[4], rec[4], pp[4];
    #pragma unroll
    for (int j = 0; j < 4; ++j) {
        int e = base + j;
        aa[j] = ei[e]; bb[j] = ei[NE + e]; rec[j] = drec[e];
    }
    #pragma unroll
    for (int j = 0; j < 4; ++j)
        pp[j] = atomicAdd((rec[j] == -1) ? &curF[bb[j]] : &curN[bb[j]], 1);
    #pragma unroll
    for (int j = 0; j < 4; ++j) {
        srcp[pp[j]] = aa[j];
        if (rec[j] != -1) { int2 r; r.x = aa[j]; r.y = rec[j]; erec[pp[j]] = r; }
    }
}

// ---------------- weight prep (once per call) ----------------
// W23f[l][k][cp] = sum_c w2[l][k][c] * we[l][c][cp]  (fp32)
__global__ __launch_bounds__(128) void k_prep23(const float* __restrict__ w2,
                                                const float* __restrict__ we,
                                                float* __restrict__ w23f) {
    int l = blockIdx.x >> 7, k = blockIdx.x & 127;
    int cp = threadIdx.x;
    float s = 0.0f;
    for (int c = 0; c < FF; ++c)
        s = fmaf(w2[((size_t)l * FF + k) * FF + c], we[((size_t)l * FF + c) * CC + cp], s);
    w23f[((size_t)l * FF + k) * CC + cp] = s;
}

// b23[l][cp] = be[l][cp] + sum_k b2[l][k] * we[l][k][cp]
__global__ __launch_bounds__(128) void k_prepb(const float* __restrict__ b2,
                                               const float* __restrict__ we,
                                               const float* __restrict__ be,
                                               float* __restrict__ b23g) {
    int l = blockIdx.x;
    int cp = threadIdx.x;
    float s = be[l * CC + cp];
    for (int k = 0; k < FF; ++k)
        s = fmaf(b2[l * FF + k], we[((size_t)l * FF + k) * CC + cp], s);
    b23g[l * CC + cp] = s;
}

// ep table: tab[l][i][cp] = MLP(gauss(d_i)) exact fp32, i in [0,NTAB]
__global__ __launch_bounds__(128) void k_prept(const float* __restrict__ w1,
                                               const float* __restrict__ b1,
                                               const float* __restrict__ w23f,
                                               const float* __restrict__ b23g,
                                               float* __restrict__ tab) {
    const int l = blockIdx.x / (NTAB + 1);
    const int i = blockIdx.x % (NTAB + 1);
    const int c = threadIdx.x;
    __shared__ float attr[GG];
    __shared__ float hid[FF];
    const float STEP = 10.0f / 49.0f;
    const float COEF = -0.5f / (STEP * STEP);
    float d = (float)i * (DMAX / (float)NTAB);
    if (c < GG) { float df = d - STEP * (float)c; attr[c] = __expf(COEF * df * df); }
    __syncthreads();
    float s = b1[l * FF + c];
    for (int g = 0; g < GG; ++g)
        s = fmaf(attr[g], w1[((size_t)l * GG + g) * FF + c], s);
    hid[c] = sspf(s);
    __syncthreads();
    float o = b23g[l * CC + c];
    for (int k = 0; k < FF; ++k)
        o = fmaf(hid[k], w23f[((size_t)l * FF + k) * CC + c], o);
    tab[((size_t)l * (NTAB + 1) + i) * CC + c] = o;
}

// bf16 DELTA table pairs: tabq[l][i][ln] = { bf16(tab[i]-ep_inf) pair, bf16(tab[i+1]-ep_inf) pair }
__global__ void k_packt(const float* __restrict__ tab, uint2* __restrict__ tabq) {
    int idx = blockIdx.x * 256 + threadIdx.x;
    if (idx >= LL * NTAB * 64) return;
    int ln = idx & 63;
    int i = (idx >> 6) % NTAB;
    int l = idx / (NTAB * 64);
    int c0 = ln * 2;
    const float* t0 = &tab[((size_t)l * (NTAB + 1) + i) * CC + c0];
    const float* t1 = t0 + CC;
    const float* ti = &tab[((size_t)l * (NTAB + 1) + NTAB) * CC + c0];
    uint2 o;
    o.x = (unsigned)f2bf(t0[0] - ti[0]) | ((unsigned)f2bf(t0[1] - ti[1]) << 16);
    o.y = (unsigned)f2bf(t1[0] - ti[0]) | ((unsigned)f2bf(t1[1] - ti[1]) << 16);
    tabq[((size_t)l * NTAB + i) * 64 + ln] = o;
}

// fold ep_inf into k/v biases: bkf = bk + ep_inf, bvf = bv + ep_inf
__global__ __launch_bounds__(128) void k_foldb(const float* __restrict__ bk,
                                               const float* __restrict__ bv,
                                               const float* __restrict__ tab,
                                               float* __restrict__ bkf,
                                               float* __restrict__ bvf) {
    int l = blockIdx.x, c = threadIdx.x;
    float ep = tab[((size_t)l * (NTAB + 1) + NTAB) * CC + c];
    bkf[l * CC + c] = bk[l * CC + c] + ep;
    bvf[l * CC + c] = bv[l * CC + c] + ep;
}

// node weights: wn[((l*5+m)*128 + c)*128 + k] = bf16(W_m[l][k][c]); m: q,k,v,skip,l
__global__ void k_prepn(const float* __restrict__ wq, const float* __restrict__ wk,
                        const float* __restrict__ wv, const float* __restrict__ wsk,
                        const float* __restrict__ wl, u16* __restrict__ wn) {
    int i = blockIdx.x * 256 + threadIdx.x;
    if (i >= LL * 5 * 128 * 128) return;
    int k = i & 127, c = (i >> 7) & 127;
    int lm = i >> 14; int m = lm % 5, l = lm / 5;
    const float* W = (m == 0) ? wq : (m == 1) ? wk : (m == 2) ? wv : (m == 3) ? wsk : wl;
    wn[i] = f2bf(W[((size_t)l * 128 + k) * 128 + c]);
}

// ---------------- fused node kernel (64-row tiles, 313 blocks) ----------------
// MODE 0: hb <- emb[z] (also writes h);         then 4 GEMMs -> q,kvw,skip
// MODE 1: tb <- tbuf; h += tb@wl (hb <- new h); then 4 GEMMs -> q,kvw,skip
// MODE 2: tb <- tbuf; h += tb@wl               (no next-layer GEMMs)
// kvw layout: per node 128 u32; u32[n*128+c]=k-pair(c,c+1) even c, [+1]=v-pair.
// NOTE: k/v biases passed in are ep_inf-folded.
template<int MODE>
__global__ __launch_bounds__(256) void k_node(
    const int* __restrict__ z, const float* __restrict__ emb,
    const float* __restrict__ tbuf,
    const u16* __restrict__ wlT, const float* __restrict__ bl,
    float* __restrict__ h,
    const u16* __restrict__ wq4,
    const float* __restrict__ bq, const float* __restrict__ bk,
    const float* __restrict__ bv, const float* __restrict__ bs,
    float* __restrict__ o_q, unsigned int* __restrict__ kvw,
    float* __restrict__ o_skip, int nrows)
{
    __shared__ __align__(16) short tb[64 * 136];
    __shared__ __align__(16) short hb[64 * 136];
    const int t = threadIdx.x, lane = t & 63, w = t >> 6;
    const int tx = lane & 15, tg = lane >> 4;
    const int n0 = blockIdx.x * 64;
    const f32x4 zf4 = { 0.0f, 0.0f, 0.0f, 0.0f };

    if (MODE == 0) {
        for (int idx = t; idx < 64 * 32; idx += 256) {
            int r = idx >> 5, kq = idx & 31;
            int n = n0 + r;
            float4 hv;
            if (n < nrows) {
                hv = *(const float4*)&emb[(size_t)z[n] * CC + kq * 4];
                *(float4*)&h[(size_t)n * CC + kq * 4] = hv;
            } else { hv.x = hv.y = hv.z = hv.w = 0.0f; }
            uint2 pk = make_uint2((unsigned)f2bf(hv.x) | ((unsigned)f2bf(hv.y) << 16),
                                  (unsigned)f2bf(hv.z) | ((unsigned)f2bf(hv.w) << 16));
            *(uint2*)&hb[r * 136 + kq * 4] = pk;
        }
        __syncthreads();
    } else {
        for (int idx = t; idx < 64 * 32; idx += 256) {
            int r = idx >> 5, kq = idx & 31;
            int n = n0 + r;
            float4 tv;
            if (n < nrows) tv = *(const float4*)&tbuf[(size_t)n * 128 + kq * 4];
            else { tv.x = tv.y = tv.z = tv.w = 0.0f; }
            uint2 pk = make_uint2((unsigned)f2bf(tv.x) | ((unsigned)f2bf(tv.y) << 16),
                                  (unsigned)f2bf(tv.z) | ((unsigned)f2bf(tv.w) << 16));
            *(uint2*)&tb[r * 136 + kq * 4] = pk;
        }
        __syncthreads();
        // GEMM tb @ wl -> new h; write h (f32) and hb (bf16)
        f32x4 acc[2][4];
        #pragma unroll
        for (int mt = 0; mt < 2; ++mt)
            #pragma unroll
            for (int nt = 0; nt < 4; ++nt) acc[mt][nt] = zf4;
        #pragma unroll
        for (int s = 0; s < 4; ++s) {
            bf16x8 af[2], bfr[4];
            #pragma unroll
            for (int mt = 0; mt < 2; ++mt)
                af[mt] = *(const bf16x8*)&wlT[(size_t)(w * 32 + mt * 16 + tx) * 128 + s * 32 + tg * 8];
            #pragma unroll
            for (int nt = 0; nt < 4; ++nt)
                bfr[nt] = *(const bf16x8*)&tb[(nt * 16 + tx) * 136 + s * 32 + tg * 8];
            #pragma unroll
            for (int mt = 0; mt < 2; ++mt)
                #pragma unroll
                for (int nt = 0; nt < 4; ++nt)
                    acc[mt][nt] = __builtin_amdgcn_mfma_f32_16x16x32_bf16(af[mt], bfr[nt], acc[mt][nt], 0, 0, 0);
        }
        #pragma unroll
        for (int mt = 0; mt < 2; ++mt) {
            int c0 = w * 32 + mt * 16 + tg * 4;
            float4 bb = *(const float4*)&bl[c0];
            #pragma unroll
            for (int nt = 0; nt < 4; ++nt) {
                int n = n0 + nt * 16 + tx;
                if (n < nrows) {
                    float4 hv = *(const float4*)&h[(size_t)n * 128 + c0];
                    hv.x += acc[mt][nt][0] + bb.x; hv.y += acc[mt][nt][1] + bb.y;
                    hv.z += acc[mt][nt][2] + bb.z; hv.w += acc[mt][nt][3] + bb.w;
                    *(float4*)&h[(size_t)n * 128 + c0] = hv;
                    if (MODE == 1) {
                        uint2 pk = make_uint2((unsigned)f2bf(hv.x) | ((unsigned)f2bf(hv.y) << 16),
                                              (unsigned)f2bf(hv.z) | ((unsigned)f2bf(hv.w) << 16));
                        *(uint2*)&hb[(nt * 16 + tx) * 136 + c0] = pk;
                    }
                }
            }
        }
        if (MODE == 1) __syncthreads();
    }

    if (MODE <= 1) {
        // 4 GEMMs from hb: m=0 q, m=1 k-pairs, m=2 v-pairs, m=3 skip
        #pragma unroll
        for (int m = 0; m < 4; ++m) {
            f32x4 acc[2][4];
            #pragma unroll
            for (int mt = 0; mt < 2; ++mt)
                #pragma unroll
                for (int nt = 0; nt < 4; ++nt) acc[mt][nt] = zf4;
            const u16* Wm = wq4 + (size_t)m * 16384;
            #pragma unroll
            for (int s = 0; s < 4; ++s) {
                bf16x8 af[2], bfr[4];
                #pragma unroll
                for (int mt = 0; mt < 2; ++mt)
                    af[mt] = *(const bf16x8*)&Wm[(size_t)(w * 32 + mt * 16 + tx) * 128 + s * 32 + tg * 8];
                #pragma unroll
                for (int nt = 0; nt < 4; ++nt)
                    bfr[nt] = *(const bf16x8*)&hb[(nt * 16 + tx) * 136 + s * 32 + tg * 8];
                #pragma unroll
                for (int mt = 0; mt < 2; ++mt)
                    #pragma unroll
                    for (int nt = 0; nt < 4; ++nt)
                        acc[mt][nt] = __builtin_amdgcn_mfma_f32_16x16x32_bf16(af[mt], bfr[nt], acc[mt][nt], 0, 0, 0);
            }
            const float* Bm = (m == 0) ? bq : (m == 1) ? bk : (m == 2) ? bv : bs;
            if (m == 0 || m == 3) {
                float* Om = (m == 0) ? o_q : o_skip;
                #pragma unroll
                for (int mt = 0; mt < 2; ++mt) {
                    int c0 = w * 32 + mt * 16 + tg * 4;
                    float4 bb = *(const float4*)&Bm[c0];
                    #pragma unroll
                    for (int nt = 0; nt < 4; ++nt) {
                        int n = n0 + nt * 16 + tx;
                        if (n < nrows) {
                            float4 ov;
                            ov.x = acc[mt][nt][0] + bb.x; ov.y = acc[mt][nt][1] + bb.y;
                            ov.z = acc[mt][nt][2] + bb.z; ov.w = acc[mt][nt][3] + bb.w;
                            *(float4*)&Om[(size_t)n * 128 + c0] = ov;
                        }
                    }
                }
            } else {
                const int off = (m == 1) ? 0 : 1;
                #pragma unroll
                for (int mt = 0; mt < 2; ++mt) {
                    int c0 = w * 32 + mt * 16 + tg * 4;
                    float4 bb = *(const float4*)&Bm[c0];
                    #pragma unroll
                    for (int nt = 0; nt < 4; ++nt) {
                        int n = n0 + nt * 16 + tx;
                        if (n < nrows) {
                            unsigned p01 = (unsigned)f2bf(acc[mt][nt][0] + bb.x)
                                         | ((unsigned)f2bf(acc[mt][nt][1] + bb.y) << 16);
                            unsigned p23 = (unsigned)f2bf(acc[mt][nt][2] + bb.z)
                                         | ((unsigned)f2bf(acc[mt][nt][3] + bb.w) << 16);
                            size_t base = (size_t)n * 128 + c0;
                            kvw[base + off] = p01;
                            kvw[base + 2 + off] = p23;
                        }
                    }
                }
            }
        }
    }
}

// ---------------- node-centric edge aggregation --------------------------------
// One wave per dst node; 2 channels/lane. Edges sorted far-first per node.
// Far edge (d>=DMAX): ep folded into kvw biases -> 1 kv gather + dot + exp.
// Near edge: + bf16 delta-table lerp. q pre-scaled by 0.25*log2(e); exp2f.
__global__ __launch_bounds__(256) void k_agg(
    const int* __restrict__ rowptr, const int* __restrict__ rowmid,
    const int* __restrict__ srcp, const int2* __restrict__ erec,
    const uint2* __restrict__ tabq, const float* __restrict__ qn,
    const unsigned int* __restrict__ kvw, const float* __restrict__ skip,
    float* __restrict__ tout)
{
    int wid0 = (blockIdx.x * 256 + threadIdx.x) >> 6;   // node id
    if (wid0 >= NN) return;
    const int wid = __builtin_amdgcn_readfirstlane(wid0);   // SGPR -> scalar loads
    const int ln = threadIdx.x & 63;
    const int c0 = ln * 2;   // head = ln>>3
    const float SC = 0.25f * 1.4426950408889634f;
    float2 q2 = *(const float2*)&qn[(size_t)wid * CC + c0];
    q2.x *= SC; q2.y *= SC;
    float nx = 0.0f, ny = 0.0f, den = 0.0f;
    int e = rowptr[wid];
    const int emid = rowmid[wid];
    const int eend = rowptr[wid + 1];
    const float FS = 1.52587890625e-5f;   // 1/65536

    auto edgeF = [&](uint2 kv) {
        float kex = __uint_as_float(kv.x << 16);
        float key = __uint_as_float(kv.x & 0xffff0000u);
        float vex = __uint_as_float(kv.y << 16);
        float vey = __uint_as_float(kv.y & 0xffff0000u);
        float p = fmaf(q2.x, kex, q2.y * key);
        p += __shfl_xor(p, 1);
        p += __shfl_xor(p, 2);
        p += __shfl_xor(p, 4);          // sum over the head's 16 channels
        float w = exp2f(p);
        nx = fmaf(w, vex, nx);
        ny = fmaf(w, vey, ny);
        den += w;
    };
    auto edgeN = [&](uint2 kv, uint2 tp, float fr) {
        float t0x = __uint_as_float(tp.x << 16);
        float t0y = __uint_as_float(tp.x & 0xffff0000u);
        float t1x = __uint_as_float(tp.y << 16);
        float t1y = __uint_as_float(tp.y & 0xffff0000u);
        float ex = fmaf(fr, t1x - t0x, t0x);
        float ey = fmaf(fr, t1y - t0y, t0y);
        float kex = __uint_as_float(kv.x << 16) + ex;
        float key = __uint_as_float(kv.x & 0xffff0000u) + ey;
        float vex = __uint_as_float(kv.y << 16) + ex;
        float vey = __uint_as_float(kv.y & 0xffff0000u) + ey;
        float p = fmaf(q2.x, kex, q2.y * key);
        p += __shfl_xor(p, 1);
        p += __shfl_xor(p, 2);
        p += __shfl_xor(p, 4);
        float w = exp2f(p);
        nx = fmaf(w, vex, nx);
        ny = fmaf(w, vey, ny);
        den += w;
    };

    // ---- far edges, 8-deep ----
    for (; e + 8 <= emid; e += 8) {
        int s0 = srcp[e + 0], s1 = srcp[e + 1], s2 = srcp[e + 2], s3 = srcp[e + 3];
        int s4 = srcp[e + 4], s5 = srcp[e + 5], s6 = srcp[e + 6], s7 = srcp[e + 7];
        uint2 kv0 = *(const uint2*)&kvw[(size_t)s0 * 128 + c0];
        uint2 kv1 = *(const uint2*)&kvw[(size_t)s1 * 128 + c0];
        uint2 kv2 = *(const uint2*)&kvw[(size_t)s2 * 128 + c0];
        uint2 kv3 = *(const uint2*)&kvw[(size_t)s3 * 128 + c0];
        uint2 kv4 = *(const uint2*)&kvw[(size_t)s4 * 128 + c0];
        uint2 kv5 = *(const uint2*)&kvw[(size_t)s5 * 128 + c0];
        uint2 kv6 = *(const uint2*)&kvw[(size_t)s6 * 128 + c0];
        uint2 kv7 = *(const uint2*)&kvw[(size_t)s7 * 128 + c0];
        edgeF(kv0); edgeF(kv1); edgeF(kv2); edgeF(kv3);
        edgeF(kv4); edgeF(kv5); edgeF(kv6); edgeF(kv7);
    }
    for (; e < emid; ++e) {
        uint2 kv = *(const uint2*)&kvw[(size_t)srcp[e] * 128 + c0];
        edgeF(kv);
    }
    // ---- near edges, 4-deep ----
    for (; e + 4 <= eend; e += 4) {
        int2 r0 = erec[e + 0], r1 = erec[e + 1], r2 = erec[e + 2], r3 = erec[e + 3];
        uint2 kv0 = *(const uint2*)&kvw[(size_t)r0.x * 128 + c0];
        uint2 kv1 = *(const uint2*)&kvw[(size_t)r1.x * 128 + c0];
        uint2 kv2 = *(const uint2*)&kvw[(size_t)r2.x * 128 + c0];
        uint2 kv3 = *(const uint2*)&kvw[(size_t)r3.x * 128 + c0];
        uint2 tp0 = tabq[(size_t)(r0.y >> 16) * 64 + ln];
        uint2 tp1 = tabq[(size_t)(r1.y >> 16) * 64 + ln];
        uint2 tp2 = tabq[(size_t)(r2.y >> 16) * 64 + ln];
        uint2 tp3 = tabq[(size_t)(r3.y >> 16) * 64 + ln];
        edgeN(kv0, tp0, (float)(r0.y & 0xffff) * FS);
        edgeN(kv1, tp1, (float)(r1.y & 0xffff) * FS);
        edgeN(kv2, tp2, (float)(r2.y & 0xffff) * FS);
        edgeN(kv3, tp3, (float)(r3.y & 0xffff) * FS);
    }
    for (; e < eend; ++e) {
        int2 r = erec[e];
        uint2 kv = *(const uint2*)&kvw[(size_t)r.x * 128 + c0];
        uint2 tp = tabq[(size_t)(r.y >> 16) * 64 + ln];
        edgeN(kv, tp, (float)(r.y & 0xffff) * FS);
    }

    const float2 sk = *(const float2*)&skip[(size_t)wid * CC + c0];
    float inv = 1.0f / (den + 1e-16f);
    float2 o;
    o.x = sspf(fmaf(nx, inv, sk.x));
    o.y = sspf(fmaf(ny, inv, sk.y));
    *(float2*)&tout[(size_t)wid * CC + c0] = o;
}

// ---------------- output head ----------------
__global__ __launch_bounds__(64) void k_head(
    const float* __restrict__ h,
    const float* __restrict__ w1, const float* __restrict__ b1,
    const float* __restrict__ w2, const float* __restrict__ b2,
    float* __restrict__ out)
{
    const int n = blockIdx.x;
    const int j = threadIdx.x;
    float acc = 0.0f;
    for (int k = 0; k < CC; ++k)
        acc = fmaf(h[(size_t)n * CC + k], w1[k * 64 + j], acc);
    float m = sspf(acc + b1[j]);
    float o = m * w2[j];
    #pragma unroll
    for (int msk = 32; msk > 0; msk >>= 1) o += __shfl_xor(o, msk);
    if (j == 0) out[n] = o + b2[0];
}

extern "C" void kernel_launch(void* const* d_in, const int* in_sizes, int n_in,
                              void* d_out, int out_size, void* d_ws, size_t ws_size,
                              hipStream_t stream)
{
    const int*   z   = (const int*)d_in[0];
    const float* pos = (const float*)d_in[1];
    const int*   ei  = (const int*)d_in[2];
    const float* emb = (const float*)d_in[3];
    const float* w1  = (const float*)d_in[4];
    const float* b1  = (const float*)d_in[5];
    const float* w2  = (const float*)d_in[6];
    const float* b2  = (const float*)d_in[7];
    const float* wq  = (const float*)d_in[8];
    const float* bq  = (const float*)d_in[9];
    const float* wk  = (const float*)d_in[10];
    const float* bk  = (const float*)d_in[11];
    const float* wv  = (const float*)d_in[12];
    const float* bv  = (const float*)d_in[13];
    const float* we  = (const float*)d_in[14];
    const float* be  = (const float*)d_in[15];
    const float* wsk = (const float*)d_in[16];
    const float* bsk = (const float*)d_in[17];
    const float* wl  = (const float*)d_in[18];
    const float* bl  = (const float*)d_in[19];
    const float* wo1 = (const float*)d_in[20];
    const float* bo1 = (const float*)d_in[21];
    const float* wo2 = (const float*)d_in[22];
    const float* bo2 = (const float*)d_in[23];

    char* p = (char*)d_ws;
    auto alloc = [&](size_t bytes) -> void* {
        void* r = (void*)p; p += (bytes + 255) & ~(size_t)255; return r;
    };
    float* h    = (float*)alloc((size_t)NN * CC * 4);
    float* q    = (float*)alloc((size_t)NN * CC * 4);
    float* skip = (float*)alloc((size_t)NN * CC * 4);
    float* tbuf = (float*)alloc((size_t)NN * CC * 4);
    unsigned int* kvw = (unsigned int*)alloc((size_t)NN * 128 * 4);  // bf16 k/v pairs
    float4* pos4 = (float4*)alloc((size_t)NN * 16);
    float* w23f = (float*)alloc((size_t)LL * FF * CC * 4);
    float* b23g = (float*)alloc((size_t)LL * CC * 4);
    float* tab  = (float*)alloc((size_t)LL * (NTAB + 1) * CC * 4);
    uint2* tabq = (uint2*)alloc((size_t)LL * NTAB * 64 * 8);
    float* bkf  = (float*)alloc((size_t)LL * CC * 4);
    float* bvf  = (float*)alloc((size_t)LL * CC * 4);
    u16*   wn   = (u16*)alloc((size_t)LL * 5 * 128 * 128 * 2);
    int* packed = (int*)alloc((size_t)NN * 4);
    int* rowptr = (int*)alloc((size_t)(NN + 1) * 4);
    int* rowmid = (int*)alloc((size_t)NN * 4);
    int* curF   = (int*)alloc((size_t)NN * 4);
    int* curN   = (int*)alloc((size_t)NN * 4);
    int* srcp   = (int*)alloc((size_t)NE * 4);
    int* drec   = (int*)alloc((size_t)NE * 4);
    int2* erec  = (int2*)alloc((size_t)NE * 8);

    k_pos4<<<(NN + 255) / 256, 256, 0, stream>>>(pos, pos4, packed);
    k_dist<<<(NE / 4 + 255) / 256, 256, 0, stream>>>(ei, pos4, packed, drec);
    k_scan<<<1, 1024, 0, stream>>>(packed, rowptr, curF);
    k_mid<<<(NN + 255) / 256, 256, 0, stream>>>(rowptr, packed, rowmid, curN);
    k_scatter<<<(NE / 4 + 255) / 256, 256, 0, stream>>>(ei, drec, curF, curN, srcp, erec);
    k_prep23<<<LL * 128, 128, 0, stream>>>(w2, we, w23f);
    k_prepb<<<LL, 128, 0, stream>>>(b2, we, be, b23g);
    k_prept<<<LL * (NTAB + 1), 128, 0, stream>>>(w1, b1, w23f, b23g, tab);
    k_packt<<<(LL * NTAB * 64 + 255) / 256, 256, 0, stream>>>(tab, tabq);
    k_foldb<<<LL, 128, 0, stream>>>(bk, bv, tab, bkf, bvf);
    k_prepn<<<(LL * 5 * 128 * 128 + 255) / 256, 256, 0, stream>>>(wq, wk, wv, wsk, wl, wn);

    const int NT = (NN + 63) / 64;   // 313
    // layer 0 q/k/v/skip from emb[z] (writes h too)
    k_node<0><<<NT, 256, 0, stream>>>(z, emb, nullptr, nullptr, nullptr, h,
        wn, bq, bkf, bvf, bsk, q, kvw, skip, NN);
    for (int l = 0; l < LL; ++l) {
        k_agg<<<(NN * 64 + 255) / 256, 256, 0, stream>>>(rowptr, rowmid, srcp, erec,
            tabq + (size_t)l * NTAB * 64, q, kvw, skip, tbuf);
        const u16* wnl = wn + (size_t)l * 5 * 16384;
        if (l < LL - 1) {
            const u16* wnn = wn + (size_t)(l + 1) * 5 * 16384;
            k_node<1><<<NT, 256, 0, stream>>>(nullptr, nullptr, tbuf,
                wnl + 4 * 16384, bl + l * CC, h,
                wnn, bq + (l + 1) * CC, bkf + (l + 1) * CC,
                bvf + (l + 1) * CC, bsk + (l + 1) * CC,
                q, kvw, skip, NN);
        } else {
            k_node<2><<<NT, 256, 0, stream>>>(nullptr, nullptr, tbuf,
                wnl + 4 * 16384, bl + l * CC, h,
                nullptr, nullptr, nullptr, nullptr, nullptr,
                nullptr, nullptr, nullptr, NN);
        }
    }
    k_head<<<NN, 64, 0, stream>>>(h, wo1, bo1, wo2, bo2, (float*)d_out);
}